// Round 8
// baseline (3737.913 us; speedup 1.0000x reference)
//
#include <hip/hip_runtime.h>
#include <hip/hip_bf16.h>
#include <math.h>

typedef unsigned short u16;
typedef __attribute__((ext_vector_type(8))) short s16x8;
typedef __attribute__((ext_vector_type(4))) short s16x4;
typedef __attribute__((ext_vector_type(4))) float f32x4;

#define DEVI static __device__ __forceinline__

DEVI u16 f2bfu(float f) {
    unsigned u = __float_as_uint(f);
    unsigned r = (u + 0x7fffu + ((u >> 16) & 1u)) >> 16;
    return (u16)r;
}
DEVI float bfu2f(u16 u) { return __uint_as_float(((unsigned)u) << 16); }
DEVI float eluf(float x) { return x > 0.f ? x : (expf(x) - 1.f); }
DEVI float sigm(float x) { return 1.f / (1.f + expf(-x)); }

#define GLOAD16(gsrc, ldst)                                                            \
    __builtin_amdgcn_global_load_lds(                                                  \
        (__attribute__((address_space(1))) void*)(void*)(gsrc),                        \
        (__attribute__((address_space(3))) void*)(ldst), 16, 0, 0)

template <int N> DEVI void vmwait();
template <> DEVI void vmwait<0>() { asm volatile("s_waitcnt vmcnt(0)" ::: "memory"); }
template <> DEVI void vmwait<3>() { asm volatile("s_waitcnt vmcnt(3)" ::: "memory"); }
template <> DEVI void vmwait<4>() { asm volatile("s_waitcnt vmcnt(4)" ::: "memory"); }
template <> DEVI void vmwait<5>() { asm volatile("s_waitcnt vmcnt(5)" ::: "memory"); }
template <> DEVI void vmwait<6>() { asm volatile("s_waitcnt vmcnt(6)" ::: "memory"); }

struct GP {
    const u16* A; int lda;
    const u16* Bt;
    float* Cf; u16* Cb; int ldc;
    const float* bias;
    const u16* aux; int auxld;
    const float* zs;               // EPI5
    const float* zmean; const float* zstd;
    double* accum;
    int* idx;                      // EPI8: argmax out
    int K; int gridN; int rbase;
};

// ---------------------------------------------------------------------------
// gemmS: BK=64, T2 XOR-swizzle, 3-deep counted-vmcnt pipeline (T3/T4, proven
// bit-identical r3 vs r4/r5 and passing r6/r7). Now the ONLY GEMM.
// EPI1: elu(v+bias)->bf16 ; EPI2: v+bias->bf16 ; EPI4: elu(v+aux)->bf16
// EPI5: recon-SSE accumulate ; EPI7: v+bias->bf16 (gh)
// EPI8: v+bias->bf16 post logits + fused per-(row,latent) argmax
// ---------------------------------------------------------------------------
template <int EPI, int MF, int NF>
DEVI void epiS(const GP& p, f32x4 (&acc)[MF][NF], int r0, int c0, int wm, int wn,
               int lrow4, int lcol) {
#pragma unroll
    for (int mf = 0; mf < MF; ++mf) {
        int rowb = r0 + (wm * MF + mf) * 16 + lrow4;
#pragma unroll
        for (int nf = 0; nf < NF; ++nf) {
            int col = c0 + (wn * NF + nf) * 16 + lcol;
#pragma unroll
            for (int j = 0; j < 4; ++j) {
                float v = acc[mf][nf][j];
                int r = rowb + j;
                if constexpr (EPI == 1) {
                    p.Cb[(size_t)r * p.ldc + col] = f2bfu(eluf(v + p.bias[col]));
                } else if constexpr (EPI == 2) {
                    p.Cb[(size_t)r * p.ldc + col] = f2bfu(v + p.bias[col]);
                } else if constexpr (EPI == 4) {
                    p.Cb[(size_t)r * p.ldc + col] = f2bfu(eluf(v + bfu2f(p.aux[(size_t)r * p.auxld + col])));
                } else if constexpr (EPI == 7) {
                    p.Cb[(size_t)r * p.ldc + col] = f2bfu(v + p.bias[col]);
                }
            }
        }
    }
}

template <int WM, int WN, int MF, int NF, int EPIa, int EPIb>
__global__ __launch_bounds__(WM * WN * 64) void gemmS(GP pa, GP pb, int nA) {
    constexpr int NT = WM * WN * 64;
    constexpr int BM = WM * MF * 16, BN = WN * NF * 16;
    constexpr int ABY = BM * 128, BBY = BN * 128;
    constexpr int LPT = (ABY + BBY) / (NT * 16);

    const int tid = threadIdx.x, w = tid >> 6, lane = tid & 63;
    const bool isA = (int)blockIdx.x < nA;
    GP p = isA ? pa : pb;
    const int bid = isA ? blockIdx.x : blockIdx.x - nA;
    const int bn = bid % p.gridN, bm = bid / p.gridN;
    const int r0 = bm * BM, c0 = bn * BN;
    const int wm = w / WN, wn = w % WN;

    __shared__ __attribute__((aligned(16))) char sm[3 * (ABY + BBY)];
    __shared__ float ps_[WM * WN];

    auto stage = [&](int kt, int buf) {
        char* s = sm + buf * (ABY + BBY);
#pragma unroll
        for (int it = 0; it < ABY / (NT * 16); ++it) {
            int bo = it * (NT * 16) + tid * 16;
            int row = bo >> 7, kb = bo & 127;
            int kbs = kb ^ ((row & 7) << 4);                       // pre-swizzled source
            GLOAD16(p.A + (size_t)(r0 + row) * p.lda + kt * 64 + (kbs >> 1), s + bo);
        }
        char* sb = s + ABY;
#pragma unroll
        for (int it = 0; it < BBY / (NT * 16); ++it) {
            int bo = it * (NT * 16) + tid * 16;
            int row = bo >> 7, kb = bo & 127;
            int kbs = kb ^ ((row & 7) << 4);
            GLOAD16(p.Bt + (size_t)(c0 + row) * p.K + kt * 64 + (kbs >> 1), sb + bo);
        }
    };

    f32x4 acc[MF][NF];
#pragma unroll
    for (int mf = 0; mf < MF; ++mf)
#pragma unroll
        for (int nf = 0; nf < NF; ++nf) acc[mf][nf] = (f32x4){0.f, 0.f, 0.f, 0.f};

    const int nk = p.K >> 6;
    stage(0, 0);
    stage(1, 1);
    int b0 = 0, b1 = 1, b2 = 2;
    for (int kt = 0; kt < nk; ++kt) {
        if (kt < nk - 1) vmwait<LPT>(); else vmwait<0>();
        __builtin_amdgcn_sched_barrier(0);
        __builtin_amdgcn_s_barrier();
        if (kt + 2 < nk) stage(kt + 2, b2);
        const char* s = sm + b0 * (ABY + BBY);
#pragma unroll
        for (int ks = 0; ks < 2; ++ks) {
            const int kb = ks * 64 + ((lane >> 4) << 4);
            s16x8 aF[MF], bF[NF];
#pragma unroll
            for (int mf = 0; mf < MF; ++mf) {
                int rt = (wm * MF + mf) * 16 + (lane & 15);
                aF[mf] = *(const s16x8*)(s + rt * 128 + (kb ^ ((rt & 7) << 4)));
            }
#pragma unroll
            for (int nf = 0; nf < NF; ++nf) {
                int rt = (wn * NF + nf) * 16 + (lane & 15);
                bF[nf] = *(const s16x8*)(s + ABY + rt * 128 + (kb ^ ((rt & 7) << 4)));
            }
#pragma unroll
            for (int mf = 0; mf < MF; ++mf)
#pragma unroll
                for (int nf = 0; nf < NF; ++nf)
                    acc[mf][nf] = __builtin_amdgcn_mfma_f32_16x16x32_bf16(aF[mf], bF[nf], acc[mf][nf], 0, 0, 0);
        }
        int t_ = b0; b0 = b1; b1 = b2; b2 = t_;
    }

    const int lrow4 = (lane >> 4) << 2, lcol = lane & 15;
    if constexpr (EPIa == 8) {
        // requires NF==2: wave (wm,wn) owns one 32-class latent group
        const int lat = (c0 >> 5) + wn;
#pragma unroll
        for (int mf = 0; mf < MF; ++mf) {
#pragma unroll
            for (int j = 0; j < 4; ++j) {
                int r = r0 + (wm * MF + mf) * 16 + lrow4 + j;
                int col0 = c0 + wn * 32 + lcol;
                float v0 = acc[mf][0][j] + p.bias[col0];
                float v1 = acc[mf][1][j] + p.bias[col0 + 16];
                p.Cb[(size_t)r * p.ldc + col0] = f2bfu(v0);
                p.Cb[(size_t)r * p.ldc + col0 + 16] = f2bfu(v1);
                float mv; int mi;
                if (v1 > v0) { mv = v1; mi = lcol + 16; } else { mv = v0; mi = lcol; }
#pragma unroll
                for (int o = 8; o >= 1; o >>= 1) {
                    float ov = __shfl_xor(mv, o, 64);
                    int oi = __shfl_xor(mi, o, 64);
                    if (ov > mv || (ov == mv && oi < mi)) { mv = ov; mi = oi; }
                }
                if (lcol == 0) p.idx[(size_t)r * 32 + lat] = mi;
            }
        }
    } else if constexpr (EPIa == 5) {
        float lsum = 0.f;
#pragma unroll
        for (int mf = 0; mf < MF; ++mf) {
            int rowb = r0 + (wm * MF + mf) * 16 + lrow4;
#pragma unroll
            for (int nf = 0; nf < NF; ++nf) {
                int col = c0 + (wn * NF + nf) * 16 + lcol;
#pragma unroll
                for (int j = 0; j < 4; ++j) {
                    float v = acc[mf][nf][j] + p.bias[col];
                    int R = rowb + j + p.rbase;
                    int tt = R >> 8, b = R & 255;
                    int ch = col >> 9;
                    float z = (p.zs[((size_t)b * 64 + tt + 1) * 2048 + col] - p.zmean[ch]) / p.zstd[ch];
                    float d = v - z;
                    lsum += d * d;
                }
            }
        }
#pragma unroll
        for (int o = 32; o > 0; o >>= 1) lsum += __shfl_down(lsum, o, 64);
        if (lane == 0) ps_[w] = lsum;
        __syncthreads();
        if (tid == 0) {
            double s = 0.0;
#pragma unroll
            for (int i = 0; i < WM * WN; ++i) s += (double)ps_[i];
            atomicAdd(p.accum, s);
        }
    } else {
        if (isA) epiS<EPIa, MF, NF>(p, acc, r0, c0, wm, wn, lrow4, lcol);
        else     epiS<EPIb, MF, NF>(p, acc, r0, c0, wm, wn, lrow4, lcol);
    }
}

// ---------------------------------------------------------------------------
// k_gates: gx (K=1024) + full GRU epilogue; 3-deep pipeline (LPT=5, proven)
// ---------------------------------------------------------------------------
template <bool FIRST>
__global__ __launch_bounds__(256) void k_gates(const u16* __restrict__ X, const u16* __restrict__ WihB,
                                               const float* __restrict__ bih, const float* __restrict__ bhh,
                                               const u16* __restrict__ GHb, float* __restrict__ hf32,
                                               u16* __restrict__ hallT) {
    constexpr int ABY = 64 * 128;       // 8 KB
    constexpr int BTB = 32 * 128;       // 4 KB per gate tile
    constexpr int TSZ = ABY + 3 * BTB;  // 20 KB
    const int tid = threadIdx.x, w = tid >> 6, lane = tid & 63;
    const int bm = blockIdx.x >> 6, bn = blockIdx.x & 63;
    const int r0 = bm * 64, c0 = bn * 32;
    const int wm = w >> 1, wn = w & 1;

    __shared__ __attribute__((aligned(16))) char sm[3 * TSZ];

    auto stage = [&](int kt, int buf) {
        char* s = sm + buf * TSZ;
#pragma unroll
        for (int it = 0; it < 2; ++it) {
            int bo = it * 4096 + tid * 16;
            int row = bo >> 7, kb = bo & 127;
            int kbs = kb ^ ((row & 7) << 4);
            GLOAD16(X + (size_t)(r0 + row) * 1024 + kt * 64 + (kbs >> 1), s + bo);
        }
        char* sb = s + ABY;
#pragma unroll
        for (int g = 0; g < 3; ++g) {
            int bo = tid * 16;
            int row = bo >> 7, kb = bo & 127;
            int kbs = kb ^ ((row & 7) << 4);
            GLOAD16(WihB + (size_t)(g * 2048 + c0 + row) * 1024 + kt * 64 + (kbs >> 1), sb + g * BTB + bo);
        }
    };

    f32x4 acc[3][2];
#pragma unroll
    for (int g = 0; g < 3; ++g)
#pragma unroll
        for (int mf = 0; mf < 2; ++mf) acc[g][mf] = (f32x4){0.f, 0.f, 0.f, 0.f};

    stage(0, 0);
    stage(1, 1);
    int b0 = 0, b1 = 1, b2 = 2;
    for (int kt = 0; kt < 16; ++kt) {
        if (kt < 15) vmwait<5>(); else vmwait<0>();
        __builtin_amdgcn_sched_barrier(0);
        __builtin_amdgcn_s_barrier();
        if (kt + 2 < 16) stage(kt + 2, b2);
        const char* s = sm + b0 * TSZ;
#pragma unroll
        for (int ks = 0; ks < 2; ++ks) {
            const int kb = ks * 64 + ((lane >> 4) << 4);
            s16x8 aF[2], bF[3];
#pragma unroll
            for (int mf = 0; mf < 2; ++mf) {
                int rt = (wm * 2 + mf) * 16 + (lane & 15);
                aF[mf] = *(const s16x8*)(s + rt * 128 + (kb ^ ((rt & 7) << 4)));
            }
#pragma unroll
            for (int g = 0; g < 3; ++g) {
                int rt = wn * 16 + (lane & 15);
                bF[g] = *(const s16x8*)(s + ABY + g * BTB + rt * 128 + (kb ^ ((rt & 7) << 4)));
            }
#pragma unroll
            for (int g = 0; g < 3; ++g)
#pragma unroll
                for (int mf = 0; mf < 2; ++mf)
                    acc[g][mf] = __builtin_amdgcn_mfma_f32_16x16x32_bf16(aF[mf], bF[g], acc[g][mf], 0, 0, 0);
        }
        int t_ = b0; b0 = b1; b1 = b2; b2 = t_;
    }

    const int lrow4 = (lane >> 4) << 2, lcol = lane & 15;
    const int cc = c0 + wn * 16 + lcol;
#pragma unroll
    for (int mf = 0; mf < 2; ++mf) {
        int rr0 = r0 + (wm * 2 + mf) * 16 + lrow4;
#pragma unroll
        for (int j = 0; j < 4; ++j) {
            int rr = rr0 + j;
            float xr = acc[0][mf][j] + bih[cc];
            float xz = acc[1][mf][j] + bih[2048 + cc];
            float xn = acc[2][mf][j] + bih[4096 + cc];
            float hr_, hz_, hn_;
            if (FIRST) { hr_ = bhh[cc]; hz_ = bhh[2048 + cc]; hn_ = bhh[4096 + cc]; }
            else {
                const u16* g = GHb + (size_t)rr * 6144;
                hr_ = bfu2f(g[cc]); hz_ = bfu2f(g[2048 + cc]); hn_ = bfu2f(g[4096 + cc]);
            }
            float r = sigm(xr + hr_);
            float u = sigm(xz + hz_);
            float n = tanhf(xn + r * hn_);
            float hold = FIRST ? 0.f : hf32[(size_t)rr * 2048 + cc];
            float h = (1.f - u) * n + u * hold;
            hf32[(size_t)rr * 2048 + cc] = h;
            hallT[(size_t)rr * 2048 + cc] = f2bfu(h);
        }
    }
}

// ---------------------------------------------------------------------------
// small kernels
// ---------------------------------------------------------------------------
__global__ void k_init(double* acc) { acc[0] = 0.0; acc[1] = 0.0; }

__global__ void k_cast(const float* __restrict__ src, u16* __restrict__ dst, int n4) {
    int i = blockIdx.x * 256 + threadIdx.x;
    if (i >= n4) return;
    f32x4 v = *(const f32x4*)(src + (size_t)i * 4);
    s16x4 o;
    o[0] = (short)f2bfu(v[0]); o[1] = (short)f2bfu(v[1]);
    o[2] = (short)f2bfu(v[2]); o[3] = (short)f2bfu(v[3]);
    *(s16x4*)(dst + (size_t)i * 4) = o;
}

__global__ void k_transpose(const float* __restrict__ src, int sld, u16* __restrict__ dst, int K) {
    __shared__ float tile[32][33];
    int k0 = blockIdx.x * 32, n0 = blockIdx.y * 32;
    for (int r = threadIdx.y; r < 32; r += 8)
        tile[r][threadIdx.x] = src[(size_t)(k0 + r) * sld + n0 + threadIdx.x];
    __syncthreads();
    for (int r = threadIdx.y; r < 32; r += 8)
        dst[(size_t)(n0 + r) * K + k0 + threadIdx.x] = f2bfu(tile[threadIdx.x][r]);
}

__global__ void k_prep(const float* __restrict__ zsp, const float* __restrict__ zm,
                       const float* __restrict__ zsd, u16* __restrict__ flat) {
    size_t i = ((size_t)blockIdx.x * 256 + threadIdx.x) * 4;
    f32x4 v = *(const f32x4*)(zsp + i);
    int ch = ((int)(i >> 9)) & 3;
    float m = zm[ch], s = zsd[ch];
    s16x4 o;
    o[0] = (short)f2bfu((v[0] - m) / s); o[1] = (short)f2bfu((v[1] - m) / s);
    o[2] = (short)f2bfu((v[2] - m) / s); o[3] = (short)f2bfu((v[3] - m) / s);
    *(s16x4*)(flat + i) = o;
}

__global__ __launch_bounds__(256) void k_xpre0(const float* __restrict__ preW, const float* __restrict__ preb,
                                               const float* __restrict__ actions, u16* __restrict__ xout) {
    int b = blockIdx.x, tid = threadIdx.x;
    __shared__ float as[3];
    if (tid < 3) as[tid] = actions[(size_t)b * 64 * 3 + tid];
    __syncthreads();
    for (int j = tid; j < 1024; j += 256) {
        float s = preb[j] + as[0] * preW[1024 * 1024 + j] + as[1] * preW[1025 * 1024 + j] + as[2] * preW[1026 * 1024 + j];
        xout[(b << 10) + j] = f2bfu(eluf(s));
    }
}

// x-gen only (argmax fused into k3's EPI8 epilogue)
__global__ __launch_bounds__(256) void k_xgen(const int* __restrict__ latidx_t,
                                              const u16* __restrict__ PreLatB, const float* __restrict__ preW,
                                              const float* __restrict__ preb,
                                              const float* __restrict__ actions, u16* __restrict__ xout,
                                              int tnext) {
    int b = blockIdx.x, tid = threadIdx.x;
    __shared__ int idxs[32];
    __shared__ float as[3];
    if (tid < 32) idxs[tid] = latidx_t[(b << 5) + tid];
    if (tid >= 64 && tid < 67) as[tid - 64] = actions[((size_t)b * 64 + tnext) * 3 + (tid - 64)];
    __syncthreads();
    const int j4 = tid * 4;
    f32x4 s = *(const f32x4*)(preb + j4);
#pragma unroll
    for (int cc = 0; cc < 3; ++cc) {
        f32x4 wv = *(const f32x4*)(preW + (size_t)(1024 + cc) * 1024 + j4);
        s[0] += as[cc] * wv[0]; s[1] += as[cc] * wv[1];
        s[2] += as[cc] * wv[2]; s[3] += as[cc] * wv[3];
    }
#pragma unroll
    for (int l = 0; l < 32; ++l) {
        s16x4 v = *(const s16x4*)(PreLatB + (size_t)((l << 5) + idxs[l]) * 1024 + j4);
        s[0] += bfu2f((u16)v[0]); s[1] += bfu2f((u16)v[1]);
        s[2] += bfu2f((u16)v[2]); s[3] += bfu2f((u16)v[3]);
    }
    s16x4 o;
    o[0] = (short)f2bfu(eluf(s[0])); o[1] = (short)f2bfu(eluf(s[1]));
    o[2] = (short)f2bfu(eluf(s[2])); o[3] = (short)f2bfu(eluf(s[3]));
    *(s16x4*)(xout + (b << 10) + j4) = o;
}

// batched KL: one block per (t,b) row; reads bf16 post/prior logits
__global__ __launch_bounds__(256) void k_kl(const u16* __restrict__ PoAll, const u16* __restrict__ PrAll,
                                            float* __restrict__ klrow) {
    int m = blockIdx.x, tid = threadIdx.x;
    const u16* Po = PoAll + (size_t)m * 1024;
    const u16* Pr = PrAll + (size_t)m * 1024;
    __shared__ float klpart[32];
    int grp = tid >> 5, c = tid & 31;
#pragma unroll
    for (int it = 0; it < 4; ++it) {
        int l = it * 8 + grp;
        float po = bfu2f(Po[l * 32 + c]);
        float pr = bfu2f(Pr[l * 32 + c]);
        float mv = po, mq = pr;
#pragma unroll
        for (int o = 16; o > 0; o >>= 1) {
            mv = fmaxf(mv, __shfl_xor(mv, o, 32));
            mq = fmaxf(mq, __shfl_xor(mq, o, 32));
        }
        float ep = expf(po - mv), eq = expf(pr - mq);
        float sp = ep, sq = eq;
#pragma unroll
        for (int o = 16; o > 0; o >>= 1) { sp += __shfl_xor(sp, o, 32); sq += __shfl_xor(sq, o, 32); }
        float logp = po - mv - logf(sp);
        float logq = pr - mq - logf(sq);
        float klc = (ep / sp) * (logp - logq);
#pragma unroll
        for (int o = 16; o > 0; o >>= 1) klc += __shfl_xor(klc, o, 32);
        if (c == 0) klpart[l] = klc;
    }
    __syncthreads();
    if (tid == 0) {
        float kl = 0.f;
        for (int l = 0; l < 32; ++l) kl += klpart[l];
        klrow[m] = fmaxf(kl, 1.0f);
    }
}

__global__ __launch_bounds__(256) void k_latsum(const u16* __restrict__ LatB, const float* __restrict__ db1,
                                                const int* __restrict__ latidx_all, u16* __restrict__ latsum) {
    int m = blockIdx.x, tid = threadIdx.x;
    __shared__ int idxs[32];
    if (tid < 32) idxs[tid] = latidx_all[(size_t)m * 32 + tid];
    __syncthreads();
    const int j4 = tid * 4;
    f32x4 s = *(const f32x4*)(db1 + j4);
#pragma unroll
    for (int l = 0; l < 32; ++l) {
        s16x4 v = *(const s16x4*)(LatB + (size_t)((l << 5) + idxs[l]) * 1024 + j4);
        s[0] += bfu2f((u16)v[0]); s[1] += bfu2f((u16)v[1]);
        s[2] += bfu2f((u16)v[2]); s[3] += bfu2f((u16)v[3]);
    }
    s16x4 o;
    o[0] = (short)f2bfu(s[0]); o[1] = (short)f2bfu(s[1]);
    o[2] = (short)f2bfu(s[2]); o[3] = (short)f2bfu(s[3]);
    *(s16x4*)(latsum + (size_t)m * 1024 + j4) = o;
}

// NOTE: MUST be launched with 256 threads (r3-r5 bug: was <<<1,1>>>)
__global__ __launch_bounds__(256) void k_finalize(const double* __restrict__ acc,
                                                  const float* __restrict__ klrow, float* __restrict__ out) {
    __shared__ double ps[256];
    int tid = threadIdx.x;
    double s = 0.0;
    for (int i = tid; i < 16128; i += 256) s += (double)klrow[i];
    ps[tid] = s;
    __syncthreads();
    for (int o = 128; o > 0; o >>= 1) {
        if (tid < o) ps[tid] += ps[tid + o];
        __syncthreads();
    }
    if (tid == 0) out[0] = (float)(acc[0] / 33030144.0 + ps[0] / 16128.0);
}

// ---------------------------------------------------------------------------
extern "C" void kernel_launch(void* const* d_in, const int* in_sizes, int n_in,
                              void* d_out, int out_size, void* d_ws, size_t ws_size,
                              hipStream_t stream) {
    const float* zs      = (const float*)d_in[0];
    const float* actions = (const float*)d_in[1];
    const float* zmean   = (const float*)d_in[2];
    const float* zstd    = (const float*)d_in[3];
    const float* encW    = (const float*)d_in[4];
    const float* encb    = (const float*)d_in[5];
    const float* preW    = (const float*)d_in[6];
    const float* preb    = (const float*)d_in[7];
    const float* Wih     = (const float*)d_in[8];
    const float* Whh     = (const float*)d_in[9];
    const float* bih     = (const float*)d_in[10];
    const float* bhh     = (const float*)d_in[11];
    const float* tW1     = (const float*)d_in[12];
    const float* tb1     = (const float*)d_in[13];
    const float* tW2     = (const float*)d_in[14];
    const float* tb2     = (const float*)d_in[15];
    const float* rW1     = (const float*)d_in[16];
    const float* rb1     = (const float*)d_in[17];
    const float* rW2     = (const float*)d_in[18];
    const float* rb2     = (const float*)d_in[19];
    const float* dW1     = (const float*)d_in[20];
    const float* db1     = (const float*)d_in[21];
    const float* dW2     = (const float*)d_in[22];
    const float* db2     = (const float*)d_in[23];

    char* W = (char*)d_ws;
    size_t off = 0;
    auto take = [&](size_t b) { char* p = W + off; off += (b + 255) & ~(size_t)255; return p; };

    double* accum  = (double*)take(16);
    u16* encWbt = (u16*)take((size_t)1024 * 2048 * 2);
    u16* WihB   = (u16*)take((size_t)6144 * 1024 * 2);
    u16* WhhB   = (u16*)take((size_t)6144 * 2048 * 2);
    u16* l1B    = (u16*)take((size_t)2048 * 2048 * 2);   // [tW1t | rW1at]
    u16* tW2bt  = (u16*)take((size_t)1024 * 1024 * 2);
    u16* rW2bt  = (u16*)take((size_t)1024 * 1024 * 2);
    u16* rW1bbt = (u16*)take((size_t)1024 * 1024 * 2);
    u16* dW1abt = (u16*)take((size_t)1024 * 2048 * 2);
    u16* dW2bt  = (u16*)take((size_t)2048 * 1024 * 2);
    u16* PreLatB = (u16*)take((size_t)1024 * 1024 * 2);
    u16* LatB    = (u16*)take((size_t)1024 * 1024 * 2);
    u16* Hall   = (u16*)take((size_t)63 * 256 * 2048 * 2);
    int* latidx = (int*)take((size_t)63 * 256 * 32 * 4);
    u16* embR   = (u16*)take((size_t)16384 * 1024 * 2);   // scan emb; then PrAll; then latsum
    u16* enc    = (u16*)take((size_t)16384 * 1024 * 2);   // encoder out; then PoAll
    float* klrow = (float*)take((size_t)16128 * 4);
    u16* GHb    = (u16*)take((size_t)2 * 256 * 6144 * 2);
    float* hf32 = (float*)take((size_t)256 * 2048 * 4);
    u16* x_bf   = (u16*)take((size_t)256 * 1024 * 2);
    u16* p1q1   = (u16*)take((size_t)256 * 1024 * 2);
    char* X     = take((size_t)17825792);                  // 17 MB: flatc/Xp/d1

    u16* flatc = (u16*)X;                                  // 4096 x 2048 per pass
    u16* Xp    = (u16*)X;                                  // 8064 x 1024 per half
    u16* d1    = (u16*)X;                                  // 8064 x 1024 per half
    u16* PoAll = enc;                                      // enc dead after embR GEMM
    u16* PrAll = embR;                                     // embR dead after scan; consumed by k_kl before latsum

    k_init<<<1, 1, 0, stream>>>(accum);

    // weight conversion
    k_cast<<<6144, 256, 0, stream>>>(Wih, WihB, 6291456 / 4);
    k_cast<<<12288, 256, 0, stream>>>(Whh, WhhB, 12582912 / 4);
    k_cast<<<1024, 256, 0, stream>>>(preW, PreLatB, 262144);
    k_cast<<<1024, 256, 0, stream>>>(dW1 + (size_t)2048 * 1024, LatB, 262144);
    k_transpose<<<dim3(64, 32), dim3(32, 8), 0, stream>>>(encW, 1024, encWbt, 2048);
    k_transpose<<<dim3(64, 32), dim3(32, 8), 0, stream>>>(tW1, 1024, l1B, 2048);
    k_transpose<<<dim3(64, 32), dim3(32, 8), 0, stream>>>(rW1, 1024, l1B + (size_t)1024 * 2048, 2048);
    k_transpose<<<dim3(32, 32), dim3(32, 8), 0, stream>>>(tW2, 1024, tW2bt, 1024);
    k_transpose<<<dim3(32, 32), dim3(32, 8), 0, stream>>>(rW2, 1024, rW2bt, 1024);
    k_transpose<<<dim3(32, 32), dim3(32, 8), 0, stream>>>(rW1 + (size_t)2048 * 1024, 1024, rW1bbt, 1024);
    k_transpose<<<dim3(64, 32), dim3(32, 8), 0, stream>>>(dW1, 1024, dW1abt, 2048);
    k_transpose<<<dim3(32, 64), dim3(32, 8), 0, stream>>>(dW2, 2048, dW2bt, 1024);

    // phase 1: encoder (4 passes of 4096 rows, BM=128 swizzled GEMM) + embR
    for (int pass = 0; pass < 4; ++pass) {
        k_prep<<<8192, 256, 0, stream>>>(zs + (size_t)pass * 4096 * 2048, zmean, zstd, flatc);
        GP e{}; e.A = flatc; e.lda = 2048; e.Bt = encWbt; e.Cb = enc + (size_t)pass * 4096 * 1024;
        e.ldc = 1024; e.bias = encb; e.K = 2048; e.gridN = 16;
        gemmS<2, 2, 4, 2, 1, 1><<<dim3(512), 256, 0, stream>>>(e, e, 512);
    }
    {
        GP e{}; e.A = enc; e.lda = 1024; e.Bt = rW1bbt; e.Cb = embR; e.ldc = 1024;
        e.bias = rb1; e.K = 1024; e.gridN = 16;
        gemmS<2, 2, 4, 2, 2, 2><<<dim3(2048), 256, 0, stream>>>(e, e, 2048);
    }

    // phase 2: sequential scan (post-only path; prior deferred)
    k_xpre0<<<256, 256, 0, stream>>>(preW, preb, actions, x_bf);
    for (int t = 0; t < 63; ++t) {
        // k1: gx + GRU -> h_t
        if (t == 0)
            k_gates<true><<<256, 256, 0, stream>>>(x_bf, WihB, bih, bhh, GHb, hf32, Hall);
        else
            k_gates<false><<<256, 256, 0, stream>>>(x_bf, WihB, bih, bhh, GHb + (size_t)(t & 1) * 256 * 6144,
                                                    hf32, Hall + (size_t)t * 256 * 2048);
        // k2: gh(t+1) (bf16, BN=128) || l1-post(t)
        {
            GP pa{}; pa.A = Hall + (size_t)t * 256 * 2048; pa.lda = 2048; pa.Bt = WhhB;
            pa.Cb = GHb + (size_t)((t + 1) & 1) * 256 * 6144; pa.ldc = 6144; pa.bias = bhh;
            pa.K = 2048; pa.gridN = 48;
            GP pb{}; pb.A = Hall + (size_t)t * 256 * 2048; pb.lda = 2048;
            pb.Bt = l1B + (size_t)1024 * 2048; pb.Cb = p1q1; pb.ldc = 1024;
            pb.aux = embR + (size_t)(t + 1) * 1024; pb.auxld = 65536;
            pb.K = 2048; pb.gridN = 8;
            int nA = (t < 62) ? 192 : 0;
            gemmS<2, 2, 2, 4, 7, 4><<<dim3(nA + 32), 256, 0, stream>>>(pa, pb, nA);
        }
        // k3: q-post (BM=32, 128 blocks) -> PoAll[t] + fused argmax -> latidx[t]
        {
            GP q{}; q.A = p1q1; q.lda = 1024; q.Bt = rW2bt; q.ldc = 1024;
            q.Cb = PoAll + (size_t)t * 256 * 1024; q.bias = rb2; q.K = 1024; q.gridN = 16;
            q.idx = latidx + (size_t)t * 256 * 32;
            gemmS<2, 2, 1, 2, 8, 8><<<dim3(128), 256, 0, stream>>>(q, q, 128);
        }
        // k4: next x from latidx
        if (t < 62)
            k_xgen<<<256, 256, 0, stream>>>(latidx + (size_t)t * 256 * 32,
                                            PreLatB, preW, preb, actions, x_bf, t + 1);
    }

    // phase 3a: batched prior (2 halves of 8064 rows, BM=128) + KL
    for (int half = 0; half < 2; ++half) {
        int m0 = half * 8064;
        GP e{}; e.A = Hall + (size_t)m0 * 2048; e.lda = 2048; e.Bt = l1B; e.Cb = Xp; e.ldc = 1024;
        e.bias = tb1; e.K = 2048; e.gridN = 16;
        gemmS<2, 2, 4, 2, 1, 1><<<dim3(1008), 256, 0, stream>>>(e, e, 1008);
        GP q{}; q.A = Xp; q.lda = 1024; q.Bt = tW2bt; q.Cb = PrAll + (size_t)m0 * 1024; q.ldc = 1024;
        q.bias = tb2; q.K = 1024; q.gridN = 16;
        gemmS<2, 2, 4, 2, 2, 2><<<dim3(1008), 256, 0, stream>>>(q, q, 1008);
    }
    k_kl<<<16128, 256, 0, stream>>>(PoAll, PrAll, klrow);

    // phase 3b: decoder + fused recon (2 halves, BM=128; latsum overwrites embR after k_kl)
    k_latsum<<<16128, 256, 0, stream>>>(LatB, db1, latidx, embR);
    for (int half = 0; half < 2; ++half) {
        int m0 = half * 8064;
        GP d{}; d.A = Hall + (size_t)m0 * 2048; d.lda = 2048; d.Bt = dW1abt; d.Cb = d1; d.ldc = 1024;
        d.aux = embR + (size_t)m0 * 1024; d.auxld = 1024; d.K = 2048; d.gridN = 16;
        gemmS<2, 2, 4, 2, 4, 4><<<dim3(1008), 256, 0, stream>>>(d, d, 1008);
        GP d2{}; d2.A = d1; d2.lda = 1024; d2.Bt = dW2bt; d2.ldc = 2048; d2.bias = db2;
        d2.zs = zs; d2.zmean = zmean; d2.zstd = zstd; d2.accum = accum; d2.K = 1024; d2.gridN = 32;
        d2.rbase = m0;
        gemmS<2, 2, 4, 2, 5, 5><<<dim3(2016), 256, 0, stream>>>(d2, d2, 2016);
    }
    k_finalize<<<1, 256, 0, stream>>>(accum, klrow, (float*)d_out);
}

// Round 9
// 3501.068 us; speedup vs baseline: 1.0676x; 1.0676x over previous
//
#include <hip/hip_runtime.h>
#include <hip/hip_bf16.h>
#include <math.h>

typedef unsigned short u16;
typedef __attribute__((ext_vector_type(8))) short s16x8;
typedef __attribute__((ext_vector_type(4))) short s16x4;
typedef __attribute__((ext_vector_type(4))) float f32x4;

#define DEVI static __device__ __forceinline__

DEVI u16 f2bfu(float f) {
    unsigned u = __float_as_uint(f);
    unsigned r = (u + 0x7fffu + ((u >> 16) & 1u)) >> 16;
    return (u16)r;
}
DEVI float bfu2f(u16 u) { return __uint_as_float(((unsigned)u) << 16); }
DEVI float eluf(float x) { return x > 0.f ? x : (expf(x) - 1.f); }
DEVI float sigm(float x) { return 1.f / (1.f + expf(-x)); }

#define GLOAD16(gsrc, ldst)                                                            \
    __builtin_amdgcn_global_load_lds(                                                  \
        (__attribute__((address_space(1))) void*)(void*)(gsrc),                        \
        (__attribute__((address_space(3))) void*)(ldst), 16, 0, 0)

template <int N> DEVI void vmwait();
template <> DEVI void vmwait<0>() { asm volatile("s_waitcnt vmcnt(0)" ::: "memory"); }
template <> DEVI void vmwait<3>() { asm volatile("s_waitcnt vmcnt(3)" ::: "memory"); }
template <> DEVI void vmwait<4>() { asm volatile("s_waitcnt vmcnt(4)" ::: "memory"); }
template <> DEVI void vmwait<5>() { asm volatile("s_waitcnt vmcnt(5)" ::: "memory"); }
template <> DEVI void vmwait<6>() { asm volatile("s_waitcnt vmcnt(6)" ::: "memory"); }

struct GP {
    const u16* A; int lda;
    const u16* Bt;
    float* Cf; u16* Cb; int ldc;
    const float* bias;
    const u16* aux; int auxld;
    const float* zs;               // EPI5
    const float* zmean; const float* zstd;
    double* accum;
    int* idx;                      // EPI8: argmax out
    int K; int gridN; int rbase;
};

// ---------------------------------------------------------------------------
// gemmS: BK=64, T2 XOR-swizzle, 3-deep counted-vmcnt pipeline. The only GEMM.
// Scan regime lesson (r8): these launches are occupancy-bound — keep
// block count >= 256 (>=1/CU); BM=BN=64 (48KB LDS, 3 blocks/CU) is the
// proven sweet spot.
// ---------------------------------------------------------------------------
template <int EPI, int MF, int NF>
DEVI void epiS(const GP& p, f32x4 (&acc)[MF][NF], int r0, int c0, int wm, int wn,
               int lrow4, int lcol) {
#pragma unroll
    for (int mf = 0; mf < MF; ++mf) {
        int rowb = r0 + (wm * MF + mf) * 16 + lrow4;
#pragma unroll
        for (int nf = 0; nf < NF; ++nf) {
            int col = c0 + (wn * NF + nf) * 16 + lcol;
#pragma unroll
            for (int j = 0; j < 4; ++j) {
                float v = acc[mf][nf][j];
                int r = rowb + j;
                if constexpr (EPI == 1) {
                    p.Cb[(size_t)r * p.ldc + col] = f2bfu(eluf(v + p.bias[col]));
                } else if constexpr (EPI == 2) {
                    p.Cb[(size_t)r * p.ldc + col] = f2bfu(v + p.bias[col]);
                } else if constexpr (EPI == 4) {
                    p.Cb[(size_t)r * p.ldc + col] = f2bfu(eluf(v + bfu2f(p.aux[(size_t)r * p.auxld + col])));
                } else if constexpr (EPI == 7) {
                    p.Cb[(size_t)r * p.ldc + col] = f2bfu(v + p.bias[col]);
                }
            }
        }
    }
}

template <int WM, int WN, int MF, int NF, int EPIa, int EPIb>
__global__ __launch_bounds__(WM * WN * 64) void gemmS(GP pa, GP pb, int nA) {
    constexpr int NT = WM * WN * 64;
    constexpr int BM = WM * MF * 16, BN = WN * NF * 16;
    constexpr int ABY = BM * 128, BBY = BN * 128;
    constexpr int LPT = (ABY + BBY) / (NT * 16);

    const int tid = threadIdx.x, w = tid >> 6, lane = tid & 63;
    const bool isA = (int)blockIdx.x < nA;
    GP p = isA ? pa : pb;
    const int bid = isA ? blockIdx.x : blockIdx.x - nA;
    const int bn = bid % p.gridN, bm = bid / p.gridN;
    const int r0 = bm * BM, c0 = bn * BN;
    const int wm = w / WN, wn = w % WN;

    __shared__ __attribute__((aligned(16))) char sm[3 * (ABY + BBY)];
    __shared__ float ps_[WM * WN];

    auto stage = [&](int kt, int buf) {
        char* s = sm + buf * (ABY + BBY);
#pragma unroll
        for (int it = 0; it < ABY / (NT * 16); ++it) {
            int bo = it * (NT * 16) + tid * 16;
            int row = bo >> 7, kb = bo & 127;
            int kbs = kb ^ ((row & 7) << 4);                       // pre-swizzled source
            GLOAD16(p.A + (size_t)(r0 + row) * p.lda + kt * 64 + (kbs >> 1), s + bo);
        }
        char* sb = s + ABY;
#pragma unroll
        for (int it = 0; it < BBY / (NT * 16); ++it) {
            int bo = it * (NT * 16) + tid * 16;
            int row = bo >> 7, kb = bo & 127;
            int kbs = kb ^ ((row & 7) << 4);
            GLOAD16(p.Bt + (size_t)(c0 + row) * p.K + kt * 64 + (kbs >> 1), sb + bo);
        }
    };

    f32x4 acc[MF][NF];
#pragma unroll
    for (int mf = 0; mf < MF; ++mf)
#pragma unroll
        for (int nf = 0; nf < NF; ++nf) acc[mf][nf] = (f32x4){0.f, 0.f, 0.f, 0.f};

    const int nk = p.K >> 6;
    stage(0, 0);
    stage(1, 1);
    int b0 = 0, b1 = 1, b2 = 2;
    for (int kt = 0; kt < nk; ++kt) {
        if (kt < nk - 1) vmwait<LPT>(); else vmwait<0>();
        __builtin_amdgcn_sched_barrier(0);
        __builtin_amdgcn_s_barrier();
        if (kt + 2 < nk) stage(kt + 2, b2);
        const char* s = sm + b0 * (ABY + BBY);
#pragma unroll
        for (int ks = 0; ks < 2; ++ks) {
            const int kb = ks * 64 + ((lane >> 4) << 4);
            s16x8 aF[MF], bF[NF];
#pragma unroll
            for (int mf = 0; mf < MF; ++mf) {
                int rt = (wm * MF + mf) * 16 + (lane & 15);
                aF[mf] = *(const s16x8*)(s + rt * 128 + (kb ^ ((rt & 7) << 4)));
            }
#pragma unroll
            for (int nf = 0; nf < NF; ++nf) {
                int rt = (wn * NF + nf) * 16 + (lane & 15);
                bF[nf] = *(const s16x8*)(s + ABY + rt * 128 + (kb ^ ((rt & 7) << 4)));
            }
#pragma unroll
            for (int mf = 0; mf < MF; ++mf)
#pragma unroll
                for (int nf = 0; nf < NF; ++nf)
                    acc[mf][nf] = __builtin_amdgcn_mfma_f32_16x16x32_bf16(aF[mf], bF[nf], acc[mf][nf], 0, 0, 0);
        }
        int t_ = b0; b0 = b1; b1 = b2; b2 = t_;
    }

    const int lrow4 = (lane >> 4) << 2, lcol = lane & 15;
    if constexpr (EPIa == 8) {
        // requires NF==2: wave (wm,wn) owns one 32-class latent group
        const int lat = (c0 >> 5) + wn;
#pragma unroll
        for (int mf = 0; mf < MF; ++mf) {
#pragma unroll
            for (int j = 0; j < 4; ++j) {
                int r = r0 + (wm * MF + mf) * 16 + lrow4 + j;
                int col0 = c0 + wn * 32 + lcol;
                float v0 = acc[mf][0][j] + p.bias[col0];
                float v1 = acc[mf][1][j] + p.bias[col0 + 16];
                p.Cb[(size_t)r * p.ldc + col0] = f2bfu(v0);
                p.Cb[(size_t)r * p.ldc + col0 + 16] = f2bfu(v1);
                float mv; int mi;
                if (v1 > v0) { mv = v1; mi = lcol + 16; } else { mv = v0; mi = lcol; }
#pragma unroll
                for (int o = 8; o >= 1; o >>= 1) {
                    float ov = __shfl_xor(mv, o, 64);
                    int oi = __shfl_xor(mi, o, 64);
                    if (ov > mv || (ov == mv && oi < mi)) { mv = ov; mi = oi; }
                }
                if (lcol == 0) p.idx[(size_t)r * 32 + lat] = mi;
            }
        }
    } else if constexpr (EPIa == 5) {
        float lsum = 0.f;
#pragma unroll
        for (int mf = 0; mf < MF; ++mf) {
            int rowb = r0 + (wm * MF + mf) * 16 + lrow4;
#pragma unroll
            for (int nf = 0; nf < NF; ++nf) {
                int col = c0 + (wn * NF + nf) * 16 + lcol;
#pragma unroll
                for (int j = 0; j < 4; ++j) {
                    float v = acc[mf][nf][j] + p.bias[col];
                    int R = rowb + j + p.rbase;
                    int tt = R >> 8, b = R & 255;
                    int ch = col >> 9;
                    float z = (p.zs[((size_t)b * 64 + tt + 1) * 2048 + col] - p.zmean[ch]) / p.zstd[ch];
                    float d = v - z;
                    lsum += d * d;
                }
            }
        }
#pragma unroll
        for (int o = 32; o > 0; o >>= 1) lsum += __shfl_down(lsum, o, 64);
        if (lane == 0) ps_[w] = lsum;
        __syncthreads();
        if (tid == 0) {
            double s = 0.0;
#pragma unroll
            for (int i = 0; i < WM * WN; ++i) s += (double)ps_[i];
            atomicAdd(p.accum, s);
        }
    } else {
        if (isA) epiS<EPIa, MF, NF>(p, acc, r0, c0, wm, wn, lrow4, lcol);
        else     epiS<EPIb, MF, NF>(p, acc, r0, c0, wm, wn, lrow4, lcol);
    }
}

// ---------------------------------------------------------------------------
// k_gates: gx (K=1024) + full GRU epilogue; 3-deep pipeline (LPT=5, proven)
// ---------------------------------------------------------------------------
template <bool FIRST>
__global__ __launch_bounds__(256) void k_gates(const u16* __restrict__ X, const u16* __restrict__ WihB,
                                               const float* __restrict__ bih, const float* __restrict__ bhh,
                                               const u16* __restrict__ GHb, float* __restrict__ hf32,
                                               u16* __restrict__ hallT) {
    constexpr int ABY = 64 * 128;       // 8 KB
    constexpr int BTB = 32 * 128;       // 4 KB per gate tile
    constexpr int TSZ = ABY + 3 * BTB;  // 20 KB
    const int tid = threadIdx.x, w = tid >> 6, lane = tid & 63;
    const int bm = blockIdx.x >> 6, bn = blockIdx.x & 63;
    const int r0 = bm * 64, c0 = bn * 32;
    const int wm = w >> 1, wn = w & 1;

    __shared__ __attribute__((aligned(16))) char sm[3 * TSZ];

    auto stage = [&](int kt, int buf) {
        char* s = sm + buf * TSZ;
#pragma unroll
        for (int it = 0; it < 2; ++it) {
            int bo = it * 4096 + tid * 16;
            int row = bo >> 7, kb = bo & 127;
            int kbs = kb ^ ((row & 7) << 4);
            GLOAD16(X + (size_t)(r0 + row) * 1024 + kt * 64 + (kbs >> 1), s + bo);
        }
        char* sb = s + ABY;
#pragma unroll
        for (int g = 0; g < 3; ++g) {
            int bo = tid * 16;
            int row = bo >> 7, kb = bo & 127;
            int kbs = kb ^ ((row & 7) << 4);
            GLOAD16(WihB + (size_t)(g * 2048 + c0 + row) * 1024 + kt * 64 + (kbs >> 1), sb + g * BTB + bo);
        }
    };

    f32x4 acc[3][2];
#pragma unroll
    for (int g = 0; g < 3; ++g)
#pragma unroll
        for (int mf = 0; mf < 2; ++mf) acc[g][mf] = (f32x4){0.f, 0.f, 0.f, 0.f};

    stage(0, 0);
    stage(1, 1);
    int b0 = 0, b1 = 1, b2 = 2;
    for (int kt = 0; kt < 16; ++kt) {
        if (kt < 15) vmwait<5>(); else vmwait<0>();
        __builtin_amdgcn_sched_barrier(0);
        __builtin_amdgcn_s_barrier();
        if (kt + 2 < 16) stage(kt + 2, b2);
        const char* s = sm + b0 * TSZ;
#pragma unroll
        for (int ks = 0; ks < 2; ++ks) {
            const int kb = ks * 64 + ((lane >> 4) << 4);
            s16x8 aF[2], bF[3];
#pragma unroll
            for (int mf = 0; mf < 2; ++mf) {
                int rt = (wm * 2 + mf) * 16 + (lane & 15);
                aF[mf] = *(const s16x8*)(s + rt * 128 + (kb ^ ((rt & 7) << 4)));
            }
#pragma unroll
            for (int g = 0; g < 3; ++g) {
                int rt = wn * 16 + (lane & 15);
                bF[g] = *(const s16x8*)(s + ABY + g * BTB + rt * 128 + (kb ^ ((rt & 7) << 4)));
            }
#pragma unroll
            for (int g = 0; g < 3; ++g)
#pragma unroll
                for (int mf = 0; mf < 2; ++mf)
                    acc[g][mf] = __builtin_amdgcn_mfma_f32_16x16x32_bf16(aF[mf], bF[g], acc[g][mf], 0, 0, 0);
        }
        int t_ = b0; b0 = b1; b1 = b2; b2 = t_;
    }

    const int lrow4 = (lane >> 4) << 2, lcol = lane & 15;
    const int cc = c0 + wn * 16 + lcol;
#pragma unroll
    for (int mf = 0; mf < 2; ++mf) {
        int rr0 = r0 + (wm * 2 + mf) * 16 + lrow4;
#pragma unroll
        for (int j = 0; j < 4; ++j) {
            int rr = rr0 + j;
            float xr = acc[0][mf][j] + bih[cc];
            float xz = acc[1][mf][j] + bih[2048 + cc];
            float xn = acc[2][mf][j] + bih[4096 + cc];
            float hr_, hz_, hn_;
            if (FIRST) { hr_ = bhh[cc]; hz_ = bhh[2048 + cc]; hn_ = bhh[4096 + cc]; }
            else {
                const u16* g = GHb + (size_t)rr * 6144;
                hr_ = bfu2f(g[cc]); hz_ = bfu2f(g[2048 + cc]); hn_ = bfu2f(g[4096 + cc]);
            }
            float r = sigm(xr + hr_);
            float u = sigm(xz + hz_);
            float n = tanhf(xn + r * hn_);
            float hold = FIRST ? 0.f : hf32[(size_t)rr * 2048 + cc];
            float h = (1.f - u) * n + u * hold;
            hf32[(size_t)rr * 2048 + cc] = h;
            hallT[(size_t)rr * 2048 + cc] = f2bfu(h);
        }
    }
}

// ---------------------------------------------------------------------------
// small kernels
// ---------------------------------------------------------------------------
__global__ void k_init(double* acc) { acc[0] = 0.0; acc[1] = 0.0; }

__global__ void k_cast(const float* __restrict__ src, u16* __restrict__ dst, int n4) {
    int i = blockIdx.x * 256 + threadIdx.x;
    if (i >= n4) return;
    f32x4 v = *(const f32x4*)(src + (size_t)i * 4);
    s16x4 o;
    o[0] = (short)f2bfu(v[0]); o[1] = (short)f2bfu(v[1]);
    o[2] = (short)f2bfu(v[2]); o[3] = (short)f2bfu(v[3]);
    *(s16x4*)(dst + (size_t)i * 4) = o;
}

__global__ void k_transpose(const float* __restrict__ src, int sld, u16* __restrict__ dst, int K) {
    __shared__ float tile[32][33];
    int k0 = blockIdx.x * 32, n0 = blockIdx.y * 32;
    for (int r = threadIdx.y; r < 32; r += 8)
        tile[r][threadIdx.x] = src[(size_t)(k0 + r) * sld + n0 + threadIdx.x];
    __syncthreads();
    for (int r = threadIdx.y; r < 32; r += 8)
        dst[(size_t)(n0 + r) * K + k0 + threadIdx.x] = f2bfu(tile[threadIdx.x][r]);
}

__global__ void k_prep(const float* __restrict__ zsp, const float* __restrict__ zm,
                       const float* __restrict__ zsd, u16* __restrict__ flat) {
    size_t i = ((size_t)blockIdx.x * 256 + threadIdx.x) * 4;
    f32x4 v = *(const f32x4*)(zsp + i);
    int ch = ((int)(i >> 9)) & 3;
    float m = zm[ch], s = zsd[ch];
    s16x4 o;
    o[0] = (short)f2bfu((v[0] - m) / s); o[1] = (short)f2bfu((v[1] - m) / s);
    o[2] = (short)f2bfu((v[2] - m) / s); o[3] = (short)f2bfu((v[3] - m) / s);
    *(s16x4*)(flat + i) = o;
}

__global__ __launch_bounds__(256) void k_xpre0(const float* __restrict__ preW, const float* __restrict__ preb,
                                               const float* __restrict__ actions, u16* __restrict__ xout) {
    int b = blockIdx.x, tid = threadIdx.x;
    __shared__ float as[3];
    if (tid < 3) as[tid] = actions[(size_t)b * 64 * 3 + tid];
    __syncthreads();
    for (int j = tid; j < 1024; j += 256) {
        float s = preb[j] + as[0] * preW[1024 * 1024 + j] + as[1] * preW[1025 * 1024 + j] + as[2] * preW[1026 * 1024 + j];
        xout[(b << 10) + j] = f2bfu(eluf(s));
    }
}

// x-gen only (argmax fused into k3's EPI8 epilogue)
__global__ __launch_bounds__(256) void k_xgen(const int* __restrict__ latidx_t,
                                              const u16* __restrict__ PreLatB, const float* __restrict__ preW,
                                              const float* __restrict__ preb,
                                              const float* __restrict__ actions, u16* __restrict__ xout,
                                              int tnext) {
    int b = blockIdx.x, tid = threadIdx.x;
    __shared__ int idxs[32];
    __shared__ float as[3];
    if (tid < 32) idxs[tid] = latidx_t[(b << 5) + tid];
    if (tid >= 64 && tid < 67) as[tid - 64] = actions[((size_t)b * 64 + tnext) * 3 + (tid - 64)];
    __syncthreads();
    const int j4 = tid * 4;
    f32x4 s = *(const f32x4*)(preb + j4);
#pragma unroll
    for (int cc = 0; cc < 3; ++cc) {
        f32x4 wv = *(const f32x4*)(preW + (size_t)(1024 + cc) * 1024 + j4);
        s[0] += as[cc] * wv[0]; s[1] += as[cc] * wv[1];
        s[2] += as[cc] * wv[2]; s[3] += as[cc] * wv[3];
    }
#pragma unroll
    for (int l = 0; l < 32; ++l) {
        s16x4 v = *(const s16x4*)(PreLatB + (size_t)((l << 5) + idxs[l]) * 1024 + j4);
        s[0] += bfu2f((u16)v[0]); s[1] += bfu2f((u16)v[1]);
        s[2] += bfu2f((u16)v[2]); s[3] += bfu2f((u16)v[3]);
    }
    s16x4 o;
    o[0] = (short)f2bfu(eluf(s[0])); o[1] = (short)f2bfu(eluf(s[1]));
    o[2] = (short)f2bfu(eluf(s[2])); o[3] = (short)f2bfu(eluf(s[3]));
    *(s16x4*)(xout + (b << 10) + j4) = o;
}

// batched KL: one block per (t,b) row; reads bf16 post/prior logits
__global__ __launch_bounds__(256) void k_kl(const u16* __restrict__ PoAll, const u16* __restrict__ PrAll,
                                            float* __restrict__ klrow) {
    int m = blockIdx.x, tid = threadIdx.x;
    const u16* Po = PoAll + (size_t)m * 1024;
    const u16* Pr = PrAll + (size_t)m * 1024;
    __shared__ float klpart[32];
    int grp = tid >> 5, c = tid & 31;
#pragma unroll
    for (int it = 0; it < 4; ++it) {
        int l = it * 8 + grp;
        float po = bfu2f(Po[l * 32 + c]);
        float pr = bfu2f(Pr[l * 32 + c]);
        float mv = po, mq = pr;
#pragma unroll
        for (int o = 16; o > 0; o >>= 1) {
            mv = fmaxf(mv, __shfl_xor(mv, o, 32));
            mq = fmaxf(mq, __shfl_xor(mq, o, 32));
        }
        float ep = expf(po - mv), eq = expf(pr - mq);
        float sp = ep, sq = eq;
#pragma unroll
        for (int o = 16; o > 0; o >>= 1) { sp += __shfl_xor(sp, o, 32); sq += __shfl_xor(sq, o, 32); }
        float logp = po - mv - logf(sp);
        float logq = pr - mq - logf(sq);
        float klc = (ep / sp) * (logp - logq);
#pragma unroll
        for (int o = 16; o > 0; o >>= 1) klc += __shfl_xor(klc, o, 32);
        if (c == 0) klpart[l] = klc;
    }
    __syncthreads();
    if (tid == 0) {
        float kl = 0.f;
        for (int l = 0; l < 32; ++l) kl += klpart[l];
        klrow[m] = fmaxf(kl, 1.0f);
    }
}

__global__ __launch_bounds__(256) void k_latsum(const u16* __restrict__ LatB, const float* __restrict__ db1,
                                                const int* __restrict__ latidx_all, u16* __restrict__ latsum) {
    int m = blockIdx.x, tid = threadIdx.x;
    __shared__ int idxs[32];
    if (tid < 32) idxs[tid] = latidx_all[(size_t)m * 32 + tid];
    __syncthreads();
    const int j4 = tid * 4;
    f32x4 s = *(const f32x4*)(db1 + j4);
#pragma unroll
    for (int l = 0; l < 32; ++l) {
        s16x4 v = *(const s16x4*)(LatB + (size_t)((l << 5) + idxs[l]) * 1024 + j4);
        s[0] += bfu2f((u16)v[0]); s[1] += bfu2f((u16)v[1]);
        s[2] += bfu2f((u16)v[2]); s[3] += bfu2f((u16)v[3]);
    }
    s16x4 o;
    o[0] = (short)f2bfu(s[0]); o[1] = (short)f2bfu(s[1]);
    o[2] = (short)f2bfu(s[2]); o[3] = (short)f2bfu(s[3]);
    *(s16x4*)(latsum + (size_t)m * 1024 + j4) = o;
}

// NOTE: MUST be launched with 256 threads (r3-r5 bug: was <<<1,1>>>)
__global__ __launch_bounds__(256) void k_finalize(const double* __restrict__ acc,
                                                  const float* __restrict__ klrow, float* __restrict__ out) {
    __shared__ double ps[256];
    int tid = threadIdx.x;
    double s = 0.0;
    for (int i = tid; i < 16128; i += 256) s += (double)klrow[i];
    ps[tid] = s;
    __syncthreads();
    for (int o = 128; o > 0; o >>= 1) {
        if (tid < o) ps[tid] += ps[tid + o];
        __syncthreads();
    }
    if (tid == 0) out[0] = (float)(acc[0] / 33030144.0 + ps[0] / 16128.0);
}

// ---------------------------------------------------------------------------
extern "C" void kernel_launch(void* const* d_in, const int* in_sizes, int n_in,
                              void* d_out, int out_size, void* d_ws, size_t ws_size,
                              hipStream_t stream) {
    const float* zs      = (const float*)d_in[0];
    const float* actions = (const float*)d_in[1];
    const float* zmean   = (const float*)d_in[2];
    const float* zstd    = (const float*)d_in[3];
    const float* encW    = (const float*)d_in[4];
    const float* encb    = (const float*)d_in[5];
    const float* preW    = (const float*)d_in[6];
    const float* preb    = (const float*)d_in[7];
    const float* Wih     = (const float*)d_in[8];
    const float* Whh     = (const float*)d_in[9];
    const float* bih     = (const float*)d_in[10];
    const float* bhh     = (const float*)d_in[11];
    const float* tW1     = (const float*)d_in[12];
    const float* tb1     = (const float*)d_in[13];
    const float* tW2     = (const float*)d_in[14];
    const float* tb2     = (const float*)d_in[15];
    const float* rW1     = (const float*)d_in[16];
    const float* rb1     = (const float*)d_in[17];
    const float* rW2     = (const float*)d_in[18];
    const float* rb2     = (const float*)d_in[19];
    const float* dW1     = (const float*)d_in[20];
    const float* db1     = (const float*)d_in[21];
    const float* dW2     = (const float*)d_in[22];
    const float* db2     = (const float*)d_in[23];

    char* W = (char*)d_ws;
    size_t off = 0;
    auto take = [&](size_t b) { char* p = W + off; off += (b + 255) & ~(size_t)255; return p; };

    double* accum  = (double*)take(16);
    u16* encWbt = (u16*)take((size_t)1024 * 2048 * 2);
    u16* WihB   = (u16*)take((size_t)6144 * 1024 * 2);
    u16* WhhB   = (u16*)take((size_t)6144 * 2048 * 2);
    u16* l1B    = (u16*)take((size_t)2048 * 2048 * 2);   // [tW1t | rW1at]
    u16* tW2bt  = (u16*)take((size_t)1024 * 1024 * 2);
    u16* rW2bt  = (u16*)take((size_t)1024 * 1024 * 2);
    u16* rW1bbt = (u16*)take((size_t)1024 * 1024 * 2);
    u16* dW1abt = (u16*)take((size_t)1024 * 2048 * 2);
    u16* dW2bt  = (u16*)take((size_t)2048 * 1024 * 2);
    u16* PreLatB = (u16*)take((size_t)1024 * 1024 * 2);
    u16* LatB    = (u16*)take((size_t)1024 * 1024 * 2);
    u16* Hall   = (u16*)take((size_t)63 * 256 * 2048 * 2);
    int* latidx = (int*)take((size_t)63 * 256 * 32 * 4);
    u16* embR   = (u16*)take((size_t)16384 * 1024 * 2);   // scan emb; then PrAll; then latsum
    u16* enc    = (u16*)take((size_t)16384 * 1024 * 2);   // encoder out; then PoAll
    float* klrow = (float*)take((size_t)16128 * 4);
    u16* GHb    = (u16*)take((size_t)2 * 256 * 6144 * 2);
    float* hf32 = (float*)take((size_t)256 * 2048 * 4);
    u16* x_bf   = (u16*)take((size_t)256 * 1024 * 2);
    u16* p1q1   = (u16*)take((size_t)256 * 1024 * 2);
    char* X     = take((size_t)17825792);                  // 17 MB: flatc/Xp/d1

    u16* flatc = (u16*)X;                                  // 4096 x 2048 per pass
    u16* Xp    = (u16*)X;                                  // 8064 x 1024 per half
    u16* d1    = (u16*)X;                                  // 8064 x 1024 per half
    u16* PoAll = enc;                                      // enc dead after embR GEMM
    u16* PrAll = embR;                                     // embR dead after scan; consumed by k_kl before latsum

    k_init<<<1, 1, 0, stream>>>(accum);

    // weight conversion
    k_cast<<<6144, 256, 0, stream>>>(Wih, WihB, 6291456 / 4);
    k_cast<<<12288, 256, 0, stream>>>(Whh, WhhB, 12582912 / 4);
    k_cast<<<1024, 256, 0, stream>>>(preW, PreLatB, 262144);
    k_cast<<<1024, 256, 0, stream>>>(dW1 + (size_t)2048 * 1024, LatB, 262144);
    k_transpose<<<dim3(64, 32), dim3(32, 8), 0, stream>>>(encW, 1024, encWbt, 2048);
    k_transpose<<<dim3(64, 32), dim3(32, 8), 0, stream>>>(tW1, 1024, l1B, 2048);
    k_transpose<<<dim3(64, 32), dim3(32, 8), 0, stream>>>(rW1, 1024, l1B + (size_t)1024 * 2048, 2048);
    k_transpose<<<dim3(32, 32), dim3(32, 8), 0, stream>>>(tW2, 1024, tW2bt, 1024);
    k_transpose<<<dim3(32, 32), dim3(32, 8), 0, stream>>>(rW2, 1024, rW2bt, 1024);
    k_transpose<<<dim3(32, 32), dim3(32, 8), 0, stream>>>(rW1 + (size_t)2048 * 1024, 1024, rW1bbt, 1024);
    k_transpose<<<dim3(64, 32), dim3(32, 8), 0, stream>>>(dW1, 1024, dW1abt, 2048);
    k_transpose<<<dim3(32, 64), dim3(32, 8), 0, stream>>>(dW2, 2048, dW2bt, 1024);

    // phase 1: encoder (4 passes of 4096 rows; BM=BN=64 gemmS, 1024 blocks/pass)
    for (int pass = 0; pass < 4; ++pass) {
        k_prep<<<8192, 256, 0, stream>>>(zs + (size_t)pass * 4096 * 2048, zmean, zstd, flatc);
        GP e{}; e.A = flatc; e.lda = 2048; e.Bt = encWbt; e.Cb = enc + (size_t)pass * 4096 * 1024;
        e.ldc = 1024; e.bias = encb; e.K = 2048; e.gridN = 16;
        gemmS<2, 2, 2, 2, 1, 1><<<dim3(1024), 256, 0, stream>>>(e, e, 1024);
    }
    {
        GP e{}; e.A = enc; e.lda = 1024; e.Bt = rW1bbt; e.Cb = embR; e.ldc = 1024;
        e.bias = rb1; e.K = 1024; e.gridN = 16;
        gemmS<2, 2, 2, 2, 2, 2><<<dim3(4096), 256, 0, stream>>>(e, e, 4096);
    }

    // phase 2: sequential scan (post-only path; prior deferred) — r7 shapes
    k_xpre0<<<256, 256, 0, stream>>>(preW, preb, actions, x_bf);
    for (int t = 0; t < 63; ++t) {
        // k1: gx + GRU -> h_t
        if (t == 0)
            k_gates<true><<<256, 256, 0, stream>>>(x_bf, WihB, bih, bhh, GHb, hf32, Hall);
        else
            k_gates<false><<<256, 256, 0, stream>>>(x_bf, WihB, bih, bhh, GHb + (size_t)(t & 1) * 256 * 6144,
                                                    hf32, Hall + (size_t)t * 256 * 2048);
        // k2: gh(t+1) (bf16) || l1-post(t) — r7 448-block shape
        {
            GP pa{}; pa.A = Hall + (size_t)t * 256 * 2048; pa.lda = 2048; pa.Bt = WhhB;
            pa.Cb = GHb + (size_t)((t + 1) & 1) * 256 * 6144; pa.ldc = 6144; pa.bias = bhh;
            pa.K = 2048; pa.gridN = 96;
            GP pb{}; pb.A = Hall + (size_t)t * 256 * 2048; pb.lda = 2048;
            pb.Bt = l1B + (size_t)1024 * 2048; pb.Cb = p1q1; pb.ldc = 1024;
            pb.aux = embR + (size_t)(t + 1) * 1024; pb.auxld = 65536;
            pb.K = 2048; pb.gridN = 16;
            int nA = (t < 62) ? 384 : 0;
            gemmS<2, 2, 2, 2, 7, 4><<<dim3(nA + 64), 256, 0, stream>>>(pa, pb, nA);
        }
        // k3: q-post (BM=32, 128 blocks) -> PoAll[t] + fused argmax -> latidx[t]
        {
            GP q{}; q.A = p1q1; q.lda = 1024; q.Bt = rW2bt; q.ldc = 1024;
            q.Cb = PoAll + (size_t)t * 256 * 1024; q.bias = rb2; q.K = 1024; q.gridN = 16;
            q.idx = latidx + (size_t)t * 256 * 32;
            gemmS<2, 2, 1, 2, 8, 8><<<dim3(128), 256, 0, stream>>>(q, q, 128);
        }
        // k4: next x from latidx
        if (t < 62)
            k_xgen<<<256, 256, 0, stream>>>(latidx + (size_t)t * 256 * 32,
                                            PreLatB, preW, preb, actions, x_bf, t + 1);
    }

    // phase 3a: batched prior (2 halves of 8064 rows; BM=BN=64, 2016 blocks) + KL
    for (int half = 0; half < 2; ++half) {
        int m0 = half * 8064;
        GP e{}; e.A = Hall + (size_t)m0 * 2048; e.lda = 2048; e.Bt = l1B; e.Cb = Xp; e.ldc = 1024;
        e.bias = tb1; e.K = 2048; e.gridN = 16;
        gemmS<2, 2, 2, 2, 1, 1><<<dim3(2016), 256, 0, stream>>>(e, e, 2016);
        GP q{}; q.A = Xp; q.lda = 1024; q.Bt = tW2bt; q.Cb = PrAll + (size_t)m0 * 1024; q.ldc = 1024;
        q.bias = tb2; q.K = 1024; q.gridN = 16;
        gemmS<2, 2, 2, 2, 2, 2><<<dim3(2016), 256, 0, stream>>>(q, q, 2016);
    }
    k_kl<<<16128, 256, 0, stream>>>(PoAll, PrAll, klrow);

    // phase 3b: decoder + fused recon (2 halves; BM=BN=64)
    k_latsum<<<16128, 256, 0, stream>>>(LatB, db1, latidx, embR);
    for (int half = 0; half < 2; ++half) {
        int m0 = half * 8064;
        GP d{}; d.A = Hall + (size_t)m0 * 2048; d.lda = 2048; d.Bt = dW1abt; d.Cb = d1; d.ldc = 1024;
        d.aux = embR + (size_t)m0 * 1024; d.auxld = 1024; d.K = 2048; d.gridN = 16;
        gemmS<2, 2, 2, 2, 4, 4><<<dim3(2016), 256, 0, stream>>>(d, d, 2016);
        GP d2{}; d2.A = d1; d2.lda = 1024; d2.Bt = dW2bt; d2.ldc = 2048; d2.bias = db2;
        d2.zs = zs; d2.zmean = zmean; d2.zstd = zstd; d2.accum = accum; d2.K = 1024; d2.gridN = 32;
        d2.rbase = m0;
        gemmS<2, 2, 2, 2, 5, 5><<<dim3(4032), 256, 0, stream>>>(d2, d2, 4032);
    }
    k_finalize<<<1, 256, 0, stream>>>(accum, klrow, (float*)d_out);
}

// Round 10
// 3399.869 us; speedup vs baseline: 1.0994x; 1.0298x over previous
//
#include <hip/hip_runtime.h>
#include <hip/hip_bf16.h>
#include <math.h>

typedef unsigned short u16;
typedef __attribute__((ext_vector_type(8))) short s16x8;
typedef __attribute__((ext_vector_type(4))) short s16x4;
typedef __attribute__((ext_vector_type(4))) float f32x4;

#define DEVI static __device__ __forceinline__

DEVI u16 f2bfu(float f) {
    unsigned u = __float_as_uint(f);
    unsigned r = (u + 0x7fffu + ((u >> 16) & 1u)) >> 16;
    return (u16)r;
}
DEVI float bfu2f(u16 u) { return __uint_as_float(((unsigned)u) << 16); }
DEVI float eluf(float x) { return x > 0.f ? x : (expf(x) - 1.f); }
DEVI float sigm(float x) { return 1.f / (1.f + expf(-x)); }

#define GLOAD16(gsrc, ldst)                                                            \
    __builtin_amdgcn_global_load_lds(                                                  \
        (__attribute__((address_space(1))) void*)(void*)(gsrc),                        \
        (__attribute__((address_space(3))) void*)(ldst), 16, 0, 0)

template <int N> DEVI void vmwait();
template <> DEVI void vmwait<0>() { asm volatile("s_waitcnt vmcnt(0)" ::: "memory"); }
template <> DEVI void vmwait<1>() { asm volatile("s_waitcnt vmcnt(1)" ::: "memory"); }
template <> DEVI void vmwait<2>() { asm volatile("s_waitcnt vmcnt(2)" ::: "memory"); }
template <> DEVI void vmwait<3>() { asm volatile("s_waitcnt vmcnt(3)" ::: "memory"); }
template <> DEVI void vmwait<4>() { asm volatile("s_waitcnt vmcnt(4)" ::: "memory"); }
template <> DEVI void vmwait<5>() { asm volatile("s_waitcnt vmcnt(5)" ::: "memory"); }
template <> DEVI void vmwait<6>() { asm volatile("s_waitcnt vmcnt(6)" ::: "memory"); }

struct GP {
    const u16* A; int lda;
    const u16* Bt;
    float* Cf; u16* Cb; int ldc;
    const float* bias;
    const u16* aux; int auxld;
    const float* zs;               // EPI5
    const float* zmean; const float* zstd;
    double* accum;
    int* idx;                      // EPI8: argmax out
    int K; int gridN; int rbase;
};

// ---------------------------------------------------------------------------
// gemmS: BK=64, T2 XOR-swizzle, 3-deep counted-vmcnt pipeline. The only GEMM.
// r8/r9 lesson: scan launches are occupancy-bound — block count and waves/CU
// dominate MFMA density. SWZ = T1 XCD-aware tile remap (requires nA%8==0,
// single-problem launches only) for L2 locality on B-panel re-reads.
// ---------------------------------------------------------------------------
template <int EPI, int MF, int NF>
DEVI void epiS(const GP& p, f32x4 (&acc)[MF][NF], int r0, int c0, int wm, int wn,
               int lrow4, int lcol) {
#pragma unroll
    for (int mf = 0; mf < MF; ++mf) {
        int rowb = r0 + (wm * MF + mf) * 16 + lrow4;
#pragma unroll
        for (int nf = 0; nf < NF; ++nf) {
            int col = c0 + (wn * NF + nf) * 16 + lcol;
#pragma unroll
            for (int j = 0; j < 4; ++j) {
                float v = acc[mf][nf][j];
                int r = rowb + j;
                if constexpr (EPI == 1) {
                    p.Cb[(size_t)r * p.ldc + col] = f2bfu(eluf(v + p.bias[col]));
                } else if constexpr (EPI == 2) {
                    p.Cb[(size_t)r * p.ldc + col] = f2bfu(v + p.bias[col]);
                } else if constexpr (EPI == 4) {
                    p.Cb[(size_t)r * p.ldc + col] = f2bfu(eluf(v + bfu2f(p.aux[(size_t)r * p.auxld + col])));
                } else if constexpr (EPI == 7) {
                    p.Cb[(size_t)r * p.ldc + col] = f2bfu(v + p.bias[col]);
                }
            }
        }
    }
}

template <int WM, int WN, int MF, int NF, int EPIa, int EPIb, bool SWZ = false>
__global__ __launch_bounds__(WM * WN * 64) void gemmS(GP pa, GP pb, int nA) {
    constexpr int NT = WM * WN * 64;
    constexpr int BM = WM * MF * 16, BN = WN * NF * 16;
    constexpr int ABY = BM * 128, BBY = BN * 128;
    constexpr int LPT = (ABY + BBY) / (NT * 16);

    const int tid = threadIdx.x, w = tid >> 6, lane = tid & 63;
    const bool isA = (int)blockIdx.x < nA;
    GP p = isA ? pa : pb;
    int bid = isA ? blockIdx.x : blockIdx.x - nA;
    if constexpr (SWZ) bid = (bid & 7) * (nA >> 3) + (bid >> 3);   // T1, needs nA%8==0
    const int bn = bid % p.gridN, bm = bid / p.gridN;
    const int r0 = bm * BM, c0 = bn * BN;
    const int wm = w / WN, wn = w % WN;

    __shared__ __attribute__((aligned(16))) char sm[3 * (ABY + BBY)];
    __shared__ float ps_[WM * WN];

    auto stage = [&](int kt, int buf) {
        char* s = sm + buf * (ABY + BBY);
#pragma unroll
        for (int it = 0; it < ABY / (NT * 16); ++it) {
            int bo = it * (NT * 16) + tid * 16;
            int row = bo >> 7, kb = bo & 127;
            int kbs = kb ^ ((row & 7) << 4);                       // pre-swizzled source
            GLOAD16(p.A + (size_t)(r0 + row) * p.lda + kt * 64 + (kbs >> 1), s + bo);
        }
        char* sb = s + ABY;
#pragma unroll
        for (int it = 0; it < BBY / (NT * 16); ++it) {
            int bo = it * (NT * 16) + tid * 16;
            int row = bo >> 7, kb = bo & 127;
            int kbs = kb ^ ((row & 7) << 4);
            GLOAD16(p.Bt + (size_t)(c0 + row) * p.K + kt * 64 + (kbs >> 1), sb + bo);
        }
    };

    f32x4 acc[MF][NF];
#pragma unroll
    for (int mf = 0; mf < MF; ++mf)
#pragma unroll
        for (int nf = 0; nf < NF; ++nf) acc[mf][nf] = (f32x4){0.f, 0.f, 0.f, 0.f};

    const int nk = p.K >> 6;
    stage(0, 0);
    stage(1, 1);
    int b0 = 0, b1 = 1, b2 = 2;
    for (int kt = 0; kt < nk; ++kt) {
        if (kt < nk - 1) vmwait<LPT>(); else vmwait<0>();
        __builtin_amdgcn_sched_barrier(0);
        __builtin_amdgcn_s_barrier();
        if (kt + 2 < nk) stage(kt + 2, b2);
        const char* s = sm + b0 * (ABY + BBY);
#pragma unroll
        for (int ks = 0; ks < 2; ++ks) {
            const int kb = ks * 64 + ((lane >> 4) << 4);
            s16x8 aF[MF], bF[NF];
#pragma unroll
            for (int mf = 0; mf < MF; ++mf) {
                int rt = (wm * MF + mf) * 16 + (lane & 15);
                aF[mf] = *(const s16x8*)(s + rt * 128 + (kb ^ ((rt & 7) << 4)));
            }
#pragma unroll
            for (int nf = 0; nf < NF; ++nf) {
                int rt = (wn * NF + nf) * 16 + (lane & 15);
                bF[nf] = *(const s16x8*)(s + ABY + rt * 128 + (kb ^ ((rt & 7) << 4)));
            }
#pragma unroll
            for (int mf = 0; mf < MF; ++mf)
#pragma unroll
                for (int nf = 0; nf < NF; ++nf)
                    acc[mf][nf] = __builtin_amdgcn_mfma_f32_16x16x32_bf16(aF[mf], bF[nf], acc[mf][nf], 0, 0, 0);
        }
        int t_ = b0; b0 = b1; b1 = b2; b2 = t_;
    }

    const int lrow4 = (lane >> 4) << 2, lcol = lane & 15;
    if constexpr (EPIa == 8) {
        // requires NF==2: wave (wm,wn) owns one 32-class latent group
        const int lat = (c0 >> 5) + wn;
#pragma unroll
        for (int mf = 0; mf < MF; ++mf) {
#pragma unroll
            for (int j = 0; j < 4; ++j) {
                int r = r0 + (wm * MF + mf) * 16 + lrow4 + j;
                int col0 = c0 + wn * 32 + lcol;
                float v0 = acc[mf][0][j] + p.bias[col0];
                float v1 = acc[mf][1][j] + p.bias[col0 + 16];
                p.Cb[(size_t)r * p.ldc + col0] = f2bfu(v0);
                p.Cb[(size_t)r * p.ldc + col0 + 16] = f2bfu(v1);
                float mv; int mi;
                if (v1 > v0) { mv = v1; mi = lcol + 16; } else { mv = v0; mi = lcol; }
#pragma unroll
                for (int o = 8; o >= 1; o >>= 1) {
                    float ov = __shfl_xor(mv, o, 64);
                    int oi = __shfl_xor(mi, o, 64);
                    if (ov > mv || (ov == mv && oi < mi)) { mv = ov; mi = oi; }
                }
                if (lcol == 0) p.idx[(size_t)r * 32 + lat] = mi;
            }
        }
    } else if constexpr (EPIa == 5) {
        float lsum = 0.f;
#pragma unroll
        for (int mf = 0; mf < MF; ++mf) {
            int rowb = r0 + (wm * MF + mf) * 16 + lrow4;
#pragma unroll
            for (int nf = 0; nf < NF; ++nf) {
                int col = c0 + (wn * NF + nf) * 16 + lcol;
#pragma unroll
                for (int j = 0; j < 4; ++j) {
                    float v = acc[mf][nf][j] + p.bias[col];
                    int R = rowb + j + p.rbase;
                    int tt = R >> 8, b = R & 255;
                    int ch = col >> 9;
                    float z = (p.zs[((size_t)b * 64 + tt + 1) * 2048 + col] - p.zmean[ch]) / p.zstd[ch];
                    float d = v - z;
                    lsum += d * d;
                }
            }
        }
#pragma unroll
        for (int o = 32; o > 0; o >>= 1) lsum += __shfl_down(lsum, o, 64);
        if (lane == 0) ps_[w] = lsum;
        __syncthreads();
        if (tid == 0) {
            double s = 0.0;
#pragma unroll
            for (int i = 0; i < WM * WN; ++i) s += (double)ps_[i];
            atomicAdd(p.accum, s);
        }
    } else {
        if (isA) epiS<EPIa, MF, NF>(p, acc, r0, c0, wm, wn, lrow4, lcol);
        else     epiS<EPIb, MF, NF>(p, acc, r0, c0, wm, wn, lrow4, lcol);
    }
}

// ---------------------------------------------------------------------------
// k_gates: gx (K=1024) + full GRU epilogue; 3-deep pipeline (LPT=5, proven)
// ---------------------------------------------------------------------------
template <bool FIRST>
__global__ __launch_bounds__(256) void k_gates(const u16* __restrict__ X, const u16* __restrict__ WihB,
                                               const float* __restrict__ bih, const float* __restrict__ bhh,
                                               const u16* __restrict__ GHb, float* __restrict__ hf32,
                                               u16* __restrict__ hallT) {
    constexpr int ABY = 64 * 128;       // 8 KB
    constexpr int BTB = 32 * 128;       // 4 KB per gate tile
    constexpr int TSZ = ABY + 3 * BTB;  // 20 KB
    const int tid = threadIdx.x, w = tid >> 6, lane = tid & 63;
    const int bm = blockIdx.x >> 6, bn = blockIdx.x & 63;
    const int r0 = bm * 64, c0 = bn * 32;
    const int wm = w >> 1, wn = w & 1;

    __shared__ __attribute__((aligned(16))) char sm[3 * TSZ];

    auto stage = [&](int kt, int buf) {
        char* s = sm + buf * TSZ;
#pragma unroll
        for (int it = 0; it < 2; ++it) {
            int bo = it * 4096 + tid * 16;
            int row = bo >> 7, kb = bo & 127;
            int kbs = kb ^ ((row & 7) << 4);
            GLOAD16(X + (size_t)(r0 + row) * 1024 + kt * 64 + (kbs >> 1), s + bo);
        }
        char* sb = s + ABY;
#pragma unroll
        for (int g = 0; g < 3; ++g) {
            int bo = tid * 16;
            int row = bo >> 7, kb = bo & 127;
            int kbs = kb ^ ((row & 7) << 4);
            GLOAD16(WihB + (size_t)(g * 2048 + c0 + row) * 1024 + kt * 64 + (kbs >> 1), sb + g * BTB + bo);
        }
    };

    f32x4 acc[3][2];
#pragma unroll
    for (int g = 0; g < 3; ++g)
#pragma unroll
        for (int mf = 0; mf < 2; ++mf) acc[g][mf] = (f32x4){0.f, 0.f, 0.f, 0.f};

    stage(0, 0);
    stage(1, 1);
    int b0 = 0, b1 = 1, b2 = 2;
    for (int kt = 0; kt < 16; ++kt) {
        if (kt < 15) vmwait<5>(); else vmwait<0>();
        __builtin_amdgcn_sched_barrier(0);
        __builtin_amdgcn_s_barrier();
        if (kt + 2 < 16) stage(kt + 2, b2);
        const char* s = sm + b0 * TSZ;
#pragma unroll
        for (int ks = 0; ks < 2; ++ks) {
            const int kb = ks * 64 + ((lane >> 4) << 4);
            s16x8 aF[2], bF[3];
#pragma unroll
            for (int mf = 0; mf < 2; ++mf) {
                int rt = (wm * 2 + mf) * 16 + (lane & 15);
                aF[mf] = *(const s16x8*)(s + rt * 128 + (kb ^ ((rt & 7) << 4)));
            }
#pragma unroll
            for (int g = 0; g < 3; ++g) {
                int rt = wn * 16 + (lane & 15);
                bF[g] = *(const s16x8*)(s + ABY + g * BTB + rt * 128 + (kb ^ ((rt & 7) << 4)));
            }
#pragma unroll
            for (int g = 0; g < 3; ++g)
#pragma unroll
                for (int mf = 0; mf < 2; ++mf)
                    acc[g][mf] = __builtin_amdgcn_mfma_f32_16x16x32_bf16(aF[mf], bF[g], acc[g][mf], 0, 0, 0);
        }
        int t_ = b0; b0 = b1; b1 = b2; b2 = t_;
    }

    const int lrow4 = (lane >> 4) << 2, lcol = lane & 15;
    const int cc = c0 + wn * 16 + lcol;
#pragma unroll
    for (int mf = 0; mf < 2; ++mf) {
        int rr0 = r0 + (wm * 2 + mf) * 16 + lrow4;
#pragma unroll
        for (int j = 0; j < 4; ++j) {
            int rr = rr0 + j;
            float xr = acc[0][mf][j] + bih[cc];
            float xz = acc[1][mf][j] + bih[2048 + cc];
            float xn = acc[2][mf][j] + bih[4096 + cc];
            float hr_, hz_, hn_;
            if (FIRST) { hr_ = bhh[cc]; hz_ = bhh[2048 + cc]; hn_ = bhh[4096 + cc]; }
            else {
                const u16* g = GHb + (size_t)rr * 6144;
                hr_ = bfu2f(g[cc]); hz_ = bfu2f(g[2048 + cc]); hn_ = bfu2f(g[4096 + cc]);
            }
            float r = sigm(xr + hr_);
            float u = sigm(xz + hz_);
            float n = tanhf(xn + r * hn_);
            float hold = FIRST ? 0.f : hf32[(size_t)rr * 2048 + cc];
            float h = (1.f - u) * n + u * hold;
            hf32[(size_t)rr * 2048 + cc] = h;
            hallT[(size_t)rr * 2048 + cc] = f2bfu(h);
        }
    }
}

// ---------------------------------------------------------------------------
// small kernels
// ---------------------------------------------------------------------------
__global__ void k_init(double* acc) { acc[0] = 0.0; acc[1] = 0.0; }

__global__ void k_cast(const float* __restrict__ src, u16* __restrict__ dst, int n4) {
    int i = blockIdx.x * 256 + threadIdx.x;
    if (i >= n4) return;
    f32x4 v = *(const f32x4*)(src + (size_t)i * 4);
    s16x4 o;
    o[0] = (short)f2bfu(v[0]); o[1] = (short)f2bfu(v[1]);
    o[2] = (short)f2bfu(v[2]); o[3] = (short)f2bfu(v[3]);
    *(s16x4*)(dst + (size_t)i * 4) = o;
}

__global__ void k_transpose(const float* __restrict__ src, int sld, u16* __restrict__ dst, int K) {
    __shared__ float tile[32][33];
    int k0 = blockIdx.x * 32, n0 = blockIdx.y * 32;
    for (int r = threadIdx.y; r < 32; r += 8)
        tile[r][threadIdx.x] = src[(size_t)(k0 + r) * sld + n0 + threadIdx.x];
    __syncthreads();
    for (int r = threadIdx.y; r < 32; r += 8)
        dst[(size_t)(n0 + r) * K + k0 + threadIdx.x] = f2bfu(tile[threadIdx.x][r]);
}

__global__ void k_prep(const float* __restrict__ zsp, const float* __restrict__ zm,
                       const float* __restrict__ zsd, u16* __restrict__ flat) {
    size_t i = ((size_t)blockIdx.x * 256 + threadIdx.x) * 4;
    f32x4 v = *(const f32x4*)(zsp + i);
    int ch = ((int)(i >> 9)) & 3;
    float m = zm[ch], s = zsd[ch];
    s16x4 o;
    o[0] = (short)f2bfu((v[0] - m) / s); o[1] = (short)f2bfu((v[1] - m) / s);
    o[2] = (short)f2bfu((v[2] - m) / s); o[3] = (short)f2bfu((v[3] - m) / s);
    *(s16x4*)(flat + i) = o;
}

__global__ __launch_bounds__(256) void k_xpre0(const float* __restrict__ preW, const float* __restrict__ preb,
                                               const float* __restrict__ actions, u16* __restrict__ xout) {
    int b = blockIdx.x, tid = threadIdx.x;
    __shared__ float as[3];
    if (tid < 3) as[tid] = actions[(size_t)b * 64 * 3 + tid];
    __syncthreads();
    for (int j = tid; j < 1024; j += 256) {
        float s = preb[j] + as[0] * preW[1024 * 1024 + j] + as[1] * preW[1025 * 1024 + j] + as[2] * preW[1026 * 1024 + j];
        xout[(b << 10) + j] = f2bfu(eluf(s));
    }
}

// x-gen only (argmax fused into k3's EPI8 epilogue)
__global__ __launch_bounds__(256) void k_xgen(const int* __restrict__ latidx_t,
                                              const u16* __restrict__ PreLatB, const float* __restrict__ preW,
                                              const float* __restrict__ preb,
                                              const float* __restrict__ actions, u16* __restrict__ xout,
                                              int tnext) {
    int b = blockIdx.x, tid = threadIdx.x;
    __shared__ int idxs[32];
    __shared__ float as[3];
    if (tid < 32) idxs[tid] = latidx_t[(b << 5) + tid];
    if (tid >= 64 && tid < 67) as[tid - 64] = actions[((size_t)b * 64 + tnext) * 3 + (tid - 64)];
    __syncthreads();
    const int j4 = tid * 4;
    f32x4 s = *(const f32x4*)(preb + j4);
#pragma unroll
    for (int cc = 0; cc < 3; ++cc) {
        f32x4 wv = *(const f32x4*)(preW + (size_t)(1024 + cc) * 1024 + j4);
        s[0] += as[cc] * wv[0]; s[1] += as[cc] * wv[1];
        s[2] += as[cc] * wv[2]; s[3] += as[cc] * wv[3];
    }
#pragma unroll
    for (int l = 0; l < 32; ++l) {
        s16x4 v = *(const s16x4*)(PreLatB + (size_t)((l << 5) + idxs[l]) * 1024 + j4);
        s[0] += bfu2f((u16)v[0]); s[1] += bfu2f((u16)v[1]);
        s[2] += bfu2f((u16)v[2]); s[3] += bfu2f((u16)v[3]);
    }
    s16x4 o;
    o[0] = (short)f2bfu(eluf(s[0])); o[1] = (short)f2bfu(eluf(s[1]));
    o[2] = (short)f2bfu(eluf(s[2])); o[3] = (short)f2bfu(eluf(s[3]));
    *(s16x4*)(xout + (b << 10) + j4) = o;
}

// batched KL: one block per (t,b) row; reads bf16 post/prior logits
__global__ __launch_bounds__(256) void k_kl(const u16* __restrict__ PoAll, const u16* __restrict__ PrAll,
                                            float* __restrict__ klrow) {
    int m = blockIdx.x, tid = threadIdx.x;
    const u16* Po = PoAll + (size_t)m * 1024;
    const u16* Pr = PrAll + (size_t)m * 1024;
    __shared__ float klpart[32];
    int grp = tid >> 5, c = tid & 31;
#pragma unroll
    for (int it = 0; it < 4; ++it) {
        int l = it * 8 + grp;
        float po = bfu2f(Po[l * 32 + c]);
        float pr = bfu2f(Pr[l * 32 + c]);
        float mv = po, mq = pr;
#pragma unroll
        for (int o = 16; o > 0; o >>= 1) {
            mv = fmaxf(mv, __shfl_xor(mv, o, 32));
            mq = fmaxf(mq, __shfl_xor(mq, o, 32));
        }
        float ep = expf(po - mv), eq = expf(pr - mq);
        float sp = ep, sq = eq;
#pragma unroll
        for (int o = 16; o > 0; o >>= 1) { sp += __shfl_xor(sp, o, 32); sq += __shfl_xor(sq, o, 32); }
        float logp = po - mv - logf(sp);
        float logq = pr - mq - logf(sq);
        float klc = (ep / sp) * (logp - logq);
#pragma unroll
        for (int o = 16; o > 0; o >>= 1) klc += __shfl_xor(klc, o, 32);
        if (c == 0) klpart[l] = klc;
    }
    __syncthreads();
    if (tid == 0) {
        float kl = 0.f;
        for (int l = 0; l < 32; ++l) kl += klpart[l];
        klrow[m] = fmaxf(kl, 1.0f);
    }
}

__global__ __launch_bounds__(256) void k_latsum(const u16* __restrict__ LatB, const float* __restrict__ db1,
                                                const int* __restrict__ latidx_all, u16* __restrict__ latsum) {
    int m = blockIdx.x, tid = threadIdx.x;
    __shared__ int idxs[32];
    if (tid < 32) idxs[tid] = latidx_all[(size_t)m * 32 + tid];
    __syncthreads();
    const int j4 = tid * 4;
    f32x4 s = *(const f32x4*)(db1 + j4);
#pragma unroll
    for (int l = 0; l < 32; ++l) {
        s16x4 v = *(const s16x4*)(LatB + (size_t)((l << 5) + idxs[l]) * 1024 + j4);
        s[0] += bfu2f((u16)v[0]); s[1] += bfu2f((u16)v[1]);
        s[2] += bfu2f((u16)v[2]); s[3] += bfu2f((u16)v[3]);
    }
    s16x4 o;
    o[0] = (short)f2bfu(s[0]); o[1] = (short)f2bfu(s[1]);
    o[2] = (short)f2bfu(s[2]); o[3] = (short)f2bfu(s[3]);
    *(s16x4*)(latsum + (size_t)m * 1024 + j4) = o;
}

// NOTE: MUST be launched with 256 threads (r3-r5 bug: was <<<1,1>>>)
__global__ __launch_bounds__(256) void k_finalize(const double* __restrict__ acc,
                                                  const float* __restrict__ klrow, float* __restrict__ out) {
    __shared__ double ps[256];
    int tid = threadIdx.x;
    double s = 0.0;
    for (int i = tid; i < 16128; i += 256) s += (double)klrow[i];
    ps[tid] = s;
    __syncthreads();
    for (int o = 128; o > 0; o >>= 1) {
        if (tid < o) ps[tid] += ps[tid + o];
        __syncthreads();
    }
    if (tid == 0) out[0] = (float)(acc[0] / 33030144.0 + ps[0] / 16128.0);
}

// ---------------------------------------------------------------------------
extern "C" void kernel_launch(void* const* d_in, const int* in_sizes, int n_in,
                              void* d_out, int out_size, void* d_ws, size_t ws_size,
                              hipStream_t stream) {
    const float* zs      = (const float*)d_in[0];
    const float* actions = (const float*)d_in[1];
    const float* zmean   = (const float*)d_in[2];
    const float* zstd    = (const float*)d_in[3];
    const float* encW    = (const float*)d_in[4];
    const float* encb    = (const float*)d_in[5];
    const float* preW    = (const float*)d_in[6];
    const float* preb    = (const float*)d_in[7];
    const float* Wih     = (const float*)d_in[8];
    const float* Whh     = (const float*)d_in[9];
    const float* bih     = (const float*)d_in[10];
    const float* bhh     = (const float*)d_in[11];
    const float* tW1     = (const float*)d_in[12];
    const float* tb1     = (const float*)d_in[13];
    const float* tW2     = (const float*)d_in[14];
    const float* tb2     = (const float*)d_in[15];
    const float* rW1     = (const float*)d_in[16];
    const float* rb1     = (const float*)d_in[17];
    const float* rW2     = (const float*)d_in[18];
    const float* rb2     = (const float*)d_in[19];
    const float* dW1     = (const float*)d_in[20];
    const float* db1     = (const float*)d_in[21];
    const float* dW2     = (const float*)d_in[22];
    const float* db2     = (const float*)d_in[23];

    char* W = (char*)d_ws;
    size_t off = 0;
    auto take = [&](size_t b) { char* p = W + off; off += (b + 255) & ~(size_t)255; return p; };

    double* accum  = (double*)take(16);
    u16* encWbt = (u16*)take((size_t)1024 * 2048 * 2);
    u16* WihB   = (u16*)take((size_t)6144 * 1024 * 2);
    u16* WhhB   = (u16*)take((size_t)6144 * 2048 * 2);
    u16* l1B    = (u16*)take((size_t)2048 * 2048 * 2);   // [tW1t | rW1at]
    u16* tW2bt  = (u16*)take((size_t)1024 * 1024 * 2);
    u16* rW2bt  = (u16*)take((size_t)1024 * 1024 * 2);
    u16* rW1bbt = (u16*)take((size_t)1024 * 1024 * 2);
    u16* dW1abt = (u16*)take((size_t)1024 * 2048 * 2);
    u16* dW2bt  = (u16*)take((size_t)2048 * 1024 * 2);
    u16* PreLatB = (u16*)take((size_t)1024 * 1024 * 2);
    u16* LatB    = (u16*)take((size_t)1024 * 1024 * 2);
    u16* Hall   = (u16*)take((size_t)63 * 256 * 2048 * 2);
    int* latidx = (int*)take((size_t)63 * 256 * 32 * 4);
    u16* embR   = (u16*)take((size_t)16384 * 1024 * 2);   // scan emb; then PrAll; then latsum
    u16* enc    = (u16*)take((size_t)16384 * 1024 * 2);   // encoder out; then PoAll
    float* klrow = (float*)take((size_t)16128 * 4);
    u16* GHb    = (u16*)take((size_t)2 * 256 * 6144 * 2);
    float* hf32 = (float*)take((size_t)256 * 2048 * 4);
    u16* x_bf   = (u16*)take((size_t)256 * 1024 * 2);
    u16* p1q1   = (u16*)take((size_t)256 * 1024 * 2);
    char* X     = take((size_t)17825792);                  // 17 MB: flatc/Xp/d1

    u16* flatc = (u16*)X;                                  // 4096 x 2048 per pass
    u16* Xp    = (u16*)X;                                  // 8064 x 1024 per half
    u16* d1    = (u16*)X;                                  // 8064 x 1024 per half
    u16* PoAll = enc;                                      // enc dead after embR GEMM
    u16* PrAll = embR;                                     // embR dead after scan; consumed by k_kl before latsum

    k_init<<<1, 1, 0, stream>>>(accum);

    // weight conversion
    k_cast<<<6144, 256, 0, stream>>>(Wih, WihB, 6291456 / 4);
    k_cast<<<12288, 256, 0, stream>>>(Whh, WhhB, 12582912 / 4);
    k_cast<<<1024, 256, 0, stream>>>(preW, PreLatB, 262144);
    k_cast<<<1024, 256, 0, stream>>>(dW1 + (size_t)2048 * 1024, LatB, 262144);
    k_transpose<<<dim3(64, 32), dim3(32, 8), 0, stream>>>(encW, 1024, encWbt, 2048);
    k_transpose<<<dim3(64, 32), dim3(32, 8), 0, stream>>>(tW1, 1024, l1B, 2048);
    k_transpose<<<dim3(64, 32), dim3(32, 8), 0, stream>>>(rW1, 1024, l1B + (size_t)1024 * 2048, 2048);
    k_transpose<<<dim3(32, 32), dim3(32, 8), 0, stream>>>(tW2, 1024, tW2bt, 1024);
    k_transpose<<<dim3(32, 32), dim3(32, 8), 0, stream>>>(rW2, 1024, rW2bt, 1024);
    k_transpose<<<dim3(32, 32), dim3(32, 8), 0, stream>>>(rW1 + (size_t)2048 * 1024, 1024, rW1bbt, 1024);
    k_transpose<<<dim3(64, 32), dim3(32, 8), 0, stream>>>(dW1, 1024, dW1abt, 2048);
    k_transpose<<<dim3(32, 64), dim3(32, 8), 0, stream>>>(dW2, 2048, dW2bt, 1024);

    // phase 1: encoder (4 passes of 4096 rows; 64² gemmS + T1 swizzle)
    for (int pass = 0; pass < 4; ++pass) {
        k_prep<<<8192, 256, 0, stream>>>(zs + (size_t)pass * 4096 * 2048, zmean, zstd, flatc);
        GP e{}; e.A = flatc; e.lda = 2048; e.Bt = encWbt; e.Cb = enc + (size_t)pass * 4096 * 1024;
        e.ldc = 1024; e.bias = encb; e.K = 2048; e.gridN = 16;
        gemmS<2, 2, 2, 2, 1, 1, true><<<dim3(1024), 256, 0, stream>>>(e, e, 1024);
    }
    {
        GP e{}; e.A = enc; e.lda = 1024; e.Bt = rW1bbt; e.Cb = embR; e.ldc = 1024;
        e.bias = rb1; e.K = 1024; e.gridN = 16;
        gemmS<2, 2, 2, 2, 2, 2, true><<<dim3(4096), 256, 0, stream>>>(e, e, 4096);
    }

    // phase 2: sequential scan (post-only path; prior deferred)
    k_xpre0<<<256, 256, 0, stream>>>(preW, preb, actions, x_bf);
    for (int t = 0; t < 63; ++t) {
        // k1: gx + GRU -> h_t
        if (t == 0)
            k_gates<true><<<256, 256, 0, stream>>>(x_bf, WihB, bih, bhh, GHb, hf32, Hall);
        else
            k_gates<false><<<256, 256, 0, stream>>>(x_bf, WihB, bih, bhh, GHb + (size_t)(t & 1) * 256 * 6144,
                                                    hf32, Hall + (size_t)t * 256 * 2048);
        // k2: gh(t+1) (bf16) || l1-post(t) — 8-wave blocks (512 thr), same 448 tiles
        {
            GP pa{}; pa.A = Hall + (size_t)t * 256 * 2048; pa.lda = 2048; pa.Bt = WhhB;
            pa.Cb = GHb + (size_t)((t + 1) & 1) * 256 * 6144; pa.ldc = 6144; pa.bias = bhh;
            pa.K = 2048; pa.gridN = 96;
            GP pb{}; pb.A = Hall + (size_t)t * 256 * 2048; pb.lda = 2048;
            pb.Bt = l1B + (size_t)1024 * 2048; pb.Cb = p1q1; pb.ldc = 1024;
            pb.aux = embR + (size_t)(t + 1) * 1024; pb.auxld = 65536;
            pb.K = 2048; pb.gridN = 16;
            int nA = (t < 62) ? 384 : 0;
            gemmS<2, 4, 2, 1, 7, 4><<<dim3(nA + 64), 512, 0, stream>>>(pa, pb, nA);
        }
        // k3: q-post (BM=32, 128 blocks) -> PoAll[t] + fused argmax -> latidx[t]
        {
            GP q{}; q.A = p1q1; q.lda = 1024; q.Bt = rW2bt; q.ldc = 1024;
            q.Cb = PoAll + (size_t)t * 256 * 1024; q.bias = rb2; q.K = 1024; q.gridN = 16;
            q.idx = latidx + (size_t)t * 256 * 32;
            gemmS<2, 2, 1, 2, 8, 8><<<dim3(128), 256, 0, stream>>>(q, q, 128);
        }
        // k4: next x from latidx
        if (t < 62)
            k_xgen<<<256, 256, 0, stream>>>(latidx + (size_t)t * 256 * 32,
                                            PreLatB, preW, preb, actions, x_bf, t + 1);
    }

    // phase 3a: batched prior (2 halves of 8064 rows; 64² + T1 swizzle) + KL
    for (int half = 0; half < 2; ++half) {
        int m0 = half * 8064;
        GP e{}; e.A = Hall + (size_t)m0 * 2048; e.lda = 2048; e.Bt = l1B; e.Cb = Xp; e.ldc = 1024;
        e.bias = tb1; e.K = 2048; e.gridN = 16;
        gemmS<2, 2, 2, 2, 1, 1, true><<<dim3(2016), 256, 0, stream>>>(e, e, 2016);
        GP q{}; q.A = Xp; q.lda = 1024; q.Bt = tW2bt; q.Cb = PrAll + (size_t)m0 * 1024; q.ldc = 1024;
        q.bias = tb2; q.K = 1024; q.gridN = 16;
        gemmS<2, 2, 2, 2, 2, 2, true><<<dim3(2016), 256, 0, stream>>>(q, q, 2016);
    }
    k_kl<<<16128, 256, 0, stream>>>(PoAll, PrAll, klrow);

    // phase 3b: decoder + fused recon (2 halves; 64² + T1 swizzle)
    k_latsum<<<16128, 256, 0, stream>>>(LatB, db1, latidx, embR);
    for (int half = 0; half < 2; ++half) {
        int m0 = half * 8064;
        GP d{}; d.A = Hall + (size_t)m0 * 2048; d.lda = 2048; d.Bt = dW1abt; d.Cb = d1; d.ldc = 1024;
        d.aux = embR + (size_t)m0 * 1024; d.auxld = 1024; d.K = 2048; d.gridN = 16;
        gemmS<2, 2, 2, 2, 4, 4, true><<<dim3(2016), 256, 0, stream>>>(d, d, 2016);
        GP d2{}; d2.A = d1; d2.lda = 1024; d2.Bt = dW2bt; d2.ldc = 2048; d2.bias = db2;
        d2.zs = zs; d2.zmean = zmean; d2.zstd = zstd; d2.accum = accum; d2.K = 1024; d2.gridN = 32;
        d2.rbase = m0;
        gemmS<2, 2, 2, 2, 5, 5, true><<<dim3(4032), 256, 0, stream>>>(d2, d2, 4032);
    }
    k_finalize<<<1, 256, 0, stream>>>(accum, klrow, (float*)d_out);
}

// Round 11
// 3322.483 us; speedup vs baseline: 1.1250x; 1.0233x over previous
//
#include <hip/hip_runtime.h>
#include <hip/hip_bf16.h>
#include <math.h>

typedef unsigned short u16;
typedef __attribute__((ext_vector_type(8))) short s16x8;
typedef __attribute__((ext_vector_type(4))) short s16x4;
typedef __attribute__((ext_vector_type(4))) float f32x4;

#define DEVI static __device__ __forceinline__

DEVI u16 f2bfu(float f) {
    unsigned u = __float_as_uint(f);
    unsigned r = (u + 0x7fffu + ((u >> 16) & 1u)) >> 16;
    return (u16)r;
}
DEVI float bfu2f(u16 u) { return __uint_as_float(((unsigned)u) << 16); }
DEVI float eluf(float x) { return x > 0.f ? x : (expf(x) - 1.f); }
DEVI float sigm(float x) { return 1.f / (1.f + expf(-x)); }

#define GLOAD16(gsrc, ldst)                                                            \
    __builtin_amdgcn_global_load_lds(                                                  \
        (__attribute__((address_space(1))) void*)(void*)(gsrc),                        \
        (__attribute__((address_space(3))) void*)(ldst), 16, 0, 0)

template <int N> DEVI void vmwait();
template <> DEVI void vmwait<0>() { asm volatile("s_waitcnt vmcnt(0)" ::: "memory"); }
template <> DEVI void vmwait<1>() { asm volatile("s_waitcnt vmcnt(1)" ::: "memory"); }
template <> DEVI void vmwait<2>() { asm volatile("s_waitcnt vmcnt(2)" ::: "memory"); }
template <> DEVI void vmwait<3>() { asm volatile("s_waitcnt vmcnt(3)" ::: "memory"); }
template <> DEVI void vmwait<4>() { asm volatile("s_waitcnt vmcnt(4)" ::: "memory"); }
template <> DEVI void vmwait<5>() { asm volatile("s_waitcnt vmcnt(5)" ::: "memory"); }
template <> DEVI void vmwait<6>() { asm volatile("s_waitcnt vmcnt(6)" ::: "memory"); }

struct GP {
    const u16* A; int lda;
    const u16* Bt;
    float* Cf; u16* Cb; int ldc;
    const float* bias;
    const u16* aux; int auxld;
    const float* zs;               // EPI5
    const float* zmean; const float* zstd;
    double* accum;
    int* idx;                      // EPI8: argmax out
    int K; int gridN; int rbase;
};

// ---------------------------------------------------------------------------
// gemmS: BK=64, T2 XOR-swizzle, 3-deep counted-vmcnt pipeline. The only GEMM.
// r8/r9/r10 lesson: scan launches are occupancy-bound — block count and
// waves/CU dominate MFMA density. SWZ = T1 XCD tile remap (needs nA%8==0).
// ---------------------------------------------------------------------------
template <int EPI, int MF, int NF>
DEVI void epiS(const GP& p, f32x4 (&acc)[MF][NF], int r0, int c0, int wm, int wn,
               int lrow4, int lcol) {
#pragma unroll
    for (int mf = 0; mf < MF; ++mf) {
        int rowb = r0 + (wm * MF + mf) * 16 + lrow4;
#pragma unroll
        for (int nf = 0; nf < NF; ++nf) {
            int col = c0 + (wn * NF + nf) * 16 + lcol;
#pragma unroll
            for (int j = 0; j < 4; ++j) {
                float v = acc[mf][nf][j];
                int r = rowb + j;
                if constexpr (EPI == 1) {
                    p.Cb[(size_t)r * p.ldc + col] = f2bfu(eluf(v + p.bias[col]));
                } else if constexpr (EPI == 2) {
                    p.Cb[(size_t)r * p.ldc + col] = f2bfu(v + p.bias[col]);
                } else if constexpr (EPI == 4) {
                    p.Cb[(size_t)r * p.ldc + col] = f2bfu(eluf(v + bfu2f(p.aux[(size_t)r * p.auxld + col])));
                } else if constexpr (EPI == 7) {
                    p.Cb[(size_t)r * p.ldc + col] = f2bfu(v + p.bias[col]);
                }
            }
        }
    }
}

template <int WM, int WN, int MF, int NF, int EPIa, int EPIb, bool SWZ = false>
__global__ __launch_bounds__(WM * WN * 64) void gemmS(GP pa, GP pb, int nA) {
    constexpr int NT = WM * WN * 64;
    constexpr int BM = WM * MF * 16, BN = WN * NF * 16;
    constexpr int ABY = BM * 128, BBY = BN * 128;
    constexpr int LPT = (ABY + BBY) / (NT * 16);

    const int tid = threadIdx.x, w = tid >> 6, lane = tid & 63;
    const bool isA = (int)blockIdx.x < nA;
    GP p = isA ? pa : pb;
    int bid = isA ? blockIdx.x : blockIdx.x - nA;
    if constexpr (SWZ) bid = (bid & 7) * (nA >> 3) + (bid >> 3);   // T1, needs nA%8==0
    const int bn = bid % p.gridN, bm = bid / p.gridN;
    const int r0 = bm * BM, c0 = bn * BN;
    const int wm = w / WN, wn = w % WN;

    __shared__ __attribute__((aligned(16))) char sm[3 * (ABY + BBY)];
    __shared__ float ps_[WM * WN];

    auto stage = [&](int kt, int buf) {
        char* s = sm + buf * (ABY + BBY);
#pragma unroll
        for (int it = 0; it < ABY / (NT * 16); ++it) {
            int bo = it * (NT * 16) + tid * 16;
            int row = bo >> 7, kb = bo & 127;
            int kbs = kb ^ ((row & 7) << 4);                       // pre-swizzled source
            GLOAD16(p.A + (size_t)(r0 + row) * p.lda + kt * 64 + (kbs >> 1), s + bo);
        }
        char* sb = s + ABY;
#pragma unroll
        for (int it = 0; it < BBY / (NT * 16); ++it) {
            int bo = it * (NT * 16) + tid * 16;
            int row = bo >> 7, kb = bo & 127;
            int kbs = kb ^ ((row & 7) << 4);
            GLOAD16(p.Bt + (size_t)(c0 + row) * p.K + kt * 64 + (kbs >> 1), sb + bo);
        }
    };

    f32x4 acc[MF][NF];
#pragma unroll
    for (int mf = 0; mf < MF; ++mf)
#pragma unroll
        for (int nf = 0; nf < NF; ++nf) acc[mf][nf] = (f32x4){0.f, 0.f, 0.f, 0.f};

    const int nk = p.K >> 6;
    stage(0, 0);
    stage(1, 1);
    int b0 = 0, b1 = 1, b2 = 2;
    for (int kt = 0; kt < nk; ++kt) {
        if (kt < nk - 1) vmwait<LPT>(); else vmwait<0>();
        __builtin_amdgcn_sched_barrier(0);
        __builtin_amdgcn_s_barrier();
        if (kt + 2 < nk) stage(kt + 2, b2);
        const char* s = sm + b0 * (ABY + BBY);
#pragma unroll
        for (int ks = 0; ks < 2; ++ks) {
            const int kb = ks * 64 + ((lane >> 4) << 4);
            s16x8 aF[MF], bF[NF];
#pragma unroll
            for (int mf = 0; mf < MF; ++mf) {
                int rt = (wm * MF + mf) * 16 + (lane & 15);
                aF[mf] = *(const s16x8*)(s + rt * 128 + (kb ^ ((rt & 7) << 4)));
            }
#pragma unroll
            for (int nf = 0; nf < NF; ++nf) {
                int rt = (wn * NF + nf) * 16 + (lane & 15);
                bF[nf] = *(const s16x8*)(s + ABY + rt * 128 + (kb ^ ((rt & 7) << 4)));
            }
#pragma unroll
            for (int mf = 0; mf < MF; ++mf)
#pragma unroll
                for (int nf = 0; nf < NF; ++nf)
                    acc[mf][nf] = __builtin_amdgcn_mfma_f32_16x16x32_bf16(aF[mf], bF[nf], acc[mf][nf], 0, 0, 0);
        }
        int t_ = b0; b0 = b1; b1 = b2; b2 = t_;
    }

    const int lrow4 = (lane >> 4) << 2, lcol = lane & 15;
    if constexpr (EPIa == 8) {
        // requires NF==2: wave (wm,wn) owns one 32-class latent group
        const int lat = (c0 >> 5) + wn;
#pragma unroll
        for (int mf = 0; mf < MF; ++mf) {
#pragma unroll
            for (int j = 0; j < 4; ++j) {
                int r = r0 + (wm * MF + mf) * 16 + lrow4 + j;
                int col0 = c0 + wn * 32 + lcol;
                float v0 = acc[mf][0][j] + p.bias[col0];
                float v1 = acc[mf][1][j] + p.bias[col0 + 16];
                p.Cb[(size_t)r * p.ldc + col0] = f2bfu(v0);
                p.Cb[(size_t)r * p.ldc + col0 + 16] = f2bfu(v1);
                float mv; int mi;
                if (v1 > v0) { mv = v1; mi = lcol + 16; } else { mv = v0; mi = lcol; }
#pragma unroll
                for (int o = 8; o >= 1; o >>= 1) {
                    float ov = __shfl_xor(mv, o, 64);
                    int oi = __shfl_xor(mi, o, 64);
                    if (ov > mv || (ov == mv && oi < mi)) { mv = ov; mi = oi; }
                }
                if (lcol == 0) p.idx[(size_t)r * 32 + lat] = mi;
            }
        }
    } else if constexpr (EPIa == 5) {
        float lsum = 0.f;
#pragma unroll
        for (int mf = 0; mf < MF; ++mf) {
            int rowb = r0 + (wm * MF + mf) * 16 + lrow4;
#pragma unroll
            for (int nf = 0; nf < NF; ++nf) {
                int col = c0 + (wn * NF + nf) * 16 + lcol;
#pragma unroll
                for (int j = 0; j < 4; ++j) {
                    float v = acc[mf][nf][j] + p.bias[col];
                    int R = rowb + j + p.rbase;
                    int tt = R >> 8, b = R & 255;
                    int ch = col >> 9;
                    float z = (p.zs[((size_t)b * 64 + tt + 1) * 2048 + col] - p.zmean[ch]) / p.zstd[ch];
                    float d = v - z;
                    lsum += d * d;
                }
            }
        }
#pragma unroll
        for (int o = 32; o > 0; o >>= 1) lsum += __shfl_down(lsum, o, 64);
        if (lane == 0) ps_[w] = lsum;
        __syncthreads();
        if (tid == 0) {
            double s = 0.0;
#pragma unroll
            for (int i = 0; i < WM * WN; ++i) s += (double)ps_[i];
            atomicAdd(p.accum, s);
        }
    } else {
        if (isA) epiS<EPIa, MF, NF>(p, acc, r0, c0, wm, wn, lrow4, lcol);
        else     epiS<EPIb, MF, NF>(p, acc, r0, c0, wm, wn, lrow4, lcol);
    }
}

// ---------------------------------------------------------------------------
// k_gates: gx (K=1024) + full GRU epilogue; 3-deep pipeline.
// r11: 512 blocks (bm 8 x bn 64), BM=32 x 32-col gate tile, TSZ=16KB, LPT=4
// -> 2 blocks/CU x 4 waves = 8 waves/CU (was 4). Occupancy-bound regime.
// ---------------------------------------------------------------------------
template <bool FIRST>
__global__ __launch_bounds__(256) void k_gates(const u16* __restrict__ X, const u16* __restrict__ WihB,
                                               const float* __restrict__ bih, const float* __restrict__ bhh,
                                               const u16* __restrict__ GHb, float* __restrict__ hf32,
                                               u16* __restrict__ hallT) {
    constexpr int ABY = 32 * 128;       // 4 KB
    constexpr int BTB = 32 * 128;       // 4 KB per gate tile
    constexpr int TSZ = ABY + 3 * BTB;  // 16 KB
    const int tid = threadIdx.x, w = tid >> 6, lane = tid & 63;
    const int bm = blockIdx.x >> 6, bn = blockIdx.x & 63;
    const int r0 = bm * 32, c0 = bn * 32;
    const int wm = w >> 1, wn = w & 1;

    __shared__ __attribute__((aligned(16))) char sm[3 * TSZ];

    auto stage = [&](int kt, int buf) {
        char* s = sm + buf * TSZ;
        {
            int bo = tid * 16;                 // 256*16 = 4KB = ABY exactly
            int row = bo >> 7, kb = bo & 127;
            int kbs = kb ^ ((row & 7) << 4);
            GLOAD16(X + (size_t)(r0 + row) * 1024 + kt * 64 + (kbs >> 1), s + bo);
        }
        char* sb = s + ABY;
#pragma unroll
        for (int g = 0; g < 3; ++g) {
            int bo = tid * 16;
            int row = bo >> 7, kb = bo & 127;
            int kbs = kb ^ ((row & 7) << 4);
            GLOAD16(WihB + (size_t)(g * 2048 + c0 + row) * 1024 + kt * 64 + (kbs >> 1), sb + g * BTB + bo);
        }
    };

    f32x4 acc[3];
#pragma unroll
    for (int g = 0; g < 3; ++g) acc[g] = (f32x4){0.f, 0.f, 0.f, 0.f};

    stage(0, 0);
    stage(1, 1);
    int b0 = 0, b1 = 1, b2 = 2;
    for (int kt = 0; kt < 16; ++kt) {
        if (kt < 15) vmwait<4>(); else vmwait<0>();
        __builtin_amdgcn_sched_barrier(0);
        __builtin_amdgcn_s_barrier();
        if (kt + 2 < 16) stage(kt + 2, b2);
        const char* s = sm + b0 * TSZ;
#pragma unroll
        for (int ks = 0; ks < 2; ++ks) {
            const int kb = ks * 64 + ((lane >> 4) << 4);
            s16x8 aF, bF[3];
            {
                int rt = wm * 16 + (lane & 15);
                aF = *(const s16x8*)(s + rt * 128 + (kb ^ ((rt & 7) << 4)));
            }
#pragma unroll
            for (int g = 0; g < 3; ++g) {
                int rt = wn * 16 + (lane & 15);
                bF[g] = *(const s16x8*)(s + ABY + g * BTB + rt * 128 + (kb ^ ((rt & 7) << 4)));
            }
#pragma unroll
            for (int g = 0; g < 3; ++g)
                acc[g] = __builtin_amdgcn_mfma_f32_16x16x32_bf16(aF, bF[g], acc[g], 0, 0, 0);
        }
        int t_ = b0; b0 = b1; b1 = b2; b2 = t_;
    }

    const int lrow4 = (lane >> 4) << 2, lcol = lane & 15;
    const int cc = c0 + wn * 16 + lcol;
    {
        int rr0 = r0 + wm * 16 + lrow4;
#pragma unroll
        for (int j = 0; j < 4; ++j) {
            int rr = rr0 + j;
            float xr = acc[0][j] + bih[cc];
            float xz = acc[1][j] + bih[2048 + cc];
            float xn = acc[2][j] + bih[4096 + cc];
            float hr_, hz_, hn_;
            if (FIRST) { hr_ = bhh[cc]; hz_ = bhh[2048 + cc]; hn_ = bhh[4096 + cc]; }
            else {
                const u16* g = GHb + (size_t)rr * 6144;
                hr_ = bfu2f(g[cc]); hz_ = bfu2f(g[2048 + cc]); hn_ = bfu2f(g[4096 + cc]);
            }
            float r = sigm(xr + hr_);
            float u = sigm(xz + hz_);
            float n = tanhf(xn + r * hn_);
            float hold = FIRST ? 0.f : hf32[(size_t)rr * 2048 + cc];
            float h = (1.f - u) * n + u * hold;
            hf32[(size_t)rr * 2048 + cc] = h;
            hallT[(size_t)rr * 2048 + cc] = f2bfu(h);
        }
    }
}

// ---------------------------------------------------------------------------
// small kernels
// ---------------------------------------------------------------------------
__global__ void k_init(double* acc) { acc[0] = 0.0; acc[1] = 0.0; }

__global__ void k_cast(const float* __restrict__ src, u16* __restrict__ dst, int n4) {
    int i = blockIdx.x * 256 + threadIdx.x;
    if (i >= n4) return;
    f32x4 v = *(const f32x4*)(src + (size_t)i * 4);
    s16x4 o;
    o[0] = (short)f2bfu(v[0]); o[1] = (short)f2bfu(v[1]);
    o[2] = (short)f2bfu(v[2]); o[3] = (short)f2bfu(v[3]);
    *(s16x4*)(dst + (size_t)i * 4) = o;
}

__global__ void k_transpose(const float* __restrict__ src, int sld, u16* __restrict__ dst, int K) {
    __shared__ float tile[32][33];
    int k0 = blockIdx.x * 32, n0 = blockIdx.y * 32;
    for (int r = threadIdx.y; r < 32; r += 8)
        tile[r][threadIdx.x] = src[(size_t)(k0 + r) * sld + n0 + threadIdx.x];
    __syncthreads();
    for (int r = threadIdx.y; r < 32; r += 8)
        dst[(size_t)(n0 + r) * K + k0 + threadIdx.x] = f2bfu(tile[threadIdx.x][r]);
}

__global__ void k_prep(const float* __restrict__ zsp, const float* __restrict__ zm,
                       const float* __restrict__ zsd, u16* __restrict__ flat) {
    size_t i = ((size_t)blockIdx.x * 256 + threadIdx.x) * 4;
    f32x4 v = *(const f32x4*)(zsp + i);
    int ch = ((int)(i >> 9)) & 3;
    float m = zm[ch], s = zsd[ch];
    s16x4 o;
    o[0] = (short)f2bfu((v[0] - m) / s); o[1] = (short)f2bfu((v[1] - m) / s);
    o[2] = (short)f2bfu((v[2] - m) / s); o[3] = (short)f2bfu((v[3] - m) / s);
    *(s16x4*)(flat + i) = o;
}

__global__ __launch_bounds__(256) void k_xpre0(const float* __restrict__ preW, const float* __restrict__ preb,
                                               const float* __restrict__ actions, u16* __restrict__ xout) {
    int b = blockIdx.x, tid = threadIdx.x;
    __shared__ float as[3];
    if (tid < 3) as[tid] = actions[(size_t)b * 64 * 3 + tid];
    __syncthreads();
    for (int j = tid; j < 1024; j += 256) {
        float s = preb[j] + as[0] * preW[1024 * 1024 + j] + as[1] * preW[1025 * 1024 + j] + as[2] * preW[1026 * 1024 + j];
        xout[(b << 10) + j] = f2bfu(eluf(s));
    }
}

// x-gen only (argmax fused into k3's EPI8 epilogue)
__global__ __launch_bounds__(256) void k_xgen(const int* __restrict__ latidx_t,
                                              const u16* __restrict__ PreLatB, const float* __restrict__ preW,
                                              const float* __restrict__ preb,
                                              const float* __restrict__ actions, u16* __restrict__ xout,
                                              int tnext) {
    int b = blockIdx.x, tid = threadIdx.x;
    __shared__ int idxs[32];
    __shared__ float as[3];
    if (tid < 32) idxs[tid] = latidx_t[(b << 5) + tid];
    if (tid >= 64 && tid < 67) as[tid - 64] = actions[((size_t)b * 64 + tnext) * 3 + (tid - 64)];
    __syncthreads();
    const int j4 = tid * 4;
    f32x4 s = *(const f32x4*)(preb + j4);
#pragma unroll
    for (int cc = 0; cc < 3; ++cc) {
        f32x4 wv = *(const f32x4*)(preW + (size_t)(1024 + cc) * 1024 + j4);
        s[0] += as[cc] * wv[0]; s[1] += as[cc] * wv[1];
        s[2] += as[cc] * wv[2]; s[3] += as[cc] * wv[3];
    }
#pragma unroll
    for (int l = 0; l < 32; ++l) {
        s16x4 v = *(const s16x4*)(PreLatB + (size_t)((l << 5) + idxs[l]) * 1024 + j4);
        s[0] += bfu2f((u16)v[0]); s[1] += bfu2f((u16)v[1]);
        s[2] += bfu2f((u16)v[2]); s[3] += bfu2f((u16)v[3]);
    }
    s16x4 o;
    o[0] = (short)f2bfu(eluf(s[0])); o[1] = (short)f2bfu(eluf(s[1]));
    o[2] = (short)f2bfu(eluf(s[2])); o[3] = (short)f2bfu(eluf(s[3]));
    *(s16x4*)(xout + (b << 10) + j4) = o;
}

// batched KL: one block per (t,b) row; reads bf16 post/prior logits
__global__ __launch_bounds__(256) void k_kl(const u16* __restrict__ PoAll, const u16* __restrict__ PrAll,
                                            float* __restrict__ klrow) {
    int m = blockIdx.x, tid = threadIdx.x;
    const u16* Po = PoAll + (size_t)m * 1024;
    const u16* Pr = PrAll + (size_t)m * 1024;
    __shared__ float klpart[32];
    int grp = tid >> 5, c = tid & 31;
#pragma unroll
    for (int it = 0; it < 4; ++it) {
        int l = it * 8 + grp;
        float po = bfu2f(Po[l * 32 + c]);
        float pr = bfu2f(Pr[l * 32 + c]);
        float mv = po, mq = pr;
#pragma unroll
        for (int o = 16; o > 0; o >>= 1) {
            mv = fmaxf(mv, __shfl_xor(mv, o, 32));
            mq = fmaxf(mq, __shfl_xor(mq, o, 32));
        }
        float ep = expf(po - mv), eq = expf(pr - mq);
        float sp = ep, sq = eq;
#pragma unroll
        for (int o = 16; o > 0; o >>= 1) { sp += __shfl_xor(sp, o, 32); sq += __shfl_xor(sq, o, 32); }
        float logp = po - mv - logf(sp);
        float logq = pr - mq - logf(sq);
        float klc = (ep / sp) * (logp - logq);
#pragma unroll
        for (int o = 16; o > 0; o >>= 1) klc += __shfl_xor(klc, o, 32);
        if (c == 0) klpart[l] = klc;
    }
    __syncthreads();
    if (tid == 0) {
        float kl = 0.f;
        for (int l = 0; l < 32; ++l) kl += klpart[l];
        klrow[m] = fmaxf(kl, 1.0f);
    }
}

__global__ __launch_bounds__(256) void k_latsum(const u16* __restrict__ LatB, const float* __restrict__ db1,
                                                const int* __restrict__ latidx_all, u16* __restrict__ latsum) {
    int m = blockIdx.x, tid = threadIdx.x;
    __shared__ int idxs[32];
    if (tid < 32) idxs[tid] = latidx_all[(size_t)m * 32 + tid];
    __syncthreads();
    const int j4 = tid * 4;
    f32x4 s = *(const f32x4*)(db1 + j4);
#pragma unroll
    for (int l = 0; l < 32; ++l) {
        s16x4 v = *(const s16x4*)(LatB + (size_t)((l << 5) + idxs[l]) * 1024 + j4);
        s[0] += bfu2f((u16)v[0]); s[1] += bfu2f((u16)v[1]);
        s[2] += bfu2f((u16)v[2]); s[3] += bfu2f((u16)v[3]);
    }
    s16x4 o;
    o[0] = (short)f2bfu(s[0]); o[1] = (short)f2bfu(s[1]);
    o[2] = (short)f2bfu(s[2]); o[3] = (short)f2bfu(s[3]);
    *(s16x4*)(latsum + (size_t)m * 1024 + j4) = o;
}

// NOTE: MUST be launched with 256 threads (r3-r5 bug: was <<<1,1>>>)
__global__ __launch_bounds__(256) void k_finalize(const double* __restrict__ acc,
                                                  const float* __restrict__ klrow, float* __restrict__ out) {
    __shared__ double ps[256];
    int tid = threadIdx.x;
    double s = 0.0;
    for (int i = tid; i < 16128; i += 256) s += (double)klrow[i];
    ps[tid] = s;
    __syncthreads();
    for (int o = 128; o > 0; o >>= 1) {
        if (tid < o) ps[tid] += ps[tid + o];
        __syncthreads();
    }
    if (tid == 0) out[0] = (float)(acc[0] / 33030144.0 + ps[0] / 16128.0);
}

// ---------------------------------------------------------------------------
extern "C" void kernel_launch(void* const* d_in, const int* in_sizes, int n_in,
                              void* d_out, int out_size, void* d_ws, size_t ws_size,
                              hipStream_t stream) {
    const float* zs      = (const float*)d_in[0];
    const float* actions = (const float*)d_in[1];
    const float* zmean   = (const float*)d_in[2];
    const float* zstd    = (const float*)d_in[3];
    const float* encW    = (const float*)d_in[4];
    const float* encb    = (const float*)d_in[5];
    const float* preW    = (const float*)d_in[6];
    const float* preb    = (const float*)d_in[7];
    const float* Wih     = (const float*)d_in[8];
    const float* Whh     = (const float*)d_in[9];
    const float* bih     = (const float*)d_in[10];
    const float* bhh     = (const float*)d_in[11];
    const float* tW1     = (const float*)d_in[12];
    const float* tb1     = (const float*)d_in[13];
    const float* tW2     = (const float*)d_in[14];
    const float* tb2     = (const float*)d_in[15];
    const float* rW1     = (const float*)d_in[16];
    const float* rb1     = (const float*)d_in[17];
    const float* rW2     = (const float*)d_in[18];
    const float* rb2     = (const float*)d_in[19];
    const float* dW1     = (const float*)d_in[20];
    const float* db1     = (const float*)d_in[21];
    const float* dW2     = (const float*)d_in[22];
    const float* db2     = (const float*)d_in[23];

    char* W = (char*)d_ws;
    size_t off = 0;
    auto take = [&](size_t b) { char* p = W + off; off += (b + 255) & ~(size_t)255; return p; };

    double* accum  = (double*)take(16);
    u16* encWbt = (u16*)take((size_t)1024 * 2048 * 2);
    u16* WihB   = (u16*)take((size_t)6144 * 1024 * 2);
    u16* WhhB   = (u16*)take((size_t)6144 * 2048 * 2);
    u16* l1B    = (u16*)take((size_t)2048 * 2048 * 2);   // [tW1t | rW1at]
    u16* tW2bt  = (u16*)take((size_t)1024 * 1024 * 2);
    u16* rW2bt  = (u16*)take((size_t)1024 * 1024 * 2);
    u16* rW1bbt = (u16*)take((size_t)1024 * 1024 * 2);
    u16* dW1abt = (u16*)take((size_t)1024 * 2048 * 2);
    u16* dW2bt  = (u16*)take((size_t)2048 * 1024 * 2);
    u16* PreLatB = (u16*)take((size_t)1024 * 1024 * 2);
    u16* LatB    = (u16*)take((size_t)1024 * 1024 * 2);
    u16* Hall   = (u16*)take((size_t)63 * 256 * 2048 * 2);
    int* latidx = (int*)take((size_t)63 * 256 * 32 * 4);
    u16* embR   = (u16*)take((size_t)16384 * 1024 * 2);   // scan emb; then PrAll; then latsum
    u16* enc    = (u16*)take((size_t)16384 * 1024 * 2);   // encoder out; then PoAll
    float* klrow = (float*)take((size_t)16128 * 4);
    u16* GHb    = (u16*)take((size_t)2 * 256 * 6144 * 2);
    float* hf32 = (float*)take((size_t)256 * 2048 * 4);
    u16* x_bf   = (u16*)take((size_t)256 * 1024 * 2);
    u16* p1q1   = (u16*)take((size_t)256 * 1024 * 2);
    char* X     = take((size_t)17825792);                  // 17 MB: flatc/Xp/d1

    u16* flatc = (u16*)X;                                  // 4096 x 2048 per pass
    u16* Xp    = (u16*)X;                                  // 8064 x 1024 per half
    u16* d1    = (u16*)X;                                  // 8064 x 1024 per half
    u16* PoAll = enc;                                      // enc dead after embR GEMM
    u16* PrAll = embR;                                     // embR dead after scan; consumed by k_kl before latsum

    k_init<<<1, 1, 0, stream>>>(accum);

    // weight conversion
    k_cast<<<6144, 256, 0, stream>>>(Wih, WihB, 6291456 / 4);
    k_cast<<<12288, 256, 0, stream>>>(Whh, WhhB, 12582912 / 4);
    k_cast<<<1024, 256, 0, stream>>>(preW, PreLatB, 262144);
    k_cast<<<1024, 256, 0, stream>>>(dW1 + (size_t)2048 * 1024, LatB, 262144);
    k_transpose<<<dim3(64, 32), dim3(32, 8), 0, stream>>>(encW, 1024, encWbt, 2048);
    k_transpose<<<dim3(64, 32), dim3(32, 8), 0, stream>>>(tW1, 1024, l1B, 2048);
    k_transpose<<<dim3(64, 32), dim3(32, 8), 0, stream>>>(rW1, 1024, l1B + (size_t)1024 * 2048, 2048);
    k_transpose<<<dim3(32, 32), dim3(32, 8), 0, stream>>>(tW2, 1024, tW2bt, 1024);
    k_transpose<<<dim3(32, 32), dim3(32, 8), 0, stream>>>(rW2, 1024, rW2bt, 1024);
    k_transpose<<<dim3(32, 32), dim3(32, 8), 0, stream>>>(rW1 + (size_t)2048 * 1024, 1024, rW1bbt, 1024);
    k_transpose<<<dim3(64, 32), dim3(32, 8), 0, stream>>>(dW1, 1024, dW1abt, 2048);
    k_transpose<<<dim3(32, 64), dim3(32, 8), 0, stream>>>(dW2, 2048, dW2bt, 1024);

    // phase 1: encoder (4 passes of 4096 rows; 64² gemmS + T1 swizzle)
    for (int pass = 0; pass < 4; ++pass) {
        k_prep<<<8192, 256, 0, stream>>>(zs + (size_t)pass * 4096 * 2048, zmean, zstd, flatc);
        GP e{}; e.A = flatc; e.lda = 2048; e.Bt = encWbt; e.Cb = enc + (size_t)pass * 4096 * 1024;
        e.ldc = 1024; e.bias = encb; e.K = 2048; e.gridN = 16;
        gemmS<2, 2, 2, 2, 1, 1, true><<<dim3(1024), 256, 0, stream>>>(e, e, 1024);
    }
    {
        GP e{}; e.A = enc; e.lda = 1024; e.Bt = rW1bbt; e.Cb = embR; e.ldc = 1024;
        e.bias = rb1; e.K = 1024; e.gridN = 16;
        gemmS<2, 2, 2, 2, 2, 2, true><<<dim3(4096), 256, 0, stream>>>(e, e, 4096);
    }

    // phase 2: sequential scan (post-only path; prior deferred)
    k_xpre0<<<256, 256, 0, stream>>>(preW, preb, actions, x_bf);
    for (int t = 0; t < 63; ++t) {
        // k1: gx + GRU -> h_t (512 blocks, 8 waves/CU)
        if (t == 0)
            k_gates<true><<<512, 256, 0, stream>>>(x_bf, WihB, bih, bhh, GHb, hf32, Hall);
        else
            k_gates<false><<<512, 256, 0, stream>>>(x_bf, WihB, bih, bhh, GHb + (size_t)(t & 1) * 256 * 6144,
                                                    hf32, Hall + (size_t)t * 256 * 2048);
        // k2: gh(t+1) (bf16) || l1-post(t) — 8-wave blocks (512 thr), 448 tiles
        {
            GP pa{}; pa.A = Hall + (size_t)t * 256 * 2048; pa.lda = 2048; pa.Bt = WhhB;
            pa.Cb = GHb + (size_t)((t + 1) & 1) * 256 * 6144; pa.ldc = 6144; pa.bias = bhh;
            pa.K = 2048; pa.gridN = 96;
            GP pb{}; pb.A = Hall + (size_t)t * 256 * 2048; pb.lda = 2048;
            pb.Bt = l1B + (size_t)1024 * 2048; pb.Cb = p1q1; pb.ldc = 1024;
            pb.aux = embR + (size_t)(t + 1) * 1024; pb.auxld = 65536;
            pb.K = 2048; pb.gridN = 16;
            int nA = (t < 62) ? 384 : 0;
            gemmS<2, 4, 2, 1, 7, 4><<<dim3(nA + 64), 512, 0, stream>>>(pa, pb, nA);
        }
        // k3: q-post (BM=32, 128 blocks) -> PoAll[t] + fused argmax -> latidx[t]
        {
            GP q{}; q.A = p1q1; q.lda = 1024; q.Bt = rW2bt; q.ldc = 1024;
            q.Cb = PoAll + (size_t)t * 256 * 1024; q.bias = rb2; q.K = 1024; q.gridN = 16;
            q.idx = latidx + (size_t)t * 256 * 32;
            gemmS<2, 2, 1, 2, 8, 8><<<dim3(128), 256, 0, stream>>>(q, q, 128);
        }
        // k4: next x from latidx
        if (t < 62)
            k_xgen<<<256, 256, 0, stream>>>(latidx + (size_t)t * 256 * 32,
                                            PreLatB, preW, preb, actions, x_bf, t + 1);
    }

    // phase 3a: batched prior (2 halves of 8064 rows; 64² + T1 swizzle) + KL
    for (int half = 0; half < 2; ++half) {
        int m0 = half * 8064;
        GP e{}; e.A = Hall + (size_t)m0 * 2048; e.lda = 2048; e.Bt = l1B; e.Cb = Xp; e.ldc = 1024;
        e.bias = tb1; e.K = 2048; e.gridN = 16;
        gemmS<2, 2, 2, 2, 1, 1, true><<<dim3(2016), 256, 0, stream>>>(e, e, 2016);
        GP q{}; q.A = Xp; q.lda = 1024; q.Bt = tW2bt; q.Cb = PrAll + (size_t)m0 * 1024; q.ldc = 1024;
        q.bias = tb2; q.K = 1024; q.gridN = 16;
        gemmS<2, 2, 2, 2, 2, 2, true><<<dim3(2016), 256, 0, stream>>>(q, q, 2016);
    }
    k_kl<<<16128, 256, 0, stream>>>(PoAll, PrAll, klrow);

    // phase 3b: decoder + fused recon (2 halves; 64² + T1 swizzle)
    k_latsum<<<16128, 256, 0, stream>>>(LatB, db1, latidx, embR);
    for (int half = 0; half < 2; ++half) {
        int m0 = half * 8064;
        GP d{}; d.A = Hall + (size_t)m0 * 2048; d.lda = 2048; d.Bt = dW1abt; d.Cb = d1; d.ldc = 1024;
        d.aux = embR + (size_t)m0 * 1024; d.auxld = 1024; d.K = 2048; d.gridN = 16;
        gemmS<2, 2, 2, 2, 4, 4, true><<<dim3(2016), 256, 0, stream>>>(d, d, 2016);
        GP d2{}; d2.A = d1; d2.lda = 1024; d2.Bt = dW2bt; d2.ldc = 2048; d2.bias = db2;
        d2.zs = zs; d2.zmean = zmean; d2.zstd = zstd; d2.accum = accum; d2.K = 1024; d2.gridN = 32;
        d2.rbase = m0;
        gemmS<2, 2, 2, 2, 5, 5, true><<<dim3(4032), 256, 0, stream>>>(d2, d2, 4032);
    }
    k_finalize<<<1, 256, 0, stream>>>(accum, klrow, (float*)d_out);
}

// Round 12
// 3236.905 us; speedup vs baseline: 1.1548x; 1.0264x over previous
//
#include <hip/hip_runtime.h>
#include <hip/hip_bf16.h>
#include <math.h>

typedef unsigned short u16;
typedef __attribute__((ext_vector_type(8))) short s16x8;
typedef __attribute__((ext_vector_type(4))) short s16x4;
typedef __attribute__((ext_vector_type(4))) float f32x4;

#define DEVI static __device__ __forceinline__

DEVI u16 f2bfu(float f) {
    unsigned u = __float_as_uint(f);
    unsigned r = (u + 0x7fffu + ((u >> 16) & 1u)) >> 16;
    return (u16)r;
}
DEVI float bfu2f(u16 u) { return __uint_as_float(((unsigned)u) << 16); }
DEVI float eluf(float x) { return x > 0.f ? x : (expf(x) - 1.f); }
DEVI float sigm(float x) { return 1.f / (1.f + expf(-x)); }

#define GLOAD16(gsrc, ldst)                                                            \
    __builtin_amdgcn_global_load_lds(                                                  \
        (__attribute__((address_space(1))) void*)(void*)(gsrc),                        \
        (__attribute__((address_space(3))) void*)(ldst), 16, 0, 0)

template <int N> DEVI void vmwait();
template <> DEVI void vmwait<0>() { asm volatile("s_waitcnt vmcnt(0)" ::: "memory"); }
template <> DEVI void vmwait<1>() { asm volatile("s_waitcnt vmcnt(1)" ::: "memory"); }
template <> DEVI void vmwait<2>() { asm volatile("s_waitcnt vmcnt(2)" ::: "memory"); }
template <> DEVI void vmwait<3>() { asm volatile("s_waitcnt vmcnt(3)" ::: "memory"); }
template <> DEVI void vmwait<4>() { asm volatile("s_waitcnt vmcnt(4)" ::: "memory"); }
template <> DEVI void vmwait<5>() { asm volatile("s_waitcnt vmcnt(5)" ::: "memory"); }
template <> DEVI void vmwait<6>() { asm volatile("s_waitcnt vmcnt(6)" ::: "memory"); }

struct GP {
    const u16* A; int lda;
    const u16* Bt;
    float* Cf; u16* Cb; int ldc;
    const float* bias;
    const u16* aux; int auxld;
    const float* zs;               // EPI5
    const float* zmean; const float* zstd;
    double* accum;
    int* idx;                      // EPI8: argmax out
    int K; int gridN; int rbase;
};

// ---------------------------------------------------------------------------
// gemmS: BK=64, T2 XOR-swizzle, 3-deep counted-vmcnt pipeline. The only GEMM.
// Regime map (r8-r11): scan launches (few blocks) are occupancy-bound — keep
// block count >= 256; fixed-phase launches (many blocks) are density-bound —
// use 128x128 8-wave tiles. SWZ = T1 XCD tile remap (needs nA%8==0).
// ---------------------------------------------------------------------------
template <int EPI, int MF, int NF>
DEVI void epiS(const GP& p, f32x4 (&acc)[MF][NF], int r0, int c0, int wm, int wn,
               int lrow4, int lcol) {
#pragma unroll
    for (int mf = 0; mf < MF; ++mf) {
        int rowb = r0 + (wm * MF + mf) * 16 + lrow4;
#pragma unroll
        for (int nf = 0; nf < NF; ++nf) {
            int col = c0 + (wn * NF + nf) * 16 + lcol;
#pragma unroll
            for (int j = 0; j < 4; ++j) {
                float v = acc[mf][nf][j];
                int r = rowb + j;
                if constexpr (EPI == 1) {
                    p.Cb[(size_t)r * p.ldc + col] = f2bfu(eluf(v + p.bias[col]));
                } else if constexpr (EPI == 2) {
                    p.Cb[(size_t)r * p.ldc + col] = f2bfu(v + p.bias[col]);
                } else if constexpr (EPI == 4) {
                    p.Cb[(size_t)r * p.ldc + col] = f2bfu(eluf(v + bfu2f(p.aux[(size_t)r * p.auxld + col])));
                } else if constexpr (EPI == 7) {
                    p.Cb[(size_t)r * p.ldc + col] = f2bfu(v + p.bias[col]);
                }
            }
        }
    }
}

template <int WM, int WN, int MF, int NF, int EPIa, int EPIb, bool SWZ = false>
__global__ __launch_bounds__(WM * WN * 64) void gemmS(GP pa, GP pb, int nA) {
    constexpr int NT = WM * WN * 64;
    constexpr int BM = WM * MF * 16, BN = WN * NF * 16;
    constexpr int ABY = BM * 128, BBY = BN * 128;
    constexpr int LPT = (ABY + BBY) / (NT * 16);

    const int tid = threadIdx.x, w = tid >> 6, lane = tid & 63;
    const bool isA = (int)blockIdx.x < nA;
    GP p = isA ? pa : pb;
    int bid = isA ? blockIdx.x : blockIdx.x - nA;
    if constexpr (SWZ) bid = (bid & 7) * (nA >> 3) + (bid >> 3);   // T1, needs nA%8==0
    const int bn = bid % p.gridN, bm = bid / p.gridN;
    const int r0 = bm * BM, c0 = bn * BN;
    const int wm = w / WN, wn = w % WN;

    __shared__ __attribute__((aligned(16))) char sm[3 * (ABY + BBY)];
    __shared__ float ps_[WM * WN];

    auto stage = [&](int kt, int buf) {
        char* s = sm + buf * (ABY + BBY);
#pragma unroll
        for (int it = 0; it < ABY / (NT * 16); ++it) {
            int bo = it * (NT * 16) + tid * 16;
            int row = bo >> 7, kb = bo & 127;
            int kbs = kb ^ ((row & 7) << 4);                       // pre-swizzled source
            GLOAD16(p.A + (size_t)(r0 + row) * p.lda + kt * 64 + (kbs >> 1), s + bo);
        }
        char* sb = s + ABY;
#pragma unroll
        for (int it = 0; it < BBY / (NT * 16); ++it) {
            int bo = it * (NT * 16) + tid * 16;
            int row = bo >> 7, kb = bo & 127;
            int kbs = kb ^ ((row & 7) << 4);
            GLOAD16(p.Bt + (size_t)(c0 + row) * p.K + kt * 64 + (kbs >> 1), sb + bo);
        }
    };

    f32x4 acc[MF][NF];
#pragma unroll
    for (int mf = 0; mf < MF; ++mf)
#pragma unroll
        for (int nf = 0; nf < NF; ++nf) acc[mf][nf] = (f32x4){0.f, 0.f, 0.f, 0.f};

    const int nk = p.K >> 6;
    stage(0, 0);
    stage(1, 1);
    int b0 = 0, b1 = 1, b2 = 2;
    for (int kt = 0; kt < nk; ++kt) {
        if (kt < nk - 1) vmwait<LPT>(); else vmwait<0>();
        __builtin_amdgcn_sched_barrier(0);
        __builtin_amdgcn_s_barrier();
        if (kt + 2 < nk) stage(kt + 2, b2);
        const char* s = sm + b0 * (ABY + BBY);
#pragma unroll
        for (int ks = 0; ks < 2; ++ks) {
            const int kb = ks * 64 + ((lane >> 4) << 4);
            s16x8 aF[MF], bF[NF];
#pragma unroll
            for (int mf = 0; mf < MF; ++mf) {
                int rt = (wm * MF + mf) * 16 + (lane & 15);
                aF[mf] = *(const s16x8*)(s + rt * 128 + (kb ^ ((rt & 7) << 4)));
            }
#pragma unroll
            for (int nf = 0; nf < NF; ++nf) {
                int rt = (wn * NF + nf) * 16 + (lane & 15);
                bF[nf] = *(const s16x8*)(s + ABY + rt * 128 + (kb ^ ((rt & 7) << 4)));
            }
#pragma unroll
            for (int mf = 0; mf < MF; ++mf)
#pragma unroll
                for (int nf = 0; nf < NF; ++nf)
                    acc[mf][nf] = __builtin_amdgcn_mfma_f32_16x16x32_bf16(aF[mf], bF[nf], acc[mf][nf], 0, 0, 0);
        }
        int t_ = b0; b0 = b1; b1 = b2; b2 = t_;
    }

    const int lrow4 = (lane >> 4) << 2, lcol = lane & 15;
    if constexpr (EPIa == 8) {
        // requires NF==2: wave (wm,wn) owns one 32-class latent group
        const int lat = (c0 >> 5) + wn;
#pragma unroll
        for (int mf = 0; mf < MF; ++mf) {
#pragma unroll
            for (int j = 0; j < 4; ++j) {
                int r = r0 + (wm * MF + mf) * 16 + lrow4 + j;
                int col0 = c0 + wn * 32 + lcol;
                float v0 = acc[mf][0][j] + p.bias[col0];
                float v1 = acc[mf][1][j] + p.bias[col0 + 16];
                p.Cb[(size_t)r * p.ldc + col0] = f2bfu(v0);
                p.Cb[(size_t)r * p.ldc + col0 + 16] = f2bfu(v1);
                float mv; int mi;
                if (v1 > v0) { mv = v1; mi = lcol + 16; } else { mv = v0; mi = lcol; }
#pragma unroll
                for (int o = 8; o >= 1; o >>= 1) {
                    float ov = __shfl_xor(mv, o, 64);
                    int oi = __shfl_xor(mi, o, 64);
                    if (ov > mv || (ov == mv && oi < mi)) { mv = ov; mi = oi; }
                }
                if (lcol == 0) p.idx[(size_t)r * 32 + lat] = mi;
            }
        }
    } else if constexpr (EPIa == 5) {
        float lsum = 0.f;
#pragma unroll
        for (int mf = 0; mf < MF; ++mf) {
            int rowb = r0 + (wm * MF + mf) * 16 + lrow4;
#pragma unroll
            for (int nf = 0; nf < NF; ++nf) {
                int col = c0 + (wn * NF + nf) * 16 + lcol;
#pragma unroll
                for (int j = 0; j < 4; ++j) {
                    float v = acc[mf][nf][j] + p.bias[col];
                    int R = rowb + j + p.rbase;
                    int tt = R >> 8, b = R & 255;
                    int ch = col >> 9;
                    float z = (p.zs[((size_t)b * 64 + tt + 1) * 2048 + col] - p.zmean[ch]) / p.zstd[ch];
                    float d = v - z;
                    lsum += d * d;
                }
            }
        }
#pragma unroll
        for (int o = 32; o > 0; o >>= 1) lsum += __shfl_down(lsum, o, 64);
        if (lane == 0) ps_[w] = lsum;
        __syncthreads();
        if (tid == 0) {
            double s = 0.0;
#pragma unroll
            for (int i = 0; i < WM * WN; ++i) s += (double)ps_[i];
            atomicAdd(p.accum, s);
        }
    } else {
        if (isA) epiS<EPIa, MF, NF>(p, acc, r0, c0, wm, wn, lrow4, lcol);
        else     epiS<EPIb, MF, NF>(p, acc, r0, c0, wm, wn, lrow4, lcol);
    }
}

// ---------------------------------------------------------------------------
// k_gates: gx (K=1024) + full GRU epilogue; 3-deep pipeline.
// 512 blocks (bm 8 x bn 64), BM=32 x 32-col gate tile, TSZ=16KB, LPT=4.
// ---------------------------------------------------------------------------
template <bool FIRST>
__global__ __launch_bounds__(256) void k_gates(const u16* __restrict__ X, const u16* __restrict__ WihB,
                                               const float* __restrict__ bih, const float* __restrict__ bhh,
                                               const u16* __restrict__ GHb, float* __restrict__ hf32,
                                               u16* __restrict__ hallT) {
    constexpr int ABY = 32 * 128;       // 4 KB
    constexpr int BTB = 32 * 128;       // 4 KB per gate tile
    constexpr int TSZ = ABY + 3 * BTB;  // 16 KB
    const int tid = threadIdx.x, w = tid >> 6, lane = tid & 63;
    const int bm = blockIdx.x >> 6, bn = blockIdx.x & 63;
    const int r0 = bm * 32, c0 = bn * 32;
    const int wm = w >> 1, wn = w & 1;

    __shared__ __attribute__((aligned(16))) char sm[3 * TSZ];

    auto stage = [&](int kt, int buf) {
        char* s = sm + buf * TSZ;
        {
            int bo = tid * 16;                 // 256*16 = 4KB = ABY exactly
            int row = bo >> 7, kb = bo & 127;
            int kbs = kb ^ ((row & 7) << 4);
            GLOAD16(X + (size_t)(r0 + row) * 1024 + kt * 64 + (kbs >> 1), s + bo);
        }
        char* sb = s + ABY;
#pragma unroll
        for (int g = 0; g < 3; ++g) {
            int bo = tid * 16;
            int row = bo >> 7, kb = bo & 127;
            int kbs = kb ^ ((row & 7) << 4);
            GLOAD16(WihB + (size_t)(g * 2048 + c0 + row) * 1024 + kt * 64 + (kbs >> 1), sb + g * BTB + bo);
        }
    };

    f32x4 acc[3];
#pragma unroll
    for (int g = 0; g < 3; ++g) acc[g] = (f32x4){0.f, 0.f, 0.f, 0.f};

    stage(0, 0);
    stage(1, 1);
    int b0 = 0, b1 = 1, b2 = 2;
    for (int kt = 0; kt < 16; ++kt) {
        if (kt < 15) vmwait<4>(); else vmwait<0>();
        __builtin_amdgcn_sched_barrier(0);
        __builtin_amdgcn_s_barrier();
        if (kt + 2 < 16) stage(kt + 2, b2);
        const char* s = sm + b0 * TSZ;
#pragma unroll
        for (int ks = 0; ks < 2; ++ks) {
            const int kb = ks * 64 + ((lane >> 4) << 4);
            s16x8 aF, bF[3];
            {
                int rt = wm * 16 + (lane & 15);
                aF = *(const s16x8*)(s + rt * 128 + (kb ^ ((rt & 7) << 4)));
            }
#pragma unroll
            for (int g = 0; g < 3; ++g) {
                int rt = wn * 16 + (lane & 15);
                bF[g] = *(const s16x8*)(s + ABY + g * BTB + rt * 128 + (kb ^ ((rt & 7) << 4)));
            }
#pragma unroll
            for (int g = 0; g < 3; ++g)
                acc[g] = __builtin_amdgcn_mfma_f32_16x16x32_bf16(aF, bF[g], acc[g], 0, 0, 0);
        }
        int t_ = b0; b0 = b1; b1 = b2; b2 = t_;
    }

    const int lrow4 = (lane >> 4) << 2, lcol = lane & 15;
    const int cc = c0 + wn * 16 + lcol;
    {
        int rr0 = r0 + wm * 16 + lrow4;
#pragma unroll
        for (int j = 0; j < 4; ++j) {
            int rr = rr0 + j;
            float xr = acc[0][j] + bih[cc];
            float xz = acc[1][j] + bih[2048 + cc];
            float xn = acc[2][j] + bih[4096 + cc];
            float hr_, hz_, hn_;
            if (FIRST) { hr_ = bhh[cc]; hz_ = bhh[2048 + cc]; hn_ = bhh[4096 + cc]; }
            else {
                const u16* g = GHb + (size_t)rr * 6144;
                hr_ = bfu2f(g[cc]); hz_ = bfu2f(g[2048 + cc]); hn_ = bfu2f(g[4096 + cc]);
            }
            float r = sigm(xr + hr_);
            float u = sigm(xz + hz_);
            float n = tanhf(xn + r * hn_);
            float hold = FIRST ? 0.f : hf32[(size_t)rr * 2048 + cc];
            float h = (1.f - u) * n + u * hold;
            hf32[(size_t)rr * 2048 + cc] = h;
            hallT[(size_t)rr * 2048 + cc] = f2bfu(h);
        }
    }
}

// ---------------------------------------------------------------------------
// small kernels
// ---------------------------------------------------------------------------
__global__ void k_init(double* acc) { acc[0] = 0.0; acc[1] = 0.0; }

__global__ void k_cast(const float* __restrict__ src, u16* __restrict__ dst, int n4) {
    int i = blockIdx.x * 256 + threadIdx.x;
    if (i >= n4) return;
    f32x4 v = *(const f32x4*)(src + (size_t)i * 4);
    s16x4 o;
    o[0] = (short)f2bfu(v[0]); o[1] = (short)f2bfu(v[1]);
    o[2] = (short)f2bfu(v[2]); o[3] = (short)f2bfu(v[3]);
    *(s16x4*)(dst + (size_t)i * 4) = o;
}

__global__ void k_transpose(const float* __restrict__ src, int sld, u16* __restrict__ dst, int K) {
    __shared__ float tile[32][33];
    int k0 = blockIdx.x * 32, n0 = blockIdx.y * 32;
    for (int r = threadIdx.y; r < 32; r += 8)
        tile[r][threadIdx.x] = src[(size_t)(k0 + r) * sld + n0 + threadIdx.x];
    __syncthreads();
    for (int r = threadIdx.y; r < 32; r += 8)
        dst[(size_t)(n0 + r) * K + k0 + threadIdx.x] = f2bfu(tile[threadIdx.x][r]);
}

__global__ void k_prep(const float* __restrict__ zsp, const float* __restrict__ zm,
                       const float* __restrict__ zsd, u16* __restrict__ flat) {
    size_t i = ((size_t)blockIdx.x * 256 + threadIdx.x) * 4;
    f32x4 v = *(const f32x4*)(zsp + i);
    int ch = ((int)(i >> 9)) & 3;
    float m = zm[ch], s = zsd[ch];
    s16x4 o;
    o[0] = (short)f2bfu((v[0] - m) / s); o[1] = (short)f2bfu((v[1] - m) / s);
    o[2] = (short)f2bfu((v[2] - m) / s); o[3] = (short)f2bfu((v[3] - m) / s);
    *(s16x4*)(flat + i) = o;
}

__global__ __launch_bounds__(256) void k_xpre0(const float* __restrict__ preW, const float* __restrict__ preb,
                                               const float* __restrict__ actions, u16* __restrict__ xout) {
    int b = blockIdx.x, tid = threadIdx.x;
    __shared__ float as[3];
    if (tid < 3) as[tid] = actions[(size_t)b * 64 * 3 + tid];
    __syncthreads();
    for (int j = tid; j < 1024; j += 256) {
        float s = preb[j] + as[0] * preW[1024 * 1024 + j] + as[1] * preW[1025 * 1024 + j] + as[2] * preW[1026 * 1024 + j];
        xout[(b << 10) + j] = f2bfu(eluf(s));
    }
}

// x-gen only (argmax fused into k3's EPI8 epilogue)
__global__ __launch_bounds__(256) void k_xgen(const int* __restrict__ latidx_t,
                                              const u16* __restrict__ PreLatB, const float* __restrict__ preW,
                                              const float* __restrict__ preb,
                                              const float* __restrict__ actions, u16* __restrict__ xout,
                                              int tnext) {
    int b = blockIdx.x, tid = threadIdx.x;
    __shared__ int idxs[32];
    __shared__ float as[3];
    if (tid < 32) idxs[tid] = latidx_t[(b << 5) + tid];
    if (tid >= 64 && tid < 67) as[tid - 64] = actions[((size_t)b * 64 + tnext) * 3 + (tid - 64)];
    __syncthreads();
    const int j4 = tid * 4;
    f32x4 s = *(const f32x4*)(preb + j4);
#pragma unroll
    for (int cc = 0; cc < 3; ++cc) {
        f32x4 wv = *(const f32x4*)(preW + (size_t)(1024 + cc) * 1024 + j4);
        s[0] += as[cc] * wv[0]; s[1] += as[cc] * wv[1];
        s[2] += as[cc] * wv[2]; s[3] += as[cc] * wv[3];
    }
#pragma unroll
    for (int l = 0; l < 32; ++l) {
        s16x4 v = *(const s16x4*)(PreLatB + (size_t)((l << 5) + idxs[l]) * 1024 + j4);
        s[0] += bfu2f((u16)v[0]); s[1] += bfu2f((u16)v[1]);
        s[2] += bfu2f((u16)v[2]); s[3] += bfu2f((u16)v[3]);
    }
    s16x4 o;
    o[0] = (short)f2bfu(eluf(s[0])); o[1] = (short)f2bfu(eluf(s[1]));
    o[2] = (short)f2bfu(eluf(s[2])); o[3] = (short)f2bfu(eluf(s[3]));
    *(s16x4*)(xout + (b << 10) + j4) = o;
}

// batched KL: one block per (t,b) row; reads bf16 post/prior logits
__global__ __launch_bounds__(256) void k_kl(const u16* __restrict__ PoAll, const u16* __restrict__ PrAll,
                                            float* __restrict__ klrow) {
    int m = blockIdx.x, tid = threadIdx.x;
    const u16* Po = PoAll + (size_t)m * 1024;
    const u16* Pr = PrAll + (size_t)m * 1024;
    __shared__ float klpart[32];
    int grp = tid >> 5, c = tid & 31;
#pragma unroll
    for (int it = 0; it < 4; ++it) {
        int l = it * 8 + grp;
        float po = bfu2f(Po[l * 32 + c]);
        float pr = bfu2f(Pr[l * 32 + c]);
        float mv = po, mq = pr;
#pragma unroll
        for (int o = 16; o > 0; o >>= 1) {
            mv = fmaxf(mv, __shfl_xor(mv, o, 32));
            mq = fmaxf(mq, __shfl_xor(mq, o, 32));
        }
        float ep = expf(po - mv), eq = expf(pr - mq);
        float sp = ep, sq = eq;
#pragma unroll
        for (int o = 16; o > 0; o >>= 1) { sp += __shfl_xor(sp, o, 32); sq += __shfl_xor(sq, o, 32); }
        float logp = po - mv - logf(sp);
        float logq = pr - mq - logf(sq);
        float klc = (ep / sp) * (logp - logq);
#pragma unroll
        for (int o = 16; o > 0; o >>= 1) klc += __shfl_xor(klc, o, 32);
        if (c == 0) klpart[l] = klc;
    }
    __syncthreads();
    if (tid == 0) {
        float kl = 0.f;
        for (int l = 0; l < 32; ++l) kl += klpart[l];
        klrow[m] = fmaxf(kl, 1.0f);
    }
}

__global__ __launch_bounds__(256) void k_latsum(const u16* __restrict__ LatB, const float* __restrict__ db1,
                                                const int* __restrict__ latidx_all, u16* __restrict__ latsum) {
    int m = blockIdx.x, tid = threadIdx.x;
    __shared__ int idxs[32];
    if (tid < 32) idxs[tid] = latidx_all[(size_t)m * 32 + tid];
    __syncthreads();
    const int j4 = tid * 4;
    f32x4 s = *(const f32x4*)(db1 + j4);
#pragma unroll
    for (int l = 0; l < 32; ++l) {
        s16x4 v = *(const s16x4*)(LatB + (size_t)((l << 5) + idxs[l]) * 1024 + j4);
        s[0] += bfu2f((u16)v[0]); s[1] += bfu2f((u16)v[1]);
        s[2] += bfu2f((u16)v[2]); s[3] += bfu2f((u16)v[3]);
    }
    s16x4 o;
    o[0] = (short)f2bfu(s[0]); o[1] = (short)f2bfu(s[1]);
    o[2] = (short)f2bfu(s[2]); o[3] = (short)f2bfu(s[3]);
    *(s16x4*)(latsum + (size_t)m * 1024 + j4) = o;
}

// NOTE: MUST be launched with 256 threads (r3-r5 bug: was <<<1,1>>>)
__global__ __launch_bounds__(256) void k_finalize(const double* __restrict__ acc,
                                                  const float* __restrict__ klrow, float* __restrict__ out) {
    __shared__ double ps[256];
    int tid = threadIdx.x;
    double s = 0.0;
    for (int i = tid; i < 16128; i += 256) s += (double)klrow[i];
    ps[tid] = s;
    __syncthreads();
    for (int o = 128; o > 0; o >>= 1) {
        if (tid < o) ps[tid] += ps[tid + o];
        __syncthreads();
    }
    if (tid == 0) out[0] = (float)(acc[0] / 33030144.0 + ps[0] / 16128.0);
}

// ---------------------------------------------------------------------------
extern "C" void kernel_launch(void* const* d_in, const int* in_sizes, int n_in,
                              void* d_out, int out_size, void* d_ws, size_t ws_size,
                              hipStream_t stream) {
    const float* zs      = (const float*)d_in[0];
    const float* actions = (const float*)d_in[1];
    const float* zmean   = (const float*)d_in[2];
    const float* zstd    = (const float*)d_in[3];
    const float* encW    = (const float*)d_in[4];
    const float* encb    = (const float*)d_in[5];
    const float* preW    = (const float*)d_in[6];
    const float* preb    = (const float*)d_in[7];
    const float* Wih     = (const float*)d_in[8];
    const float* Whh     = (const float*)d_in[9];
    const float* bih     = (const float*)d_in[10];
    const float* bhh     = (const float*)d_in[11];
    const float* tW1     = (const float*)d_in[12];
    const float* tb1     = (const float*)d_in[13];
    const float* tW2     = (const float*)d_in[14];
    const float* tb2     = (const float*)d_in[15];
    const float* rW1     = (const float*)d_in[16];
    const float* rb1     = (const float*)d_in[17];
    const float* rW2     = (const float*)d_in[18];
    const float* rb2     = (const float*)d_in[19];
    const float* dW1     = (const float*)d_in[20];
    const float* db1     = (const float*)d_in[21];
    const float* dW2     = (const float*)d_in[22];
    const float* db2     = (const float*)d_in[23];

    char* W = (char*)d_ws;
    size_t off = 0;
    auto take = [&](size_t b) { char* p = W + off; off += (b + 255) & ~(size_t)255; return p; };

    double* accum  = (double*)take(16);
    u16* encWbt = (u16*)take((size_t)1024 * 2048 * 2);
    u16* WihB   = (u16*)take((size_t)6144 * 1024 * 2);
    u16* WhhB   = (u16*)take((size_t)6144 * 2048 * 2);
    u16* l1B    = (u16*)take((size_t)2048 * 2048 * 2);   // [tW1t | rW1at]
    u16* tW2bt  = (u16*)take((size_t)1024 * 1024 * 2);
    u16* rW2bt  = (u16*)take((size_t)1024 * 1024 * 2);
    u16* rW1bbt = (u16*)take((size_t)1024 * 1024 * 2);
    u16* dW1abt = (u16*)take((size_t)1024 * 2048 * 2);
    u16* dW2bt  = (u16*)take((size_t)2048 * 1024 * 2);
    u16* PreLatB = (u16*)take((size_t)1024 * 1024 * 2);
    u16* LatB    = (u16*)take((size_t)1024 * 1024 * 2);
    u16* Hall   = (u16*)take((size_t)63 * 256 * 2048 * 2);
    int* latidx = (int*)take((size_t)63 * 256 * 32 * 4);
    u16* embR   = (u16*)take((size_t)16384 * 1024 * 2);   // scan emb; then PrAll; then latsum
    u16* enc    = (u16*)take((size_t)16384 * 1024 * 2);   // encoder out; then PoAll
    float* klrow = (float*)take((size_t)16128 * 4);
    u16* GHb    = (u16*)take((size_t)2 * 256 * 6144 * 2);
    float* hf32 = (float*)take((size_t)256 * 2048 * 4);
    u16* x_bf   = (u16*)take((size_t)256 * 1024 * 2);
    u16* p1q1   = (u16*)take((size_t)256 * 1024 * 2);
    char* X     = take((size_t)17825792);                  // 17 MB: flatc/Xp/d1

    u16* flatc = (u16*)X;                                  // 4096 x 2048 per pass
    u16* Xp    = (u16*)X;                                  // 8064 x 1024 per half
    u16* d1    = (u16*)X;                                  // 8064 x 1024 per half
    u16* PoAll = enc;                                      // enc dead after embR GEMM
    u16* PrAll = embR;                                     // embR dead after scan; consumed by k_kl before latsum

    k_init<<<1, 1, 0, stream>>>(accum);

    // weight conversion
    k_cast<<<6144, 256, 0, stream>>>(Wih, WihB, 6291456 / 4);
    k_cast<<<12288, 256, 0, stream>>>(Whh, WhhB, 12582912 / 4);
    k_cast<<<1024, 256, 0, stream>>>(preW, PreLatB, 262144);
    k_cast<<<1024, 256, 0, stream>>>(dW1 + (size_t)2048 * 1024, LatB, 262144);
    k_transpose<<<dim3(64, 32), dim3(32, 8), 0, stream>>>(encW, 1024, encWbt, 2048);
    k_transpose<<<dim3(64, 32), dim3(32, 8), 0, stream>>>(tW1, 1024, l1B, 2048);
    k_transpose<<<dim3(64, 32), dim3(32, 8), 0, stream>>>(rW1, 1024, l1B + (size_t)1024 * 2048, 2048);
    k_transpose<<<dim3(32, 32), dim3(32, 8), 0, stream>>>(tW2, 1024, tW2bt, 1024);
    k_transpose<<<dim3(32, 32), dim3(32, 8), 0, stream>>>(rW2, 1024, rW2bt, 1024);
    k_transpose<<<dim3(32, 32), dim3(32, 8), 0, stream>>>(rW1 + (size_t)2048 * 1024, 1024, rW1bbt, 1024);
    k_transpose<<<dim3(64, 32), dim3(32, 8), 0, stream>>>(dW1, 1024, dW1abt, 2048);
    k_transpose<<<dim3(32, 64), dim3(32, 8), 0, stream>>>(dW2, 2048, dW2bt, 1024);

    // phase 1: encoder (4 passes of 4096 rows; 128² 8-wave gemmS + T1 swizzle)
    for (int pass = 0; pass < 4; ++pass) {
        k_prep<<<8192, 256, 0, stream>>>(zs + (size_t)pass * 4096 * 2048, zmean, zstd, flatc);
        GP e{}; e.A = flatc; e.lda = 2048; e.Bt = encWbt; e.Cb = enc + (size_t)pass * 4096 * 1024;
        e.ldc = 1024; e.bias = encb; e.K = 2048; e.gridN = 8;
        gemmS<4, 2, 2, 4, 1, 1, true><<<dim3(256), 512, 0, stream>>>(e, e, 256);
    }
    {
        GP e{}; e.A = enc; e.lda = 1024; e.Bt = rW1bbt; e.Cb = embR; e.ldc = 1024;
        e.bias = rb1; e.K = 1024; e.gridN = 8;
        gemmS<4, 2, 2, 4, 2, 2, true><<<dim3(1024), 512, 0, stream>>>(e, e, 1024);
    }

    // phase 2: sequential scan (post-only path; prior deferred)
    k_xpre0<<<256, 256, 0, stream>>>(preW, preb, actions, x_bf);
    for (int t = 0; t < 63; ++t) {
        // k1: gx + GRU -> h_t (512 blocks)
        if (t == 0)
            k_gates<true><<<512, 256, 0, stream>>>(x_bf, WihB, bih, bhh, GHb, hf32, Hall);
        else
            k_gates<false><<<512, 256, 0, stream>>>(x_bf, WihB, bih, bhh, GHb + (size_t)(t & 1) * 256 * 6144,
                                                    hf32, Hall + (size_t)t * 256 * 2048);
        // k2: gh(t+1) (bf16) || l1-post(t) — 8-wave blocks (512 thr), 448 tiles
        {
            GP pa{}; pa.A = Hall + (size_t)t * 256 * 2048; pa.lda = 2048; pa.Bt = WhhB;
            pa.Cb = GHb + (size_t)((t + 1) & 1) * 256 * 6144; pa.ldc = 6144; pa.bias = bhh;
            pa.K = 2048; pa.gridN = 96;
            GP pb{}; pb.A = Hall + (size_t)t * 256 * 2048; pb.lda = 2048;
            pb.Bt = l1B + (size_t)1024 * 2048; pb.Cb = p1q1; pb.ldc = 1024;
            pb.aux = embR + (size_t)(t + 1) * 1024; pb.auxld = 65536;
            pb.K = 2048; pb.gridN = 16;
            int nA = (t < 62) ? 384 : 0;
            gemmS<2, 4, 2, 1, 7, 4><<<dim3(nA + 64), 512, 0, stream>>>(pa, pb, nA);
        }
        // k3: q-post (BM=32, 128 blocks) -> PoAll[t] + fused argmax -> latidx[t]
        {
            GP q{}; q.A = p1q1; q.lda = 1024; q.Bt = rW2bt; q.ldc = 1024;
            q.Cb = PoAll + (size_t)t * 256 * 1024; q.bias = rb2; q.K = 1024; q.gridN = 16;
            q.idx = latidx + (size_t)t * 256 * 32;
            gemmS<2, 2, 1, 2, 8, 8><<<dim3(128), 256, 0, stream>>>(q, q, 128);
        }
        // k4: next x from latidx
        if (t < 62)
            k_xgen<<<256, 256, 0, stream>>>(latidx + (size_t)t * 256 * 32,
                                            PreLatB, preW, preb, actions, x_bf, t + 1);
    }

    // phase 3a: batched prior (2 halves of 8064 rows; 128² + T1 swizzle) + KL
    for (int half = 0; half < 2; ++half) {
        int m0 = half * 8064;
        GP e{}; e.A = Hall + (size_t)m0 * 2048; e.lda = 2048; e.Bt = l1B; e.Cb = Xp; e.ldc = 1024;
        e.bias = tb1; e.K = 2048; e.gridN = 8;
        gemmS<4, 2, 2, 4, 1, 1, true><<<dim3(504), 512, 0, stream>>>(e, e, 504);
        GP q{}; q.A = Xp; q.lda = 1024; q.Bt = tW2bt; q.Cb = PrAll + (size_t)m0 * 1024; q.ldc = 1024;
        q.bias = tb2; q.K = 1024; q.gridN = 8;
        gemmS<4, 2, 2, 4, 2, 2, true><<<dim3(504), 512, 0, stream>>>(q, q, 504);
    }
    k_kl<<<16128, 256, 0, stream>>>(PoAll, PrAll, klrow);

    // phase 3b: decoder + fused recon (2 halves; 128² + T1 swizzle)
    k_latsum<<<16128, 256, 0, stream>>>(LatB, db1, latidx, embR);
    for (int half = 0; half < 2; ++half) {
        int m0 = half * 8064;
        GP d{}; d.A = Hall + (size_t)m0 * 2048; d.lda = 2048; d.Bt = dW1abt; d.Cb = d1; d.ldc = 1024;
        d.aux = embR + (size_t)m0 * 1024; d.auxld = 1024; d.K = 2048; d.gridN = 8;
        gemmS<4, 2, 2, 4, 4, 4, true><<<dim3(504), 512, 0, stream>>>(d, d, 504);
        GP d2{}; d2.A = d1; d2.lda = 1024; d2.Bt = dW2bt; d2.ldc = 2048; d2.bias = db2;
        d2.zs = zs; d2.zmean = zmean; d2.zstd = zstd; d2.accum = accum; d2.K = 1024; d2.gridN = 16;
        d2.rbase = m0;
        gemmS<4, 2, 2, 4, 5, 5, true><<<dim3(1008), 512, 0, stream>>>(d2, d2, 1008);
    }
    k_finalize<<<1, 256, 0, stream>>>(accum, klrow, (float*)d_out);
}

// Round 13
// 3209.966 us; speedup vs baseline: 1.1645x; 1.0084x over previous
//
#include <hip/hip_runtime.h>
#include <hip/hip_bf16.h>
#include <math.h>

typedef unsigned short u16;
typedef __attribute__((ext_vector_type(8))) short s16x8;
typedef __attribute__((ext_vector_type(4))) short s16x4;
typedef __attribute__((ext_vector_type(4))) float f32x4;

#define DEVI static __device__ __forceinline__

DEVI u16 f2bfu(float f) {
    unsigned u = __float_as_uint(f);
    unsigned r = (u + 0x7fffu + ((u >> 16) & 1u)) >> 16;
    return (u16)r;
}
DEVI float bfu2f(u16 u) { return __uint_as_float(((unsigned)u) << 16); }
DEVI float eluf(float x) { return x > 0.f ? x : (expf(x) - 1.f); }
DEVI float sigm(float x) { return 1.f / (1.f + expf(-x)); }

#define GLOAD16(gsrc, ldst)                                                            \
    __builtin_amdgcn_global_load_lds(                                                  \
        (__attribute__((address_space(1))) void*)(void*)(gsrc),                        \
        (__attribute__((address_space(3))) void*)(ldst), 16, 0, 0)

template <int N> DEVI void vmwait();
template <> DEVI void vmwait<0>() { asm volatile("s_waitcnt vmcnt(0)" ::: "memory"); }
template <> DEVI void vmwait<1>() { asm volatile("s_waitcnt vmcnt(1)" ::: "memory"); }
template <> DEVI void vmwait<2>() { asm volatile("s_waitcnt vmcnt(2)" ::: "memory"); }
template <> DEVI void vmwait<3>() { asm volatile("s_waitcnt vmcnt(3)" ::: "memory"); }
template <> DEVI void vmwait<4>() { asm volatile("s_waitcnt vmcnt(4)" ::: "memory"); }
template <> DEVI void vmwait<5>() { asm volatile("s_waitcnt vmcnt(5)" ::: "memory"); }
template <> DEVI void vmwait<6>() { asm volatile("s_waitcnt vmcnt(6)" ::: "memory"); }

struct GP {
    const u16* A; int lda;
    const u16* Bt;
    float* Cf; u16* Cb; int ldc;
    const float* bias;
    const u16* aux; int auxld;
    const float* zs;               // EPI5
    const float* zmean; const float* zstd;
    double* accum;
    int* idx;                      // EPI8: argmax out
    int K; int gridN; int rbase;
};

// ---------------------------------------------------------------------------
// gemmS: BK=64, T2 XOR-swizzle, 3-deep counted-vmcnt pipeline. The only GEMM.
// Regime map (r8-r12): scan launches (few blocks) are occupancy-bound —
// spread blocks over all 256 CUs; fixed-phase launches (many blocks) are
// density-bound — 128x128 8-wave tiles. SWZ = T1 XCD remap (needs nA%8==0).
// ---------------------------------------------------------------------------
template <int EPI, int MF, int NF>
DEVI void epiS(const GP& p, f32x4 (&acc)[MF][NF], int r0, int c0, int wm, int wn,
               int lrow4, int lcol) {
#pragma unroll
    for (int mf = 0; mf < MF; ++mf) {
        int rowb = r0 + (wm * MF + mf) * 16 + lrow4;
#pragma unroll
        for (int nf = 0; nf < NF; ++nf) {
            int col = c0 + (wn * NF + nf) * 16 + lcol;
#pragma unroll
            for (int j = 0; j < 4; ++j) {
                float v = acc[mf][nf][j];
                int r = rowb + j;
                if constexpr (EPI == 1) {
                    p.Cb[(size_t)r * p.ldc + col] = f2bfu(eluf(v + p.bias[col]));
                } else if constexpr (EPI == 2) {
                    p.Cb[(size_t)r * p.ldc + col] = f2bfu(v + p.bias[col]);
                } else if constexpr (EPI == 4) {
                    p.Cb[(size_t)r * p.ldc + col] = f2bfu(eluf(v + bfu2f(p.aux[(size_t)r * p.auxld + col])));
                } else if constexpr (EPI == 7) {
                    p.Cb[(size_t)r * p.ldc + col] = f2bfu(v + p.bias[col]);
                }
            }
        }
    }
}

template <int WM, int WN, int MF, int NF, int EPIa, int EPIb, bool SWZ = false>
__global__ __launch_bounds__(WM * WN * 64) void gemmS(GP pa, GP pb, int nA) {
    constexpr int NT = WM * WN * 64;
    constexpr int BM = WM * MF * 16, BN = WN * NF * 16;
    constexpr int ABY = BM * 128, BBY = BN * 128;
    constexpr int LPT = (ABY + BBY) / (NT * 16);

    const int tid = threadIdx.x, w = tid >> 6, lane = tid & 63;
    const bool isA = (int)blockIdx.x < nA;
    GP p = isA ? pa : pb;
    int bid = isA ? blockIdx.x : blockIdx.x - nA;
    if constexpr (SWZ) bid = (bid & 7) * (nA >> 3) + (bid >> 3);   // T1, needs nA%8==0
    const int bn = bid % p.gridN, bm = bid / p.gridN;
    const int r0 = bm * BM, c0 = bn * BN;
    const int wm = w / WN, wn = w % WN;

    __shared__ __attribute__((aligned(16))) char sm[3 * (ABY + BBY)];
    __shared__ float ps_[WM * WN];

    auto stage = [&](int kt, int buf) {
        char* s = sm + buf * (ABY + BBY);
#pragma unroll
        for (int it = 0; it < ABY / (NT * 16); ++it) {
            int bo = it * (NT * 16) + tid * 16;
            int row = bo >> 7, kb = bo & 127;
            int kbs = kb ^ ((row & 7) << 4);                       // pre-swizzled source
            GLOAD16(p.A + (size_t)(r0 + row) * p.lda + kt * 64 + (kbs >> 1), s + bo);
        }
        char* sb = s + ABY;
#pragma unroll
        for (int it = 0; it < BBY / (NT * 16); ++it) {
            int bo = it * (NT * 16) + tid * 16;
            int row = bo >> 7, kb = bo & 127;
            int kbs = kb ^ ((row & 7) << 4);
            GLOAD16(p.Bt + (size_t)(c0 + row) * p.K + kt * 64 + (kbs >> 1), sb + bo);
        }
    };

    f32x4 acc[MF][NF];
#pragma unroll
    for (int mf = 0; mf < MF; ++mf)
#pragma unroll
        for (int nf = 0; nf < NF; ++nf) acc[mf][nf] = (f32x4){0.f, 0.f, 0.f, 0.f};

    const int nk = p.K >> 6;
    stage(0, 0);
    stage(1, 1);
    int b0 = 0, b1 = 1, b2 = 2;
    for (int kt = 0; kt < nk; ++kt) {
        if (kt < nk - 1) vmwait<LPT>(); else vmwait<0>();
        __builtin_amdgcn_sched_barrier(0);
        __builtin_amdgcn_s_barrier();
        if (kt + 2 < nk) stage(kt + 2, b2);
        const char* s = sm + b0 * (ABY + BBY);
#pragma unroll
        for (int ks = 0; ks < 2; ++ks) {
            const int kb = ks * 64 + ((lane >> 4) << 4);
            s16x8 aF[MF], bF[NF];
#pragma unroll
            for (int mf = 0; mf < MF; ++mf) {
                int rt = (wm * MF + mf) * 16 + (lane & 15);
                aF[mf] = *(const s16x8*)(s + rt * 128 + (kb ^ ((rt & 7) << 4)));
            }
#pragma unroll
            for (int nf = 0; nf < NF; ++nf) {
                int rt = (wn * NF + nf) * 16 + (lane & 15);
                bF[nf] = *(const s16x8*)(s + ABY + rt * 128 + (kb ^ ((rt & 7) << 4)));
            }
#pragma unroll
            for (int mf = 0; mf < MF; ++mf)
#pragma unroll
                for (int nf = 0; nf < NF; ++nf)
                    acc[mf][nf] = __builtin_amdgcn_mfma_f32_16x16x32_bf16(aF[mf], bF[nf], acc[mf][nf], 0, 0, 0);
        }
        int t_ = b0; b0 = b1; b1 = b2; b2 = t_;
    }

    const int lrow4 = (lane >> 4) << 2, lcol = lane & 15;
    if constexpr (EPIa == 8) {
        // requires NF==2: wave (wm,wn) owns one 32-class latent group
        const int lat = (c0 >> 5) + wn;
#pragma unroll
        for (int mf = 0; mf < MF; ++mf) {
#pragma unroll
            for (int j = 0; j < 4; ++j) {
                int r = r0 + (wm * MF + mf) * 16 + lrow4 + j;
                int col0 = c0 + wn * 32 + lcol;
                float v0 = acc[mf][0][j] + p.bias[col0];
                float v1 = acc[mf][1][j] + p.bias[col0 + 16];
                p.Cb[(size_t)r * p.ldc + col0] = f2bfu(v0);
                p.Cb[(size_t)r * p.ldc + col0 + 16] = f2bfu(v1);
                float mv; int mi;
                if (v1 > v0) { mv = v1; mi = lcol + 16; } else { mv = v0; mi = lcol; }
#pragma unroll
                for (int o = 8; o >= 1; o >>= 1) {
                    float ov = __shfl_xor(mv, o, 64);
                    int oi = __shfl_xor(mi, o, 64);
                    if (ov > mv || (ov == mv && oi < mi)) { mv = ov; mi = oi; }
                }
                if (lcol == 0) p.idx[(size_t)r * 32 + lat] = mi;
            }
        }
    } else if constexpr (EPIa == 5) {
        float lsum = 0.f;
#pragma unroll
        for (int mf = 0; mf < MF; ++mf) {
            int rowb = r0 + (wm * MF + mf) * 16 + lrow4;
#pragma unroll
            for (int nf = 0; nf < NF; ++nf) {
                int col = c0 + (wn * NF + nf) * 16 + lcol;
#pragma unroll
                for (int j = 0; j < 4; ++j) {
                    float v = acc[mf][nf][j] + p.bias[col];
                    int R = rowb + j + p.rbase;
                    int tt = R >> 8, b = R & 255;
                    int ch = col >> 9;
                    float z = (p.zs[((size_t)b * 64 + tt + 1) * 2048 + col] - p.zmean[ch]) / p.zstd[ch];
                    float d = v - z;
                    lsum += d * d;
                }
            }
        }
#pragma unroll
        for (int o = 32; o > 0; o >>= 1) lsum += __shfl_down(lsum, o, 64);
        if (lane == 0) ps_[w] = lsum;
        __syncthreads();
        if (tid == 0) {
            double s = 0.0;
#pragma unroll
            for (int i = 0; i < WM * WN; ++i) s += (double)ps_[i];
            atomicAdd(p.accum, s);
        }
    } else {
        if (isA) epiS<EPIa, MF, NF>(p, acc, r0, c0, wm, wn, lrow4, lcol);
        else     epiS<EPIb, MF, NF>(p, acc, r0, c0, wm, wn, lrow4, lcol);
    }
}

// ---------------------------------------------------------------------------
// k_gates: gx (K=1024) + full GRU epilogue; 3-deep pipeline.
// 512 blocks (bm 8 x bn 64), BM=32 x 32-col gate tile, TSZ=16KB, LPT=4.
// ---------------------------------------------------------------------------
template <bool FIRST>
__global__ __launch_bounds__(256) void k_gates(const u16* __restrict__ X, const u16* __restrict__ WihB,
                                               const float* __restrict__ bih, const float* __restrict__ bhh,
                                               const u16* __restrict__ GHb, float* __restrict__ hf32,
                                               u16* __restrict__ hallT) {
    constexpr int ABY = 32 * 128;       // 4 KB
    constexpr int BTB = 32 * 128;       // 4 KB per gate tile
    constexpr int TSZ = ABY + 3 * BTB;  // 16 KB
    const int tid = threadIdx.x, w = tid >> 6, lane = tid & 63;
    const int bm = blockIdx.x >> 6, bn = blockIdx.x & 63;
    const int r0 = bm * 32, c0 = bn * 32;
    const int wm = w >> 1, wn = w & 1;

    __shared__ __attribute__((aligned(16))) char sm[3 * TSZ];

    auto stage = [&](int kt, int buf) {
        char* s = sm + buf * TSZ;
        {
            int bo = tid * 16;                 // 256*16 = 4KB = ABY exactly
            int row = bo >> 7, kb = bo & 127;
            int kbs = kb ^ ((row & 7) << 4);
            GLOAD16(X + (size_t)(r0 + row) * 1024 + kt * 64 + (kbs >> 1), s + bo);
        }
        char* sb = s + ABY;
#pragma unroll
        for (int g = 0; g < 3; ++g) {
            int bo = tid * 16;
            int row = bo >> 7, kb = bo & 127;
            int kbs = kb ^ ((row & 7) << 4);
            GLOAD16(WihB + (size_t)(g * 2048 + c0 + row) * 1024 + kt * 64 + (kbs >> 1), sb + g * BTB + bo);
        }
    };

    f32x4 acc[3];
#pragma unroll
    for (int g = 0; g < 3; ++g) acc[g] = (f32x4){0.f, 0.f, 0.f, 0.f};

    stage(0, 0);
    stage(1, 1);
    int b0 = 0, b1 = 1, b2 = 2;
    for (int kt = 0; kt < 16; ++kt) {
        if (kt < 15) vmwait<4>(); else vmwait<0>();
        __builtin_amdgcn_sched_barrier(0);
        __builtin_amdgcn_s_barrier();
        if (kt + 2 < 16) stage(kt + 2, b2);
        const char* s = sm + b0 * TSZ;
#pragma unroll
        for (int ks = 0; ks < 2; ++ks) {
            const int kb = ks * 64 + ((lane >> 4) << 4);
            s16x8 aF, bF[3];
            {
                int rt = wm * 16 + (lane & 15);
                aF = *(const s16x8*)(s + rt * 128 + (kb ^ ((rt & 7) << 4)));
            }
#pragma unroll
            for (int g = 0; g < 3; ++g) {
                int rt = wn * 16 + (lane & 15);
                bF[g] = *(const s16x8*)(s + ABY + g * BTB + rt * 128 + (kb ^ ((rt & 7) << 4)));
            }
#pragma unroll
            for (int g = 0; g < 3; ++g)
                acc[g] = __builtin_amdgcn_mfma_f32_16x16x32_bf16(aF, bF[g], acc[g], 0, 0, 0);
        }
        int t_ = b0; b0 = b1; b1 = b2; b2 = t_;
    }

    const int lrow4 = (lane >> 4) << 2, lcol = lane & 15;
    const int cc = c0 + wn * 16 + lcol;
    {
        int rr0 = r0 + wm * 16 + lrow4;
#pragma unroll
        for (int j = 0; j < 4; ++j) {
            int rr = rr0 + j;
            float xr = acc[0][j] + bih[cc];
            float xz = acc[1][j] + bih[2048 + cc];
            float xn = acc[2][j] + bih[4096 + cc];
            float hr_, hz_, hn_;
            if (FIRST) { hr_ = bhh[cc]; hz_ = bhh[2048 + cc]; hn_ = bhh[4096 + cc]; }
            else {
                const u16* g = GHb + (size_t)rr * 6144;
                hr_ = bfu2f(g[cc]); hz_ = bfu2f(g[2048 + cc]); hn_ = bfu2f(g[4096 + cc]);
            }
            float r = sigm(xr + hr_);
            float u = sigm(xz + hz_);
            float n = tanhf(xn + r * hn_);
            float hold = FIRST ? 0.f : hf32[(size_t)rr * 2048 + cc];
            float h = (1.f - u) * n + u * hold;
            hf32[(size_t)rr * 2048 + cc] = h;
            hallT[(size_t)rr * 2048 + cc] = f2bfu(h);
        }
    }
}

// ---------------------------------------------------------------------------
// small kernels
// ---------------------------------------------------------------------------
__global__ void k_init(double* acc) { acc[0] = 0.0; acc[1] = 0.0; }

__global__ void k_cast(const float* __restrict__ src, u16* __restrict__ dst, int n4) {
    int i = blockIdx.x * 256 + threadIdx.x;
    if (i >= n4) return;
    f32x4 v = *(const f32x4*)(src + (size_t)i * 4);
    s16x4 o;
    o[0] = (short)f2bfu(v[0]); o[1] = (short)f2bfu(v[1]);
    o[2] = (short)f2bfu(v[2]); o[3] = (short)f2bfu(v[3]);
    *(s16x4*)(dst + (size_t)i * 4) = o;
}

__global__ void k_transpose(const float* __restrict__ src, int sld, u16* __restrict__ dst, int K) {
    __shared__ float tile[32][33];
    int k0 = blockIdx.x * 32, n0 = blockIdx.y * 32;
    for (int r = threadIdx.y; r < 32; r += 8)
        tile[r][threadIdx.x] = src[(size_t)(k0 + r) * sld + n0 + threadIdx.x];
    __syncthreads();
    for (int r = threadIdx.y; r < 32; r += 8)
        dst[(size_t)(n0 + r) * K + k0 + threadIdx.x] = f2bfu(tile[threadIdx.x][r]);
}

__global__ void k_prep(const float* __restrict__ zsp, const float* __restrict__ zm,
                       const float* __restrict__ zsd, u16* __restrict__ flat) {
    size_t i = ((size_t)blockIdx.x * 256 + threadIdx.x) * 4;
    f32x4 v = *(const f32x4*)(zsp + i);
    int ch = ((int)(i >> 9)) & 3;
    float m = zm[ch], s = zsd[ch];
    s16x4 o;
    o[0] = (short)f2bfu((v[0] - m) / s); o[1] = (short)f2bfu((v[1] - m) / s);
    o[2] = (short)f2bfu((v[2] - m) / s); o[3] = (short)f2bfu((v[3] - m) / s);
    *(s16x4*)(flat + i) = o;
}

__global__ __launch_bounds__(256) void k_xpre0(const float* __restrict__ preW, const float* __restrict__ preb,
                                               const float* __restrict__ actions, u16* __restrict__ xout) {
    int b = blockIdx.x, tid = threadIdx.x;
    __shared__ float as[3];
    if (tid < 3) as[tid] = actions[(size_t)b * 64 * 3 + tid];
    __syncthreads();
    for (int j = tid; j < 1024; j += 256) {
        float s = preb[j] + as[0] * preW[1024 * 1024 + j] + as[1] * preW[1025 * 1024 + j] + as[2] * preW[1026 * 1024 + j];
        xout[(b << 10) + j] = f2bfu(eluf(s));
    }
}

// x-gen only (argmax fused into k3's EPI8 epilogue)
__global__ __launch_bounds__(256) void k_xgen(const int* __restrict__ latidx_t,
                                              const u16* __restrict__ PreLatB, const float* __restrict__ preW,
                                              const float* __restrict__ preb,
                                              const float* __restrict__ actions, u16* __restrict__ xout,
                                              int tnext) {
    int b = blockIdx.x, tid = threadIdx.x;
    __shared__ int idxs[32];
    __shared__ float as[3];
    if (tid < 32) idxs[tid] = latidx_t[(b << 5) + tid];
    if (tid >= 64 && tid < 67) as[tid - 64] = actions[((size_t)b * 64 + tnext) * 3 + (tid - 64)];
    __syncthreads();
    const int j4 = tid * 4;
    f32x4 s = *(const f32x4*)(preb + j4);
#pragma unroll
    for (int cc = 0; cc < 3; ++cc) {
        f32x4 wv = *(const f32x4*)(preW + (size_t)(1024 + cc) * 1024 + j4);
        s[0] += as[cc] * wv[0]; s[1] += as[cc] * wv[1];
        s[2] += as[cc] * wv[2]; s[3] += as[cc] * wv[3];
    }
#pragma unroll
    for (int l = 0; l < 32; ++l) {
        s16x4 v = *(const s16x4*)(PreLatB + (size_t)((l << 5) + idxs[l]) * 1024 + j4);
        s[0] += bfu2f((u16)v[0]); s[1] += bfu2f((u16)v[1]);
        s[2] += bfu2f((u16)v[2]); s[3] += bfu2f((u16)v[3]);
    }
    s16x4 o;
    o[0] = (short)f2bfu(eluf(s[0])); o[1] = (short)f2bfu(eluf(s[1]));
    o[2] = (short)f2bfu(eluf(s[2])); o[3] = (short)f2bfu(eluf(s[3]));
    *(s16x4*)(xout + (b << 10) + j4) = o;
}

// batched KL: one block per (t,b) row; reads bf16 post/prior logits
__global__ __launch_bounds__(256) void k_kl(const u16* __restrict__ PoAll, const u16* __restrict__ PrAll,
                                            float* __restrict__ klrow) {
    int m = blockIdx.x, tid = threadIdx.x;
    const u16* Po = PoAll + (size_t)m * 1024;
    const u16* Pr = PrAll + (size_t)m * 1024;
    __shared__ float klpart[32];
    int grp = tid >> 5, c = tid & 31;
#pragma unroll
    for (int it = 0; it < 4; ++it) {
        int l = it * 8 + grp;
        float po = bfu2f(Po[l * 32 + c]);
        float pr = bfu2f(Pr[l * 32 + c]);
        float mv = po, mq = pr;
#pragma unroll
        for (int o = 16; o > 0; o >>= 1) {
            mv = fmaxf(mv, __shfl_xor(mv, o, 32));
            mq = fmaxf(mq, __shfl_xor(mq, o, 32));
        }
        float ep = expf(po - mv), eq = expf(pr - mq);
        float sp = ep, sq = eq;
#pragma unroll
        for (int o = 16; o > 0; o >>= 1) { sp += __shfl_xor(sp, o, 32); sq += __shfl_xor(sq, o, 32); }
        float logp = po - mv - logf(sp);
        float logq = pr - mq - logf(sq);
        float klc = (ep / sp) * (logp - logq);
#pragma unroll
        for (int o = 16; o > 0; o >>= 1) klc += __shfl_xor(klc, o, 32);
        if (c == 0) klpart[l] = klc;
    }
    __syncthreads();
    if (tid == 0) {
        float kl = 0.f;
        for (int l = 0; l < 32; ++l) kl += klpart[l];
        klrow[m] = fmaxf(kl, 1.0f);
    }
}

__global__ __launch_bounds__(256) void k_latsum(const u16* __restrict__ LatB, const float* __restrict__ db1,
                                                const int* __restrict__ latidx_all, u16* __restrict__ latsum) {
    int m = blockIdx.x, tid = threadIdx.x;
    __shared__ int idxs[32];
    if (tid < 32) idxs[tid] = latidx_all[(size_t)m * 32 + tid];
    __syncthreads();
    const int j4 = tid * 4;
    f32x4 s = *(const f32x4*)(db1 + j4);
#pragma unroll
    for (int l = 0; l < 32; ++l) {
        s16x4 v = *(const s16x4*)(LatB + (size_t)((l << 5) + idxs[l]) * 1024 + j4);
        s[0] += bfu2f((u16)v[0]); s[1] += bfu2f((u16)v[1]);
        s[2] += bfu2f((u16)v[2]); s[3] += bfu2f((u16)v[3]);
    }
    s16x4 o;
    o[0] = (short)f2bfu(s[0]); o[1] = (short)f2bfu(s[1]);
    o[2] = (short)f2bfu(s[2]); o[3] = (short)f2bfu(s[3]);
    *(s16x4*)(latsum + (size_t)m * 1024 + j4) = o;
}

// NOTE: MUST be launched with 256 threads (r3-r5 bug: was <<<1,1>>>)
__global__ __launch_bounds__(256) void k_finalize(const double* __restrict__ acc,
                                                  const float* __restrict__ klrow, float* __restrict__ out) {
    __shared__ double ps[256];
    int tid = threadIdx.x;
    double s = 0.0;
    for (int i = tid; i < 16128; i += 256) s += (double)klrow[i];
    ps[tid] = s;
    __syncthreads();
    for (int o = 128; o > 0; o >>= 1) {
        if (tid < o) ps[tid] += ps[tid + o];
        __syncthreads();
    }
    if (tid == 0) out[0] = (float)(acc[0] / 33030144.0 + ps[0] / 16128.0);
}

// ---------------------------------------------------------------------------
extern "C" void kernel_launch(void* const* d_in, const int* in_sizes, int n_in,
                              void* d_out, int out_size, void* d_ws, size_t ws_size,
                              hipStream_t stream) {
    const float* zs      = (const float*)d_in[0];
    const float* actions = (const float*)d_in[1];
    const float* zmean   = (const float*)d_in[2];
    const float* zstd    = (const float*)d_in[3];
    const float* encW    = (const float*)d_in[4];
    const float* encb    = (const float*)d_in[5];
    const float* preW    = (const float*)d_in[6];
    const float* preb    = (const float*)d_in[7];
    const float* Wih     = (const float*)d_in[8];
    const float* Whh     = (const float*)d_in[9];
    const float* bih     = (const float*)d_in[10];
    const float* bhh     = (const float*)d_in[11];
    const float* tW1     = (const float*)d_in[12];
    const float* tb1     = (const float*)d_in[13];
    const float* tW2     = (const float*)d_in[14];
    const float* tb2     = (const float*)d_in[15];
    const float* rW1     = (const float*)d_in[16];
    const float* rb1     = (const float*)d_in[17];
    const float* rW2     = (const float*)d_in[18];
    const float* rb2     = (const float*)d_in[19];
    const float* dW1     = (const float*)d_in[20];
    const float* db1     = (const float*)d_in[21];
    const float* dW2     = (const float*)d_in[22];
    const float* db2     = (const float*)d_in[23];

    char* W = (char*)d_ws;
    size_t off = 0;
    auto take = [&](size_t b) { char* p = W + off; off += (b + 255) & ~(size_t)255; return p; };

    // ws budget ~250 MB (282 MB proven safe: r4@282MB and r5@233MB were
    // bit-identical, so no overflow occurred at 282)
    double* accum  = (double*)take(16);
    u16* encWbt = (u16*)take((size_t)1024 * 2048 * 2);
    u16* WihB   = (u16*)take((size_t)6144 * 1024 * 2);
    u16* WhhB   = (u16*)take((size_t)6144 * 2048 * 2);
    u16* l1B    = (u16*)take((size_t)2048 * 2048 * 2);   // [tW1t | rW1at]
    u16* tW2bt  = (u16*)take((size_t)1024 * 1024 * 2);
    u16* rW2bt  = (u16*)take((size_t)1024 * 1024 * 2);
    u16* rW1bbt = (u16*)take((size_t)1024 * 1024 * 2);
    u16* dW1abt = (u16*)take((size_t)1024 * 2048 * 2);
    u16* dW2bt  = (u16*)take((size_t)2048 * 1024 * 2);
    u16* PreLatB = (u16*)take((size_t)1024 * 1024 * 2);
    u16* LatB    = (u16*)take((size_t)1024 * 1024 * 2);
    u16* Hall   = (u16*)take((size_t)63 * 256 * 2048 * 2);
    int* latidx = (int*)take((size_t)63 * 256 * 32 * 4);
    u16* embR   = (u16*)take((size_t)16384 * 1024 * 2);   // scan emb; then PrAll; then latsum
    u16* enc    = (u16*)take((size_t)16384 * 1024 * 2);   // encoder out; then PoAll
    float* klrow = (float*)take((size_t)16128 * 4);
    u16* GHb    = (u16*)take((size_t)2 * 256 * 6144 * 2);
    float* hf32 = (float*)take((size_t)256 * 2048 * 4);
    u16* x_bf   = (u16*)take((size_t)256 * 1024 * 2);
    u16* p1q1   = (u16*)take((size_t)256 * 1024 * 2);
    char* X     = take((size_t)34000000);                  // 34 MB: flatc/Xp/d1

    u16* flatc = (u16*)X;                                  // 8192 x 2048 per pass
    u16* Xp    = (u16*)X;                                  // 16128 x 1024 (1-shot)
    u16* d1    = (u16*)X;                                  // 16128 x 1024 (1-shot)
    u16* PoAll = enc;                                      // enc dead after embR GEMM
    u16* PrAll = embR;                                     // embR dead after scan; consumed by k_kl before latsum

    k_init<<<1, 1, 0, stream>>>(accum);

    // weight conversion
    k_cast<<<6144, 256, 0, stream>>>(Wih, WihB, 6291456 / 4);
    k_cast<<<12288, 256, 0, stream>>>(Whh, WhhB, 12582912 / 4);
    k_cast<<<1024, 256, 0, stream>>>(preW, PreLatB, 262144);
    k_cast<<<1024, 256, 0, stream>>>(dW1 + (size_t)2048 * 1024, LatB, 262144);
    k_transpose<<<dim3(64, 32), dim3(32, 8), 0, stream>>>(encW, 1024, encWbt, 2048);
    k_transpose<<<dim3(64, 32), dim3(32, 8), 0, stream>>>(tW1, 1024, l1B, 2048);
    k_transpose<<<dim3(64, 32), dim3(32, 8), 0, stream>>>(rW1, 1024, l1B + (size_t)1024 * 2048, 2048);
    k_transpose<<<dim3(32, 32), dim3(32, 8), 0, stream>>>(tW2, 1024, tW2bt, 1024);
    k_transpose<<<dim3(32, 32), dim3(32, 8), 0, stream>>>(rW2, 1024, rW2bt, 1024);
    k_transpose<<<dim3(32, 32), dim3(32, 8), 0, stream>>>(rW1 + (size_t)2048 * 1024, 1024, rW1bbt, 1024);
    k_transpose<<<dim3(64, 32), dim3(32, 8), 0, stream>>>(dW1, 1024, dW1abt, 2048);
    k_transpose<<<dim3(32, 64), dim3(32, 8), 0, stream>>>(dW2, 2048, dW2bt, 1024);

    // phase 1: encoder (2 passes of 8192 rows; 128² 8-wave gemmS + T1 swizzle)
    for (int pass = 0; pass < 2; ++pass) {
        k_prep<<<16384, 256, 0, stream>>>(zs + (size_t)pass * 8192 * 2048, zmean, zstd, flatc);
        GP e{}; e.A = flatc; e.lda = 2048; e.Bt = encWbt; e.Cb = enc + (size_t)pass * 8192 * 1024;
        e.ldc = 1024; e.bias = encb; e.K = 2048; e.gridN = 8;
        gemmS<4, 2, 2, 4, 1, 1, true><<<dim3(512), 512, 0, stream>>>(e, e, 512);
    }
    {
        GP e{}; e.A = enc; e.lda = 1024; e.Bt = rW1bbt; e.Cb = embR; e.ldc = 1024;
        e.bias = rb1; e.K = 1024; e.gridN = 8;
        gemmS<4, 2, 2, 4, 2, 2, true><<<dim3(1024), 512, 0, stream>>>(e, e, 1024);
    }

    // phase 2: sequential scan (post-only path; prior deferred)
    k_xpre0<<<256, 256, 0, stream>>>(preW, preb, actions, x_bf);
    for (int t = 0; t < 63; ++t) {
        // k1: gx + GRU -> h_t (512 blocks)
        if (t == 0)
            k_gates<true><<<512, 256, 0, stream>>>(x_bf, WihB, bih, bhh, GHb, hf32, Hall);
        else
            k_gates<false><<<512, 256, 0, stream>>>(x_bf, WihB, bih, bhh, GHb + (size_t)(t & 1) * 256 * 6144,
                                                    hf32, Hall + (size_t)t * 256 * 2048);
        // k2: gh(t+1) (bf16) || l1-post(t) — 8-wave blocks (512 thr), 448 tiles
        {
            GP pa{}; pa.A = Hall + (size_t)t * 256 * 2048; pa.lda = 2048; pa.Bt = WhhB;
            pa.Cb = GHb + (size_t)((t + 1) & 1) * 256 * 6144; pa.ldc = 6144; pa.bias = bhh;
            pa.K = 2048; pa.gridN = 96;
            GP pb{}; pb.A = Hall + (size_t)t * 256 * 2048; pb.lda = 2048;
            pb.Bt = l1B + (size_t)1024 * 2048; pb.Cb = p1q1; pb.ldc = 1024;
            pb.aux = embR + (size_t)(t + 1) * 1024; pb.auxld = 65536;
            pb.K = 2048; pb.gridN = 16;
            int nA = (t < 62) ? 384 : 0;
            gemmS<2, 4, 2, 1, 7, 4><<<dim3(nA + 64), 512, 0, stream>>>(pa, pb, nA);
        }
        // k3: q-post — 256 blocks x 2 waves (1 block/CU, occupancy regime)
        {
            GP q{}; q.A = p1q1; q.lda = 1024; q.Bt = rW2bt; q.ldc = 1024;
            q.Cb = PoAll + (size_t)t * 256 * 1024; q.bias = rb2; q.K = 1024; q.gridN = 32;
            q.idx = latidx + (size_t)t * 256 * 32;
            gemmS<2, 1, 1, 2, 8, 8><<<dim3(256), 128, 0, stream>>>(q, q, 256);
        }
        // k4: next x from latidx
        if (t < 62)
            k_xgen<<<256, 256, 0, stream>>>(latidx + (size_t)t * 256 * 32,
                                            PreLatB, preW, preb, actions, x_bf, t + 1);
    }

    // phase 3a: batched prior (1-shot, 16128 rows; 128² + T1 swizzle) + KL
    {
        GP e{}; e.A = Hall; e.lda = 2048; e.Bt = l1B; e.Cb = Xp; e.ldc = 1024;
        e.bias = tb1; e.K = 2048; e.gridN = 8;
        gemmS<4, 2, 2, 4, 1, 1, true><<<dim3(1008), 512, 0, stream>>>(e, e, 1008);
        GP q{}; q.A = Xp; q.lda = 1024; q.Bt = tW2bt; q.Cb = PrAll; q.ldc = 1024;
        q.bias = tb2; q.K = 1024; q.gridN = 8;
        gemmS<4, 2, 2, 4, 2, 2, true><<<dim3(1008), 512, 0, stream>>>(q, q, 1008);
    }
    k_kl<<<16128, 256, 0, stream>>>(PoAll, PrAll, klrow);

    // phase 3b: decoder + fused recon (1-shot; 128² + T1 swizzle)
    k_latsum<<<16128, 256, 0, stream>>>(LatB, db1, latidx, embR);
    {
        GP d{}; d.A = Hall; d.lda = 2048; d.Bt = dW1abt; d.Cb = d1; d.ldc = 1024;
        d.aux = embR; d.auxld = 1024; d.K = 2048; d.gridN = 8;
        gemmS<4, 2, 2, 4, 4, 4, true><<<dim3(1008), 512, 0, stream>>>(d, d, 1008);
        GP d2{}; d2.A = d1; d2.lda = 1024; d2.Bt = dW2bt; d2.ldc = 2048; d2.bias = db2;
        d2.zs = zs; d2.zmean = zmean; d2.zstd = zstd; d2.accum = accum; d2.K = 1024; d2.gridN = 16;
        d2.rbase = 0;
        gemmS<4, 2, 2, 4, 5, 5, true><<<dim3(2016), 512, 0, stream>>>(d2, d2, 2016);
    }
    k_finalize<<<1, 256, 0, stream>>>(accum, klrow, (float*)d_out);
}

// Round 14
// 3208.441 us; speedup vs baseline: 1.1650x; 1.0005x over previous
//
#include <hip/hip_runtime.h>
#include <hip/hip_bf16.h>
#include <math.h>

typedef unsigned short u16;
typedef __attribute__((ext_vector_type(8))) short s16x8;
typedef __attribute__((ext_vector_type(4))) short s16x4;
typedef __attribute__((ext_vector_type(4))) float f32x4;

#define DEVI static __device__ __forceinline__

DEVI u16 f2bfu(float f) {
    unsigned u = __float_as_uint(f);
    unsigned r = (u + 0x7fffu + ((u >> 16) & 1u)) >> 16;
    return (u16)r;
}
DEVI float bfu2f(u16 u) { return __uint_as_float(((unsigned)u) << 16); }
DEVI float eluf(float x) { return x > 0.f ? x : (expf(x) - 1.f); }
DEVI float sigm(float x) { return 1.f / (1.f + expf(-x)); }

#define GLOAD16(gsrc, ldst)                                                            \
    __builtin_amdgcn_global_load_lds(                                                  \
        (__attribute__((address_space(1))) void*)(void*)(gsrc),                        \
        (__attribute__((address_space(3))) void*)(ldst), 16, 0, 0)

template <int N> DEVI void vmwait();
template <> DEVI void vmwait<0>() { asm volatile("s_waitcnt vmcnt(0)" ::: "memory"); }
template <> DEVI void vmwait<1>() { asm volatile("s_waitcnt vmcnt(1)" ::: "memory"); }
template <> DEVI void vmwait<2>() { asm volatile("s_waitcnt vmcnt(2)" ::: "memory"); }
template <> DEVI void vmwait<3>() { asm volatile("s_waitcnt vmcnt(3)" ::: "memory"); }
template <> DEVI void vmwait<4>() { asm volatile("s_waitcnt vmcnt(4)" ::: "memory"); }
template <> DEVI void vmwait<5>() { asm volatile("s_waitcnt vmcnt(5)" ::: "memory"); }
template <> DEVI void vmwait<6>() { asm volatile("s_waitcnt vmcnt(6)" ::: "memory"); }

struct GP {
    const u16* A; int lda;
    const u16* Bt;
    float* Cf; u16* Cb; int ldc;
    const float* bias;
    const u16* aux; int auxld;
    const float* zs;               // EPI5
    const float* zmean; const float* zstd;
    double* accum;
    int* idx;                      // EPI8: argmax out
    int K; int gridN; int rbase;
};

// ---------------------------------------------------------------------------
// gemmS: BK=64, T2 XOR-swizzle, 3-deep counted-vmcnt pipeline. The only GEMM.
// Regime map (r8-r13): scan launches (few blocks) are occupancy-bound —
// spread blocks over all 256 CUs; fixed-phase launches (many blocks) are
// density-bound — 128x128 8-wave tiles. SWZ = T1 XCD remap (needs nA%8==0).
// ---------------------------------------------------------------------------
template <int EPI, int MF, int NF>
DEVI void epiS(const GP& p, f32x4 (&acc)[MF][NF], int r0, int c0, int wm, int wn,
               int lrow4, int lcol) {
#pragma unroll
    for (int mf = 0; mf < MF; ++mf) {
        int rowb = r0 + (wm * MF + mf) * 16 + lrow4;
#pragma unroll
        for (int nf = 0; nf < NF; ++nf) {
            int col = c0 + (wn * NF + nf) * 16 + lcol;
#pragma unroll
            for (int j = 0; j < 4; ++j) {
                float v = acc[mf][nf][j];
                int r = rowb + j;
                if constexpr (EPI == 1) {
                    p.Cb[(size_t)r * p.ldc + col] = f2bfu(eluf(v + p.bias[col]));
                } else if constexpr (EPI == 2) {
                    p.Cb[(size_t)r * p.ldc + col] = f2bfu(v + p.bias[col]);
                } else if constexpr (EPI == 4) {
                    p.Cb[(size_t)r * p.ldc + col] = f2bfu(eluf(v + bfu2f(p.aux[(size_t)r * p.auxld + col])));
                } else if constexpr (EPI == 7) {
                    p.Cb[(size_t)r * p.ldc + col] = f2bfu(v + p.bias[col]);
                }
            }
        }
    }
}

template <int WM, int WN, int MF, int NF, int EPIa, int EPIb, bool SWZ = false>
__global__ __launch_bounds__(WM * WN * 64) void gemmS(GP pa, GP pb, int nA) {
    constexpr int NT = WM * WN * 64;
    constexpr int BM = WM * MF * 16, BN = WN * NF * 16;
    constexpr int ABY = BM * 128, BBY = BN * 128;
    constexpr int LPT = (ABY + BBY) / (NT * 16);

    const int tid = threadIdx.x, w = tid >> 6, lane = tid & 63;
    const bool isA = (int)blockIdx.x < nA;
    GP p = isA ? pa : pb;
    int bid = isA ? blockIdx.x : blockIdx.x - nA;
    if constexpr (SWZ) bid = (bid & 7) * (nA >> 3) + (bid >> 3);   // T1, needs nA%8==0
    const int bn = bid % p.gridN, bm = bid / p.gridN;
    const int r0 = bm * BM, c0 = bn * BN;
    const int wm = w / WN, wn = w % WN;

    __shared__ __attribute__((aligned(16))) char sm[3 * (ABY + BBY)];
    __shared__ float ps_[WM * WN];

    auto stage = [&](int kt, int buf) {
        char* s = sm + buf * (ABY + BBY);
#pragma unroll
        for (int it = 0; it < ABY / (NT * 16); ++it) {
            int bo = it * (NT * 16) + tid * 16;
            int row = bo >> 7, kb = bo & 127;
            int kbs = kb ^ ((row & 7) << 4);                       // pre-swizzled source
            GLOAD16(p.A + (size_t)(r0 + row) * p.lda + kt * 64 + (kbs >> 1), s + bo);
        }
        char* sb = s + ABY;
#pragma unroll
        for (int it = 0; it < BBY / (NT * 16); ++it) {
            int bo = it * (NT * 16) + tid * 16;
            int row = bo >> 7, kb = bo & 127;
            int kbs = kb ^ ((row & 7) << 4);
            GLOAD16(p.Bt + (size_t)(c0 + row) * p.K + kt * 64 + (kbs >> 1), sb + bo);
        }
    };

    f32x4 acc[MF][NF];
#pragma unroll
    for (int mf = 0; mf < MF; ++mf)
#pragma unroll
        for (int nf = 0; nf < NF; ++nf) acc[mf][nf] = (f32x4){0.f, 0.f, 0.f, 0.f};

    const int nk = p.K >> 6;
    stage(0, 0);
    stage(1, 1);
    int b0 = 0, b1 = 1, b2 = 2;
    for (int kt = 0; kt < nk; ++kt) {
        if (kt < nk - 1) vmwait<LPT>(); else vmwait<0>();
        __builtin_amdgcn_sched_barrier(0);
        __builtin_amdgcn_s_barrier();
        if (kt + 2 < nk) stage(kt + 2, b2);
        const char* s = sm + b0 * (ABY + BBY);
#pragma unroll
        for (int ks = 0; ks < 2; ++ks) {
            const int kb = ks * 64 + ((lane >> 4) << 4);
            s16x8 aF[MF], bF[NF];
#pragma unroll
            for (int mf = 0; mf < MF; ++mf) {
                int rt = (wm * MF + mf) * 16 + (lane & 15);
                aF[mf] = *(const s16x8*)(s + rt * 128 + (kb ^ ((rt & 7) << 4)));
            }
#pragma unroll
            for (int nf = 0; nf < NF; ++nf) {
                int rt = (wn * NF + nf) * 16 + (lane & 15);
                bF[nf] = *(const s16x8*)(s + ABY + rt * 128 + (kb ^ ((rt & 7) << 4)));
            }
#pragma unroll
            for (int mf = 0; mf < MF; ++mf)
#pragma unroll
                for (int nf = 0; nf < NF; ++nf)
                    acc[mf][nf] = __builtin_amdgcn_mfma_f32_16x16x32_bf16(aF[mf], bF[nf], acc[mf][nf], 0, 0, 0);
        }
        int t_ = b0; b0 = b1; b1 = b2; b2 = t_;
    }

    const int lrow4 = (lane >> 4) << 2, lcol = lane & 15;
    if constexpr (EPIa == 8) {
        // requires NF==2: wave (wm,wn) owns one 32-class latent group
        const int lat = (c0 >> 5) + wn;
#pragma unroll
        for (int mf = 0; mf < MF; ++mf) {
#pragma unroll
            for (int j = 0; j < 4; ++j) {
                int r = r0 + (wm * MF + mf) * 16 + lrow4 + j;
                int col0 = c0 + wn * 32 + lcol;
                float v0 = acc[mf][0][j] + p.bias[col0];
                float v1 = acc[mf][1][j] + p.bias[col0 + 16];
                p.Cb[(size_t)r * p.ldc + col0] = f2bfu(v0);
                p.Cb[(size_t)r * p.ldc + col0 + 16] = f2bfu(v1);
                float mv; int mi;
                if (v1 > v0) { mv = v1; mi = lcol + 16; } else { mv = v0; mi = lcol; }
#pragma unroll
                for (int o = 8; o >= 1; o >>= 1) {
                    float ov = __shfl_xor(mv, o, 64);
                    int oi = __shfl_xor(mi, o, 64);
                    if (ov > mv || (ov == mv && oi < mi)) { mv = ov; mi = oi; }
                }
                if (lcol == 0) p.idx[(size_t)r * 32 + lat] = mi;
            }
        }
    } else if constexpr (EPIa == 5) {
        float lsum = 0.f;
#pragma unroll
        for (int mf = 0; mf < MF; ++mf) {
            int rowb = r0 + (wm * MF + mf) * 16 + lrow4;
#pragma unroll
            for (int nf = 0; nf < NF; ++nf) {
                int col = c0 + (wn * NF + nf) * 16 + lcol;
#pragma unroll
                for (int j = 0; j < 4; ++j) {
                    float v = acc[mf][nf][j] + p.bias[col];
                    int R = rowb + j + p.rbase;
                    int tt = R >> 8, b = R & 255;
                    int ch = col >> 9;
                    float z = (p.zs[((size_t)b * 64 + tt + 1) * 2048 + col] - p.zmean[ch]) / p.zstd[ch];
                    float d = v - z;
                    lsum += d * d;
                }
            }
        }
#pragma unroll
        for (int o = 32; o > 0; o >>= 1) lsum += __shfl_down(lsum, o, 64);
        if (lane == 0) ps_[w] = lsum;
        __syncthreads();
        if (tid == 0) {
            double s = 0.0;
#pragma unroll
            for (int i = 0; i < WM * WN; ++i) s += (double)ps_[i];
            atomicAdd(p.accum, s);
        }
    } else {
        if (isA) epiS<EPIa, MF, NF>(p, acc, r0, c0, wm, wn, lrow4, lcol);
        else     epiS<EPIb, MF, NF>(p, acc, r0, c0, wm, wn, lrow4, lcol);
    }
}

// ---------------------------------------------------------------------------
// k_gates: gx (K=1024) + full GRU epilogue; 3-deep pipeline.
// 512 blocks (bm 8 x bn 64), BM=32 x 32-col gate tile, TSZ=16KB, LPT=4.
// ---------------------------------------------------------------------------
template <bool FIRST>
__global__ __launch_bounds__(256) void k_gates(const u16* __restrict__ X, const u16* __restrict__ WihB,
                                               const float* __restrict__ bih, const float* __restrict__ bhh,
                                               const u16* __restrict__ GHb, float* __restrict__ hf32,
                                               u16* __restrict__ hallT) {
    constexpr int ABY = 32 * 128;       // 4 KB
    constexpr int BTB = 32 * 128;       // 4 KB per gate tile
    constexpr int TSZ = ABY + 3 * BTB;  // 16 KB
    const int tid = threadIdx.x, w = tid >> 6, lane = tid & 63;
    const int bm = blockIdx.x >> 6, bn = blockIdx.x & 63;
    const int r0 = bm * 32, c0 = bn * 32;
    const int wm = w >> 1, wn = w & 1;

    __shared__ __attribute__((aligned(16))) char sm[3 * TSZ];

    auto stage = [&](int kt, int buf) {
        char* s = sm + buf * TSZ;
        {
            int bo = tid * 16;                 // 256*16 = 4KB = ABY exactly
            int row = bo >> 7, kb = bo & 127;
            int kbs = kb ^ ((row & 7) << 4);
            GLOAD16(X + (size_t)(r0 + row) * 1024 + kt * 64 + (kbs >> 1), s + bo);
        }
        char* sb = s + ABY;
#pragma unroll
        for (int g = 0; g < 3; ++g) {
            int bo = tid * 16;
            int row = bo >> 7, kb = bo & 127;
            int kbs = kb ^ ((row & 7) << 4);
            GLOAD16(WihB + (size_t)(g * 2048 + c0 + row) * 1024 + kt * 64 + (kbs >> 1), sb + g * BTB + bo);
        }
    };

    f32x4 acc[3];
#pragma unroll
    for (int g = 0; g < 3; ++g) acc[g] = (f32x4){0.f, 0.f, 0.f, 0.f};

    stage(0, 0);
    stage(1, 1);
    int b0 = 0, b1 = 1, b2 = 2;
    for (int kt = 0; kt < 16; ++kt) {
        if (kt < 15) vmwait<4>(); else vmwait<0>();
        __builtin_amdgcn_sched_barrier(0);
        __builtin_amdgcn_s_barrier();
        if (kt + 2 < 16) stage(kt + 2, b2);
        const char* s = sm + b0 * TSZ;
#pragma unroll
        for (int ks = 0; ks < 2; ++ks) {
            const int kb = ks * 64 + ((lane >> 4) << 4);
            s16x8 aF, bF[3];
            {
                int rt = wm * 16 + (lane & 15);
                aF = *(const s16x8*)(s + rt * 128 + (kb ^ ((rt & 7) << 4)));
            }
#pragma unroll
            for (int g = 0; g < 3; ++g) {
                int rt = wn * 16 + (lane & 15);
                bF[g] = *(const s16x8*)(s + ABY + g * BTB + rt * 128 + (kb ^ ((rt & 7) << 4)));
            }
#pragma unroll
            for (int g = 0; g < 3; ++g)
                acc[g] = __builtin_amdgcn_mfma_f32_16x16x32_bf16(aF, bF[g], acc[g], 0, 0, 0);
        }
        int t_ = b0; b0 = b1; b1 = b2; b2 = t_;
    }

    const int lrow4 = (lane >> 4) << 2, lcol = lane & 15;
    const int cc = c0 + wn * 16 + lcol;
    {
        int rr0 = r0 + wm * 16 + lrow4;
#pragma unroll
        for (int j = 0; j < 4; ++j) {
            int rr = rr0 + j;
            float xr = acc[0][j] + bih[cc];
            float xz = acc[1][j] + bih[2048 + cc];
            float xn = acc[2][j] + bih[4096 + cc];
            float hr_, hz_, hn_;
            if (FIRST) { hr_ = bhh[cc]; hz_ = bhh[2048 + cc]; hn_ = bhh[4096 + cc]; }
            else {
                const u16* g = GHb + (size_t)rr * 6144;
                hr_ = bfu2f(g[cc]); hz_ = bfu2f(g[2048 + cc]); hn_ = bfu2f(g[4096 + cc]);
            }
            float r = sigm(xr + hr_);
            float u = sigm(xz + hz_);
            float n = tanhf(xn + r * hn_);
            float hold = FIRST ? 0.f : hf32[(size_t)rr * 2048 + cc];
            float h = (1.f - u) * n + u * hold;
            hf32[(size_t)rr * 2048 + cc] = h;
            hallT[(size_t)rr * 2048 + cc] = f2bfu(h);
        }
    }
}

// ---------------------------------------------------------------------------
// small kernels
// ---------------------------------------------------------------------------
__global__ void k_init(double* acc) { acc[0] = 0.0; acc[1] = 0.0; }

__global__ void k_cast(const float* __restrict__ src, u16* __restrict__ dst, int n4) {
    int i = blockIdx.x * 256 + threadIdx.x;
    if (i >= n4) return;
    f32x4 v = *(const f32x4*)(src + (size_t)i * 4);
    s16x4 o;
    o[0] = (short)f2bfu(v[0]); o[1] = (short)f2bfu(v[1]);
    o[2] = (short)f2bfu(v[2]); o[3] = (short)f2bfu(v[3]);
    *(s16x4*)(dst + (size_t)i * 4) = o;
}

// batched transpose: up to 4 (src,dst) pairs selected by blockIdx.z
struct TP { const float* s0; u16* d0; const float* s1; u16* d1;
            const float* s2; u16* d2; const float* s3; u16* d3; };
__global__ void k_transposeB(TP tp, int sld, int K) {
    __shared__ float tile[32][33];
    const float* src; u16* dst;
    switch (blockIdx.z) {
        case 0: src = tp.s0; dst = tp.d0; break;
        case 1: src = tp.s1; dst = tp.d1; break;
        case 2: src = tp.s2; dst = tp.d2; break;
        default: src = tp.s3; dst = tp.d3; break;
    }
    int k0 = blockIdx.x * 32, n0 = blockIdx.y * 32;
    for (int r = threadIdx.y; r < 32; r += 8)
        tile[r][threadIdx.x] = src[(size_t)(k0 + r) * sld + n0 + threadIdx.x];
    __syncthreads();
    for (int r = threadIdx.y; r < 32; r += 8)
        dst[(size_t)(n0 + r) * K + k0 + threadIdx.x] = f2bfu(tile[threadIdx.x][r]);
}

__global__ void k_transpose(const float* __restrict__ src, int sld, u16* __restrict__ dst, int K) {
    __shared__ float tile[32][33];
    int k0 = blockIdx.x * 32, n0 = blockIdx.y * 32;
    for (int r = threadIdx.y; r < 32; r += 8)
        tile[r][threadIdx.x] = src[(size_t)(k0 + r) * sld + n0 + threadIdx.x];
    __syncthreads();
    for (int r = threadIdx.y; r < 32; r += 8)
        dst[(size_t)(n0 + r) * K + k0 + threadIdx.x] = f2bfu(tile[threadIdx.x][r]);
}

__global__ void k_prep(const float* __restrict__ zsp, const float* __restrict__ zm,
                       const float* __restrict__ zsd, u16* __restrict__ flat) {
    size_t i = ((size_t)blockIdx.x * 256 + threadIdx.x) * 4;
    f32x4 v = *(const f32x4*)(zsp + i);
    int ch = ((int)(i >> 9)) & 3;
    float m = zm[ch], s = zsd[ch];
    s16x4 o;
    o[0] = (short)f2bfu((v[0] - m) / s); o[1] = (short)f2bfu((v[1] - m) / s);
    o[2] = (short)f2bfu((v[2] - m) / s); o[3] = (short)f2bfu((v[3] - m) / s);
    *(s16x4*)(flat + i) = o;
}

__global__ __launch_bounds__(256) void k_xpre0(const float* __restrict__ preW, const float* __restrict__ preb,
                                               const float* __restrict__ actions, u16* __restrict__ xout) {
    int b = blockIdx.x, tid = threadIdx.x;
    __shared__ float as[3];
    if (tid < 3) as[tid] = actions[(size_t)b * 64 * 3 + tid];
    __syncthreads();
    for (int j = tid; j < 1024; j += 256) {
        float s = preb[j] + as[0] * preW[1024 * 1024 + j] + as[1] * preW[1025 * 1024 + j] + as[2] * preW[1026 * 1024 + j];
        xout[(b << 10) + j] = f2bfu(eluf(s));
    }
}

// x-gen only (argmax fused into k3's EPI8 epilogue)
__global__ __launch_bounds__(256) void k_xgen(const int* __restrict__ latidx_t,
                                              const u16* __restrict__ PreLatB, const float* __restrict__ preW,
                                              const float* __restrict__ preb,
                                              const float* __restrict__ actions, u16* __restrict__ xout,
                                              int tnext) {
    int b = blockIdx.x, tid = threadIdx.x;
    __shared__ int idxs[32];
    __shared__ float as[3];
    if (tid < 32) idxs[tid] = latidx_t[(b << 5) + tid];
    if (tid >= 64 && tid < 67) as[tid - 64] = actions[((size_t)b * 64 + tnext) * 3 + (tid - 64)];
    __syncthreads();
    const int j4 = tid * 4;
    f32x4 s = *(const f32x4*)(preb + j4);
#pragma unroll
    for (int cc = 0; cc < 3; ++cc) {
        f32x4 wv = *(const f32x4*)(preW + (size_t)(1024 + cc) * 1024 + j4);
        s[0] += as[cc] * wv[0]; s[1] += as[cc] * wv[1];
        s[2] += as[cc] * wv[2]; s[3] += as[cc] * wv[3];
    }
#pragma unroll
    for (int l = 0; l < 32; ++l) {
        s16x4 v = *(const s16x4*)(PreLatB + (size_t)((l << 5) + idxs[l]) * 1024 + j4);
        s[0] += bfu2f((u16)v[0]); s[1] += bfu2f((u16)v[1]);
        s[2] += bfu2f((u16)v[2]); s[3] += bfu2f((u16)v[3]);
    }
    s16x4 o;
    o[0] = (short)f2bfu(eluf(s[0])); o[1] = (short)f2bfu(eluf(s[1]));
    o[2] = (short)f2bfu(eluf(s[2])); o[3] = (short)f2bfu(eluf(s[3]));
    *(s16x4*)(xout + (b << 10) + j4) = o;
}

// batched KL: one block per (t,b) row; reads bf16 post/prior logits
__global__ __launch_bounds__(256) void k_kl(const u16* __restrict__ PoAll, const u16* __restrict__ PrAll,
                                            float* __restrict__ klrow) {
    int m = blockIdx.x, tid = threadIdx.x;
    const u16* Po = PoAll + (size_t)m * 1024;
    const u16* Pr = PrAll + (size_t)m * 1024;
    __shared__ float klpart[32];
    int grp = tid >> 5, c = tid & 31;
#pragma unroll
    for (int it = 0; it < 4; ++it) {
        int l = it * 8 + grp;
        float po = bfu2f(Po[l * 32 + c]);
        float pr = bfu2f(Pr[l * 32 + c]);
        float mv = po, mq = pr;
#pragma unroll
        for (int o = 16; o > 0; o >>= 1) {
            mv = fmaxf(mv, __shfl_xor(mv, o, 32));
            mq = fmaxf(mq, __shfl_xor(mq, o, 32));
        }
        float ep = expf(po - mv), eq = expf(pr - mq);
        float sp = ep, sq = eq;
#pragma unroll
        for (int o = 16; o > 0; o >>= 1) { sp += __shfl_xor(sp, o, 32); sq += __shfl_xor(sq, o, 32); }
        float logp = po - mv - logf(sp);
        float logq = pr - mq - logf(sq);
        float klc = (ep / sp) * (logp - logq);
#pragma unroll
        for (int o = 16; o > 0; o >>= 1) klc += __shfl_xor(klc, o, 32);
        if (c == 0) klpart[l] = klc;
    }
    __syncthreads();
    if (tid == 0) {
        float kl = 0.f;
        for (int l = 0; l < 32; ++l) kl += klpart[l];
        klrow[m] = fmaxf(kl, 1.0f);
    }
}

__global__ __launch_bounds__(256) void k_latsum(const u16* __restrict__ LatB, const float* __restrict__ db1,
                                                const int* __restrict__ latidx_all, u16* __restrict__ latsum) {
    int m = blockIdx.x, tid = threadIdx.x;
    __shared__ int idxs[32];
    if (tid < 32) idxs[tid] = latidx_all[(size_t)m * 32 + tid];
    __syncthreads();
    const int j4 = tid * 4;
    f32x4 s = *(const f32x4*)(db1 + j4);
#pragma unroll
    for (int l = 0; l < 32; ++l) {
        s16x4 v = *(const s16x4*)(LatB + (size_t)((l << 5) + idxs[l]) * 1024 + j4);
        s[0] += bfu2f((u16)v[0]); s[1] += bfu2f((u16)v[1]);
        s[2] += bfu2f((u16)v[2]); s[3] += bfu2f((u16)v[3]);
    }
    s16x4 o;
    o[0] = (short)f2bfu(s[0]); o[1] = (short)f2bfu(s[1]);
    o[2] = (short)f2bfu(s[2]); o[3] = (short)f2bfu(s[3]);
    *(s16x4*)(latsum + (size_t)m * 1024 + j4) = o;
}

// NOTE: MUST be launched with 256 threads (r3-r5 bug: was <<<1,1>>>)
__global__ __launch_bounds__(256) void k_finalize(const double* __restrict__ acc,
                                                  const float* __restrict__ klrow, float* __restrict__ out) {
    __shared__ double ps[256];
    int tid = threadIdx.x;
    double s = 0.0;
    for (int i = tid; i < 16128; i += 256) s += (double)klrow[i];
    ps[tid] = s;
    __syncthreads();
    for (int o = 128; o > 0; o >>= 1) {
        if (tid < o) ps[tid] += ps[tid + o];
        __syncthreads();
    }
    if (tid == 0) out[0] = (float)(acc[0] / 33030144.0 + ps[0] / 16128.0);
}

// ---------------------------------------------------------------------------
extern "C" void kernel_launch(void* const* d_in, const int* in_sizes, int n_in,
                              void* d_out, int out_size, void* d_ws, size_t ws_size,
                              hipStream_t stream) {
    const float* zs      = (const float*)d_in[0];
    const float* actions = (const float*)d_in[1];
    const float* zmean   = (const float*)d_in[2];
    const float* zstd    = (const float*)d_in[3];
    const float* encW    = (const float*)d_in[4];
    const float* encb    = (const float*)d_in[5];
    const float* preW    = (const float*)d_in[6];
    const float* preb    = (const float*)d_in[7];
    const float* Wih     = (const float*)d_in[8];
    const float* Whh     = (const float*)d_in[9];
    const float* bih     = (const float*)d_in[10];
    const float* bhh     = (const float*)d_in[11];
    const float* tW1     = (const float*)d_in[12];
    const float* tb1     = (const float*)d_in[13];
    const float* tW2     = (const float*)d_in[14];
    const float* tb2     = (const float*)d_in[15];
    const float* rW1     = (const float*)d_in[16];
    const float* rb1     = (const float*)d_in[17];
    const float* rW2     = (const float*)d_in[18];
    const float* rb2     = (const float*)d_in[19];
    const float* dW1     = (const float*)d_in[20];
    const float* db1     = (const float*)d_in[21];
    const float* dW2     = (const float*)d_in[22];
    const float* db2     = (const float*)d_in[23];

    char* W = (char*)d_ws;
    size_t off = 0;
    auto take = [&](size_t b) { char* p = W + off; off += (b + 255) & ~(size_t)255; return p; };

    // ws budget ~271 MB (282 MB proven safe in r4: r4@282 and r5@233 bit-identical)
    double* accum  = (double*)take(16);
    u16* encWbt = (u16*)take((size_t)1024 * 2048 * 2);
    u16* WihB   = (u16*)take((size_t)6144 * 1024 * 2);
    u16* WhhB   = (u16*)take((size_t)6144 * 2048 * 2);
    u16* l1B    = (u16*)take((size_t)2048 * 2048 * 2);   // [tW1t | rW1at]
    u16* tW2bt  = (u16*)take((size_t)1024 * 1024 * 2);
    u16* rW2bt  = (u16*)take((size_t)1024 * 1024 * 2);
    u16* rW1bbt = (u16*)take((size_t)1024 * 1024 * 2);
    u16* dW1abt = (u16*)take((size_t)1024 * 2048 * 2);
    u16* dW2bt  = (u16*)take((size_t)2048 * 1024 * 2);
    u16* PreLatB = (u16*)take((size_t)1024 * 1024 * 2);
    u16* LatB    = (u16*)take((size_t)1024 * 1024 * 2);
    u16* Hall   = (u16*)take((size_t)63 * 256 * 2048 * 2);
    int* latidx = (int*)take((size_t)63 * 256 * 32 * 4);
    u16* embR   = (u16*)take((size_t)16384 * 1024 * 2);   // scan emb; then PrAll; then latsum
    u16* enc    = (u16*)take((size_t)16384 * 1024 * 2);   // encoder out; then PoAll
    float* klrow = (float*)take((size_t)16128 * 4);
    u16* GHb    = (u16*)take((size_t)2 * 256 * 6144 * 2);
    float* hf32 = (float*)take((size_t)256 * 2048 * 4);
    u16* x_bf   = (u16*)take((size_t)256 * 1024 * 2);
    u16* p1q1   = (u16*)take((size_t)256 * 1024 * 2);
    char* X     = take((size_t)67108864);                  // 64 MB: flatc (1-shot) / Xp / d1

    u16* flatc = (u16*)X;                                  // 16384 x 2048 (1-shot)
    u16* Xp    = (u16*)X;                                  // 16128 x 1024 (1-shot)
    u16* d1    = (u16*)X;                                  // 16128 x 1024 (1-shot)
    u16* PoAll = enc;                                      // enc dead after embR GEMM
    u16* PrAll = embR;                                     // embR dead after scan; consumed by k_kl before latsum

    k_init<<<1, 1, 0, stream>>>(accum);

    // weight conversion (batched transposes: 8 launches -> 3)
    k_cast<<<6144, 256, 0, stream>>>(Wih, WihB, 6291456 / 4);
    k_cast<<<12288, 256, 0, stream>>>(Whh, WhhB, 12582912 / 4);
    k_cast<<<1024, 256, 0, stream>>>(preW, PreLatB, 262144);
    k_cast<<<1024, 256, 0, stream>>>(dW1 + (size_t)2048 * 1024, LatB, 262144);
    {
        TP t4{encW, encWbt, tW1, l1B, rW1, l1B + (size_t)1024 * 2048, dW1, dW1abt};
        k_transposeB<<<dim3(64, 32, 4), dim3(32, 8), 0, stream>>>(t4, 1024, 2048);
        TP t3{tW2, tW2bt, rW2, rW2bt, rW1 + (size_t)2048 * 1024, rW1bbt, nullptr, nullptr};
        k_transposeB<<<dim3(32, 32, 3), dim3(32, 8), 0, stream>>>(t3, 1024, 1024);
    }
    k_transpose<<<dim3(32, 64), dim3(32, 8), 0, stream>>>(dW2, 2048, dW2bt, 1024);

    // phase 1: encoder (single pass, 16384 rows; 128² 8-wave gemmS + T1 swizzle)
    k_prep<<<32768, 256, 0, stream>>>(zs, zmean, zstd, flatc);
    {
        GP e{}; e.A = flatc; e.lda = 2048; e.Bt = encWbt; e.Cb = enc;
        e.ldc = 1024; e.bias = encb; e.K = 2048; e.gridN = 8;
        gemmS<4, 2, 2, 4, 1, 1, true><<<dim3(1024), 512, 0, stream>>>(e, e, 1024);
    }
    {
        GP e{}; e.A = enc; e.lda = 1024; e.Bt = rW1bbt; e.Cb = embR; e.ldc = 1024;
        e.bias = rb1; e.K = 1024; e.gridN = 8;
        gemmS<4, 2, 2, 4, 2, 2, true><<<dim3(1024), 512, 0, stream>>>(e, e, 1024);
    }

    // phase 2: sequential scan (post-only path; prior deferred)
    k_xpre0<<<256, 256, 0, stream>>>(preW, preb, actions, x_bf);
    for (int t = 0; t < 63; ++t) {
        // k1: gx + GRU -> h_t (512 blocks)
        if (t == 0)
            k_gates<true><<<512, 256, 0, stream>>>(x_bf, WihB, bih, bhh, GHb, hf32, Hall);
        else
            k_gates<false><<<512, 256, 0, stream>>>(x_bf, WihB, bih, bhh, GHb + (size_t)(t & 1) * 256 * 6144,
                                                    hf32, Hall + (size_t)t * 256 * 2048);
        // k2: gh(t+1) (bf16) || l1-post(t) — 8-wave blocks (512 thr), 448 tiles
        {
            GP pa{}; pa.A = Hall + (size_t)t * 256 * 2048; pa.lda = 2048; pa.Bt = WhhB;
            pa.Cb = GHb + (size_t)((t + 1) & 1) * 256 * 6144; pa.ldc = 6144; pa.bias = bhh;
            pa.K = 2048; pa.gridN = 96;
            GP pb{}; pb.A = Hall + (size_t)t * 256 * 2048; pb.lda = 2048;
            pb.Bt = l1B + (size_t)1024 * 2048; pb.Cb = p1q1; pb.ldc = 1024;
            pb.aux = embR + (size_t)(t + 1) * 1024; pb.auxld = 65536;
            pb.K = 2048; pb.gridN = 16;
            int nA = (t < 62) ? 384 : 0;
            gemmS<2, 4, 2, 1, 7, 4><<<dim3(nA + 64), 512, 0, stream>>>(pa, pb, nA);
        }
        // k3: q-post — 256 blocks x 2 waves (1 block/CU, occupancy regime)
        {
            GP q{}; q.A = p1q1; q.lda = 1024; q.Bt = rW2bt; q.ldc = 1024;
            q.Cb = PoAll + (size_t)t * 256 * 1024; q.bias = rb2; q.K = 1024; q.gridN = 32;
            q.idx = latidx + (size_t)t * 256 * 32;
            gemmS<2, 1, 1, 2, 8, 8><<<dim3(256), 128, 0, stream>>>(q, q, 256);
        }
        // k4: next x from latidx
        if (t < 62)
            k_xgen<<<256, 256, 0, stream>>>(latidx + (size_t)t * 256 * 32,
                                            PreLatB, preW, preb, actions, x_bf, t + 1);
    }

    // phase 3a: batched prior (1-shot, 16128 rows; 128² + T1 swizzle) + KL
    {
        GP e{}; e.A = Hall; e.lda = 2048; e.Bt = l1B; e.Cb = Xp; e.ldc = 1024;
        e.bias = tb1; e.K = 2048; e.gridN = 8;
        gemmS<4, 2, 2, 4, 1, 1, true><<<dim3(1008), 512, 0, stream>>>(e, e, 1008);
        GP q{}; q.A = Xp; q.lda = 1024; q.Bt = tW2bt; q.Cb = PrAll; q.ldc = 1024;
        q.bias = tb2; q.K = 1024; q.gridN = 8;
        gemmS<4, 2, 2, 4, 2, 2, true><<<dim3(1008), 512, 0, stream>>>(q, q, 1008);
    }
    k_kl<<<16128, 256, 0, stream>>>(PoAll, PrAll, klrow);

    // phase 3b: decoder + fused recon (1-shot; 128² + T1 swizzle)
    k_latsum<<<16128, 256, 0, stream>>>(LatB, db1, latidx, embR);
    {
        GP d{}; d.A = Hall; d.lda = 2048; d.Bt = dW1abt; d.Cb = d1; d.ldc = 1024;
        d.aux = embR; d.auxld = 1024; d.K = 2048; d.gridN = 8;
        gemmS<4, 2, 2, 4, 4, 4, true><<<dim3(1008), 512, 0, stream>>>(d, d, 1008);
        GP d2{}; d2.A = d1; d2.lda = 1024; d2.Bt = dW2bt; d2.ldc = 2048; d2.bias = db2;
        d2.zs = zs; d2.zmean = zmean; d2.zstd = zstd; d2.accum = accum; d2.K = 1024; d2.gridN = 16;
        d2.rbase = 0;
        gemmS<4, 2, 2, 4, 5, 5, true><<<dim3(2016), 512, 0, stream>>>(d2, d2, 2016);
    }
    k_finalize<<<1, 256, 0, stream>>>(accum, klrow, (float*)d_out);
}